// Round 8
// baseline (568.369 us; speedup 1.0000x reference)
//
#include <hip/hip_runtime.h>
#include <math.h>

#define B_ 2
#define H_ 64
#define W_ 64
#define C_ 256
#define G_ 16
#define HW_ (H_*W_)          // 4096
#define M_ (B_*HW_)          // 8192
#define C4_ (4*C_)           // 1024
#define OFFN_ 288
#define MSKN_ 144
#define OMN_ 432
#define UH_ 128
#define UW_ 128
#define MUP_ (B_*UH_*UW_)    // 32768
#define KUP_ (9*C_)          // 2304
#define NOUT_ 128

typedef short short8 __attribute__((ext_vector_type(8)));
typedef float f32x4 __attribute__((ext_vector_type(4)));
typedef unsigned short us4 __attribute__((ext_vector_type(4)));

__device__ __forceinline__ float gelu_f(float x){
  return 0.5f * x * (1.f + erff(x * 0.70710678118654752440f));
}
__device__ __forceinline__ float sigmoid_f(float x){ return 1.f/(1.f+expf(-x)); }
__device__ __forceinline__ unsigned short f2bf(float x){
  unsigned int u = __float_as_uint(x);
  unsigned int r = (u + 0x7fffu + ((u>>16)&1u)) >> 16;
  return (unsigned short)r;
}
__device__ __forceinline__ float bf2f(unsigned short u){
  return __uint_as_float(((unsigned int)u) << 16);
}
__device__ __forceinline__ float bfl(unsigned int u){ return __uint_as_float(u<<16); }
__device__ __forceinline__ float bfh(unsigned int u){ return __uint_as_float(u & 0xffff0000u); }
__device__ __forceinline__ unsigned int pk(float a, float b){
  return (unsigned int)f2bf(a) | ((unsigned int)f2bf(b) << 16);
}

__device__ __forceinline__ void block_sum2(float& s, float& ss, float* sm){
  #pragma unroll
  for (int off=32; off>0; off>>=1){ s += __shfl_down(s, off); ss += __shfl_down(ss, off); }
  int lane = threadIdx.x & 63, wid = threadIdx.x >> 6;
  if (lane == 0){ sm[wid] = s; sm[4+wid] = ss; }
  __syncthreads();
  float a = 0.f, b = 0.f;
  int nw = blockDim.x >> 6;
  for (int i=0;i<nw;i++){ a += sm[i]; b += sm[4+i]; }
  s = a; ss = b;
}

__device__ __forceinline__ void block_summax(float& s, float& m, float* sm){
  #pragma unroll
  for (int off=32; off>0; off>>=1){ s += __shfl_down(s, off); m = fmaxf(m, __shfl_down(m, off)); }
  int lane = threadIdx.x & 63, wid = threadIdx.x >> 6;
  if (lane == 0){ sm[wid] = s; sm[4+wid] = m; }
  __syncthreads();
  float a = 0.f, b = -3.4e38f;
  int nw = blockDim.x >> 6;
  for (int i=0;i<nw;i++){ a += sm[i]; b = fmaxf(b, sm[4+i]); }
  s = a; m = b;
}

// ---------------- batched weight prep: W[K][N] fp32 -> Wt[N][K] bf16 ----------------
#define NJOBS 13
struct WtJobs {
  const float* src[NJOBS];
  unsigned short* dst[NJOBS];
  int Kd[NJOBS], Nd[NJOBS];
  int tOff[NJOBS+1];
};

__global__ __launch_bounds__(256) void k_wt_all(WtJobs J){
  __shared__ float tile[32][33];
  int bid = blockIdx.x;
  int j = 0;
  while (bid >= J.tOff[j+1]) j++;
  int lt = bid - J.tOff[j];
  const float* W = J.src[j];
  unsigned short* Wt = J.dst[j];
  int Kd = J.Kd[j], Nd = J.Nd[j];
  int ktiles = Kd >> 5;
  int k0 = (lt % ktiles) * 32, n0 = (lt / ktiles) * 32;
  int t = threadIdx.x;
  int r = t>>3, c4 = (t&7)*4;
  float4 v = make_float4(0.f,0.f,0.f,0.f);
  if (n0 + c4 < Nd) v = *(const float4*)(W + (size_t)(k0+r)*Nd + n0 + c4);
  tile[c4+0][r]=v.x; tile[c4+1][r]=v.y; tile[c4+2][r]=v.z; tile[c4+3][r]=v.w;
  __syncthreads();
  if (n0 + r < Nd){
    us4 o;
    o.x = f2bf(tile[r][c4+0]); o.y = f2bf(tile[r][c4+1]);
    o.z = f2bf(tile[r][c4+2]); o.w = f2bf(tile[r][c4+3]);
    *(us4*)(Wt + (size_t)(n0+r)*Kd + k0 + c4) = o;
  }
}

// ---------------- CBAM ----------------
__global__ __launch_bounds__(256) void k_chpool(const float* __restrict__ Xin,
      float* __restrict__ psum, float* __restrict__ pmax){
  int chunk = blockIdx.x, b = blockIdx.y; int c = threadIdx.x;
  const float* p = Xin + (((size_t)b*HW_) + chunk*32)*C_ + c;
  float s = 0.f, m = -3.4e38f;
  for (int i=0;i<32;i++){ float v = p[(size_t)i*C_]; s += v; m = fmaxf(m, v); }
  psum[(b*128+chunk)*C_+c] = s; pmax[(b*128+chunk)*C_+c] = m;
}

__global__ __launch_bounds__(512) void k_ca(const float* __restrict__ psum, const float* __restrict__ pmax,
    const float* __restrict__ w1, const float* __restrict__ w2, float* __restrict__ ca){
  __shared__ float pm[2][256], px[2][256], hh[2][2][16];
  int t = threadIdx.x;
  {
    int b = t >> 8, c = t & 255;
    float s = 0.f, m = -3.4e38f;
    for (int ch=0; ch<128; ch++){ s += psum[(b*128+ch)*256+c]; m = fmaxf(m, pmax[(b*128+ch)*256+c]); }
    pm[b][c] = s * (1.f/4096.f); px[b][c] = m;
  }
  __syncthreads();
  if (t < 64){
    int b = t >> 5, typ = (t >> 4) & 1, j = t & 15;
    const float* src = typ ? px[b] : pm[b];
    float a = 0.f;
    for (int c2=0;c2<256;c2++) a += src[c2]*w1[c2*16+j];
    hh[b][typ][j] = fmaxf(a, 0.f);
  }
  __syncthreads();
  {
    int b = t >> 8, c = t & 255;
    float a = 0.f;
    for (int j=0;j<16;j++) a += (hh[b][0][j]+hh[b][1][j]) * w2[j*256+c];
    ca[b*256+c] = sigmoid_f(a);
  }
}

__global__ __launch_bounds__(256) void k_apply_ca(const float* __restrict__ Xin, float* __restrict__ X,
    const float* __restrict__ ca, float* __restrict__ smean, float* __restrict__ smax){
  __shared__ float sm[12];
  int pix = blockIdx.x, c = threadIdx.x;
  int b = pix >> 12;
  float v = Xin[(size_t)pix*C_+c] * ca[b*C_+c];
  X[(size_t)pix*C_+c] = v;
  float s = v, m = v;
  block_summax(s, m, sm);
  if (c == 0){ smean[pix] = s * (1.f/C_); smax[pix] = m; }
}

__global__ __launch_bounds__(256) void k_sa(const float* __restrict__ smean, const float* __restrict__ smax,
    const float* __restrict__ w, float* __restrict__ sa){
  int pix = blockIdx.x*256 + threadIdx.x;
  if (pix >= M_) return;
  int b = pix >> 12, hw = pix & 4095, h = hw >> 6, ww = hw & 63;
  float s = 0.f;
  for (int ky=0;ky<7;ky++){
    int hh = h + ky - 3; if (hh < 0 || hh >= H_) continue;
    for (int kx=0;kx<7;kx++){
      int xx = ww + kx - 3; if (xx < 0 || xx >= W_) continue;
      int q = (b<<12) + (hh<<6) + xx;
      s += smean[q]*w[(ky*7+kx)*2+0] + smax[q]*w[(ky*7+kx)*2+1];
    }
  }
  sa[pix] = sigmoid_f(s);
}

// X = LN(X*sa)  (CBAM LN), then Tb = LN1(X) bf16  — two LNs fused
__global__ __launch_bounds__(256) void k_mul_ln_ln1(float* __restrict__ X, const float* __restrict__ sa,
    const float* __restrict__ g, const float* __restrict__ b,
    const float* __restrict__ g1, const float* __restrict__ b1, unsigned short* __restrict__ Tb){
  __shared__ float sm[12];
  int pix = blockIdx.x, c = threadIdx.x;
  float v = X[(size_t)pix*C_+c] * sa[pix];
  float s = v, ss = v*v;
  block_sum2(s, ss, sm);
  float mean = s * (1.f/C_), var = ss*(1.f/C_) - mean*mean;
  float r = rsqrtf(var + 1e-6f);
  float x0 = (v-mean)*r*g[c] + b[c];
  X[(size_t)pix*C_+c] = x0;
  __syncthreads();
  s = x0; ss = x0*x0;
  block_sum2(s, ss, sm);
  mean = s * (1.f/C_); var = ss*(1.f/C_) - mean*mean;
  r = rsqrtf(var + 1e-6f);
  Tb[(size_t)pix*C_+c] = f2bf((x0-mean)*r*g1[c] + b1[c]);
}

// depthwise conv (bf16 in) + bias + LN (+GELU) -> bf16, 8 ch/thread  (R5 proven)
template<int KS, int DOGELU>
__global__ __launch_bounds__(256) void k_dwconv(const unsigned short* __restrict__ T,
    unsigned short* __restrict__ Out,
    const float* __restrict__ w, const float* __restrict__ bias,
    const float* __restrict__ g, const float* __restrict__ bb){
  constexpr int R = KS/2;
  int t = blockIdx.x*256 + threadIdx.x;
  int pix = t >> 5, grp = t & 31;
  int c0 = grp*8;
  int b = pix >> 12, hw = pix & 4095, h = hw >> 6, ww = hw & 63;
  float acc[8];
  {
    float4 b0 = *(const float4*)(bias + c0), b1 = *(const float4*)(bias + c0 + 4);
    acc[0]=b0.x; acc[1]=b0.y; acc[2]=b0.z; acc[3]=b0.w;
    acc[4]=b1.x; acc[5]=b1.y; acc[6]=b1.z; acc[7]=b1.w;
  }
  const unsigned short* tb = T + ((size_t)b*HW_)*C_ + c0;
  for (int ky=0;ky<KS;ky++){
    int hh = h + ky - R; if (hh < 0 || hh >= H_) continue;
    for (int kx=0;kx<KS;kx++){
      int xx = ww + kx - R; if (xx < 0 || xx >= W_) continue;
      uint4 a = *(const uint4*)(tb + ((size_t)hh*W_+xx)*C_);
      const float* wp = w + (ky*KS+kx)*C_ + c0;
      float4 w0 = *(const float4*)wp, w1 = *(const float4*)(wp+4);
      acc[0] += bfl(a.x)*w0.x; acc[1] += bfh(a.x)*w0.y;
      acc[2] += bfl(a.y)*w0.z; acc[3] += bfh(a.y)*w0.w;
      acc[4] += bfl(a.z)*w1.x; acc[5] += bfh(a.z)*w1.y;
      acc[6] += bfl(a.w)*w1.z; acc[7] += bfh(a.w)*w1.w;
    }
  }
  float s = 0.f, ss = 0.f;
  #pragma unroll
  for (int i=0;i<8;i++){ s += acc[i]; ss += acc[i]*acc[i]; }
  #pragma unroll
  for (int off=1; off<32; off<<=1){ s += __shfl_xor(s, off); ss += __shfl_xor(ss, off); }
  float mean = s * (1.f/C_), var = ss*(1.f/C_) - mean*mean;
  float r = rsqrtf(var + 1e-6f);
  float4 g0 = *(const float4*)(g + c0), g1 = *(const float4*)(g + c0 + 4);
  float4 p0 = *(const float4*)(bb + c0), p1 = *(const float4*)(bb + c0 + 4);
  float o[8];
  o[0]=(acc[0]-mean)*r*g0.x+p0.x; o[1]=(acc[1]-mean)*r*g0.y+p0.y;
  o[2]=(acc[2]-mean)*r*g0.z+p0.z; o[3]=(acc[3]-mean)*r*g0.w+p0.w;
  o[4]=(acc[4]-mean)*r*g1.x+p1.x; o[5]=(acc[5]-mean)*r*g1.y+p1.y;
  o[6]=(acc[6]-mean)*r*g1.z+p1.z; o[7]=(acc[7]-mean)*r*g1.w+p1.w;
  if (DOGELU){
    #pragma unroll
    for (int i=0;i<8;i++) o[i] = gelu_f(o[i]);
  }
  uint4 ov;
  ov.x = pk(o[0],o[1]); ov.y = pk(o[2],o[3]); ov.z = pk(o[4],o[5]); ov.w = pk(o[6],o[7]);
  *(uint4*)(Out + (size_t)pix*C_ + c0) = ov;
}

// ---------------- bf16 MFMA GEMM (generic, N-tiled, BK=32)  (R5 proven) ----------------
// EP: 0=bias, 1=bias+gelu, 4=concat-bias (n<288: bias[n], else bias2[n-288])
template<int TM, int EP, int OUTBF>
__global__ __launch_bounds__(256) void k_gemm_mfma(
    const unsigned short* __restrict__ A, const unsigned short* __restrict__ Bt,
    void* __restrict__ OutV, const float* __restrict__ bias,
    const float* __restrict__ bias2, int Ni, int Ki)
{
  constexpr int LD = 40;
  __shared__ unsigned short As[TM*LD];
  __shared__ unsigned short Bs[128*LD];
  const int tid = threadIdx.x;
  const int wave = tid >> 6, lane = tid & 63;
  const int m0 = blockIdx.x * TM, n0 = blockIdx.y * 128;
  const int wm0 = (wave >> 1) * (TM/2);
  const int wn0 = (wave & 1) * 64;
  constexpr int MI = (TM+31)/32;
  f32x4 acc[MI][4] = {};
  const int lm = lane & 15, kq = lane >> 4;

  for (int k0 = 0; k0 < Ki; k0 += 32){
    for (int ch = tid; ch < TM*4; ch += 256){
      int r = ch >> 2, cc = (ch & 3) << 3;
      short8 v = *(const short8*)(A + (size_t)(m0 + r)*Ki + k0 + cc);
      *(short8*)(As + r*LD + cc) = v;
    }
    #pragma unroll
    for (int i=0;i<2;i++){
      int ch = tid + 256*i;
      int r = ch >> 2, cc = (ch & 3) << 3;
      short8 v = {};
      if (n0 + r < Ni) v = *(const short8*)(Bt + (size_t)(n0 + r)*Ki + k0 + cc);
      *(short8*)(Bs + r*LD + cc) = v;
    }
    __syncthreads();
    short8 af[MI], bf[4];
    #pragma unroll
    for (int mi=0;mi<MI;mi++) af[mi] = *(const short8*)(As + (wm0 + mi*16 + lm)*LD + kq*8);
    #pragma unroll
    for (int ni=0;ni<4;ni++)  bf[ni] = *(const short8*)(Bs + (wn0 + ni*16 + lm)*LD + kq*8);
    #pragma unroll
    for (int mi=0;mi<MI;mi++)
      #pragma unroll
      for (int ni=0;ni<4;ni++)
        acc[mi][ni] = __builtin_amdgcn_mfma_f32_16x16x32_bf16(af[mi], bf[ni], acc[mi][ni], 0,0,0);
    __syncthreads();
  }
  #pragma unroll
  for (int mi=0;mi<MI;mi++){
    #pragma unroll
    for (int ni=0;ni<4;ni++){
      int n = n0 + wn0 + ni*16 + lm;
      if (n < Ni){
        float bv;
        if constexpr (EP==4) bv = (n < OFFN_) ? bias[n] : bias2[n-OFFN_];
        else bv = bias[n];
        #pragma unroll
        for (int r=0;r<4;r++){
          int m = m0 + wm0 + mi*16 + kq*4 + r;
          size_t o = (size_t)m*Ni + n;
          float v = acc[mi][ni][r] + bv;
          if constexpr (EP==1) v = gelu_f(v);
          if constexpr (OUTBF) ((unsigned short*)OutV)[o] = f2bf(v);
          else                 ((float*)OutV)[o] = v;
        }
      }
    }
  }
}

// ---------------- GEMM with fused residual + row-LN epilogue ----------------
// TM=32, N=256 full in-block. block=512 (8 waves: 2 m-halves x 4 n-quarters), BK=64.
// EP=2: v = acc+bias+X[o];            X[o]=v; LN(v) -> OutTb bf16
// EP=3: v = X[o]+bf(res2b[o])+gamma[n]*(acc+bias); X[o]=v; LN(v) -> OutTb bf16
template<int EP>
__global__ __launch_bounds__(512) void k_gemm_ln(
    const unsigned short* __restrict__ A, const unsigned short* __restrict__ Bt,
    float* __restrict__ X, const float* __restrict__ bias,
    const unsigned short* __restrict__ res2b, const float* __restrict__ gamma,
    unsigned short* __restrict__ OutTb,
    const float* __restrict__ lng, const float* __restrict__ lnb, int Ki)
{
  constexpr int LD = 72;
  __shared__ unsigned short As[32*LD];
  __shared__ unsigned short Bs[256*LD];
  __shared__ float rs[32][4], rq[32][4];
  const int tid = threadIdx.x;
  const int wave = tid >> 6, lane = tid & 63;
  const int m0 = blockIdx.x * 32;
  const int wm0 = (wave >> 2) * 16;       // 2 m-halves
  const int wn0 = (wave & 3) * 64;        // 4 n-quarters
  const int lm = lane & 15, kq = lane >> 4;
  f32x4 acc[4] = {};

  for (int k0 = 0; k0 < Ki; k0 += 64){
    if (tid < 256){
      int r = tid >> 3, cc = (tid & 7) << 3;
      short8 v = *(const short8*)(A + (size_t)(m0 + r)*Ki + k0 + cc);
      *(short8*)(As + r*LD + cc) = v;
    }
    #pragma unroll
    for (int i=0;i<4;i++){
      int ch = tid + 512*i;
      int r = ch >> 3, cc = (ch & 7) << 3;
      short8 v = *(const short8*)(Bt + (size_t)r*Ki + k0 + cc);
      *(short8*)(Bs + r*LD + cc) = v;
    }
    __syncthreads();
    short8 af[2], bf4[4][2];
    #pragma unroll
    for (int kk=0;kk<2;kk++)
      af[kk] = *(const short8*)(As + (wm0 + lm)*LD + kk*32 + kq*8);
    #pragma unroll
    for (int ni=0;ni<4;ni++)
      #pragma unroll
      for (int kk=0;kk<2;kk++)
        bf4[ni][kk] = *(const short8*)(Bs + (wn0 + ni*16 + lm)*LD + kk*32 + kq*8);
    #pragma unroll
    for (int kk=0;kk<2;kk++)
      #pragma unroll
      for (int ni=0;ni<4;ni++)
        acc[ni] = __builtin_amdgcn_mfma_f32_16x16x32_bf16(af[kk], bf4[ni][kk], acc[ni], 0,0,0);
    __syncthreads();
  }
  // epilogue: residual add, write X, row-LN (quarter-sums -> LDS), write OutTb
  int nn[4]; float bv[4], gv[4];
  #pragma unroll
  for (int ni=0;ni<4;ni++){
    nn[ni] = wn0 + ni*16 + lm;
    bv[ni] = bias[nn[ni]];
    if constexpr (EP==3) gv[ni] = gamma[nn[ni]];
  }
  float ps[4] = {}, pq[4] = {};
  #pragma unroll
  for (int r=0;r<4;r++){
    int m = m0 + wm0 + kq*4 + r;
    #pragma unroll
    for (int ni=0;ni<4;ni++){
      size_t o = (size_t)m*C_ + nn[ni];
      float v = acc[ni][r] + bv[ni];
      if constexpr (EP==2) v = X[o] + v;
      if constexpr (EP==3) v = X[o] + bf2f(res2b[o]) + gv[ni]*v;
      X[o] = v;
      acc[ni][r] = v;
      ps[r] += v; pq[r] += v*v;
    }
  }
  #pragma unroll
  for (int off=1; off<16; off<<=1){
    #pragma unroll
    for (int r=0;r<4;r++){ ps[r] += __shfl_xor(ps[r], off); pq[r] += __shfl_xor(pq[r], off); }
  }
  if (lm == 0){
    #pragma unroll
    for (int r=0;r<4;r++){
      rs[wm0 + kq*4 + r][wave & 3] = ps[r];
      rq[wm0 + kq*4 + r][wave & 3] = pq[r];
    }
  }
  __syncthreads();
  float lg[4], lb[4];
  #pragma unroll
  for (int ni=0;ni<4;ni++){ lg[ni] = lng[nn[ni]]; lb[ni] = lnb[nn[ni]]; }
  #pragma unroll
  for (int r=0;r<4;r++){
    int row = wm0 + kq*4 + r;
    int m = m0 + row;
    float s = rs[row][0] + rs[row][1] + rs[row][2] + rs[row][3];
    float q = rq[row][0] + rq[row][1] + rq[row][2] + rq[row][3];
    float mean = s * (1.f/C_), var = q*(1.f/C_) - mean*mean;
    float rstd = rsqrtf(var + 1e-6f);
    #pragma unroll
    for (int ni=0;ni<4;ni++){
      size_t o = (size_t)m*C_ + nn[ni];
      OutTb[o] = f2bf((acc[ni][r]-mean)*rstd*lg[ni] + lb[ni]);
    }
  }
}

// DCNv3 sampling, thread = (pix, g), 16 ch; OM staged in LDS
__global__ __launch_bounds__(256) void k_dcn(const unsigned short* __restrict__ xp,
    const float* __restrict__ OM, unsigned short* __restrict__ S){
  __shared__ float lom[16*OMN_];
  int pix0 = blockIdx.x * 16;
  {
    const float* gsrc = OM + (size_t)pix0*OMN_;
    for (int idx = threadIdx.x; idx < 16*OMN_; idx += 256) lom[idx] = gsrc[idx];
  }
  __syncthreads();
  int pl = threadIdx.x >> 4, g = threadIdx.x & 15;
  int pix = pix0 + pl;
  int b = pix >> 12, hw = pix & 4095, h = hw >> 6, ww = hw & 63;
  const float* offp = lom + pl*OMN_ + g*18;
  const float* mp   = lom + pl*OMN_ + OFFN_ + g*9;
  const unsigned short* xpb = xp + ((size_t)b*HW_)*C_ + g*16;
  float e[9]; float mx = -3.4e38f;
  #pragma unroll
  for (int k=0;k<9;k++){ e[k] = mp[k]; mx = fmaxf(mx, e[k]); }
  float ssum = 0.f;
  #pragma unroll
  for (int k=0;k<9;k++){ e[k] = expf(e[k]-mx); ssum += e[k]; }
  float rinv = 1.f/ssum;
  float acc[16] = {};
  #pragma unroll
  for (int k=0;k<9;k++){
    float ox = offp[k*2+0], oy = offp[k*2+1];
    float px = (float)(ww + (k%3)) + ox;
    float py = (float)(h  + (k/3)) + oy;
    int x0 = (int)floorf(px), y0 = (int)floorf(py);
    float fx = px - (float)x0, fy = py - (float)y0;
    float mk = e[k]*rinv;
    float w00 = mk*(1.f-fx)*(1.f-fy), w01 = mk*fx*(1.f-fy);
    float w10 = mk*(1.f-fx)*fy,       w11 = mk*fx*fy;
    #define CORNER(yy,xx,WGT) do{ \
      if ((yy)>=1 && (yy)<=H_ && (xx)>=1 && (xx)<=W_){ \
        const unsigned short* p = xpb + ((size_t)((yy)-1)*W_ + ((xx)-1))*C_; \
        uint4 a0 = *(const uint4*)p; uint4 a1 = *(const uint4*)(p+8); \
        acc[0]+=WGT*bfl(a0.x); acc[1]+=WGT*bfh(a0.x); acc[2]+=WGT*bfl(a0.y); acc[3]+=WGT*bfh(a0.y); \
        acc[4]+=WGT*bfl(a0.z); acc[5]+=WGT*bfh(a0.z); acc[6]+=WGT*bfl(a0.w); acc[7]+=WGT*bfh(a0.w); \
        acc[8]+=WGT*bfl(a1.x); acc[9]+=WGT*bfh(a1.x); acc[10]+=WGT*bfl(a1.y); acc[11]+=WGT*bfh(a1.y); \
        acc[12]+=WGT*bfl(a1.z); acc[13]+=WGT*bfh(a1.z); acc[14]+=WGT*bfl(a1.w); acc[15]+=WGT*bfh(a1.w); \
      } \
    }while(0)
    CORNER(y0,   x0,   w00);
    CORNER(y0,   x0+1, w01);
    CORNER(y0+1, x0,   w10);
    CORNER(y0+1, x0+1, w11);
    #undef CORNER
  }
  unsigned short* sp = S + (size_t)pix*C_ + g*16;
  uint4 o0, o1;
  o0.x = pk(acc[0],acc[1]);   o0.y = pk(acc[2],acc[3]);
  o0.z = pk(acc[4],acc[5]);   o0.w = pk(acc[6],acc[7]);
  o1.x = pk(acc[8],acc[9]);   o1.y = pk(acc[10],acc[11]);
  o1.z = pk(acc[12],acc[13]); o1.w = pk(acc[14],acc[15]);
  *(uint4*)sp = o0;
  *(uint4*)(sp+8) = o1;
}

// bilinear 2x upsample (bf16 in) -> bf16, 8 ch/thread
__global__ __launch_bounds__(256) void k_upsample(const unsigned short* __restrict__ T, unsigned short* __restrict__ U){
  int t = blockIdx.x*256 + threadIdx.x;
  int opix = t >> 5, grp = t & 31;
  int c0 = grp*8;
  int ox = opix & 127, oy = (opix >> 7) & 127, b = opix >> 14;
  float sy = oy*0.5f - 0.25f, sx = ox*0.5f - 0.25f;
  int y0 = (int)floorf(sy), x0 = (int)floorf(sx);
  float fy = sy - (float)y0, fx = sx - (float)x0;
  int y0c = min(max(y0,0),H_-1), y1c = min(max(y0+1,0),H_-1);
  int x0c = min(max(x0,0),W_-1), x1c = min(max(x0+1,0),W_-1);
  const unsigned short* tb = T + ((size_t)b*HW_)*C_ + c0;
  uint4 q00 = *(const uint4*)(tb + ((size_t)y0c*W_+x0c)*C_);
  uint4 q01 = *(const uint4*)(tb + ((size_t)y0c*W_+x1c)*C_);
  uint4 q10 = *(const uint4*)(tb + ((size_t)y1c*W_+x0c)*C_);
  uint4 q11 = *(const uint4*)(tb + ((size_t)y1c*W_+x1c)*C_);
  float w00=(1.f-fy)*(1.f-fx), w01=(1.f-fy)*fx, w10=fy*(1.f-fx), w11=fy*fx;
  float o[8];
  o[0]=w00*bfl(q00.x)+w01*bfl(q01.x)+w10*bfl(q10.x)+w11*bfl(q11.x);
  o[1]=w00*bfh(q00.x)+w01*bfh(q01.x)+w10*bfh(q10.x)+w11*bfh(q11.x);
  o[2]=w00*bfl(q00.y)+w01*bfl(q01.y)+w10*bfl(q10.y)+w11*bfl(q11.y);
  o[3]=w00*bfh(q00.y)+w01*bfh(q01.y)+w10*bfh(q10.y)+w11*bfh(q11.y);
  o[4]=w00*bfl(q00.z)+w01*bfl(q01.z)+w10*bfl(q10.z)+w11*bfl(q11.z);
  o[5]=w00*bfh(q00.z)+w01*bfh(q01.z)+w10*bfh(q10.z)+w11*bfh(q11.z);
  o[6]=w00*bfl(q00.w)+w01*bfl(q01.w)+w10*bfl(q10.w)+w11*bfl(q11.w);
  o[7]=w00*bfh(q00.w)+w01*bfh(q01.w)+w10*bfh(q10.w)+w11*bfh(q11.w);
  uint4 ov;
  ov.x = pk(o[0],o[1]); ov.y = pk(o[2],o[3]); ov.z = pk(o[4],o[5]); ov.w = pk(o[6],o[7]);
  *(uint4*)(U + (size_t)opix*C_ + c0) = ov;
}

// implicit-GEMM 3x3 conv (TM=64, BK=128) + fused bias + row-LN + GELU -> d_out fp32
// 32 MFMA per K-iter, 18 iters. grid 512.  (R7 measured: 50.4 vs 54.3 µs)
__global__ __launch_bounds__(256) void k_upconv_ln(
    const unsigned short* __restrict__ U, const unsigned short* __restrict__ Wt,  // Wt[128][2304]
    float* __restrict__ Out, const float* __restrict__ bias,
    const float* __restrict__ g, const float* __restrict__ bb)
{
  constexpr int LD = 136;   // 128 + 8 pad
  __shared__ unsigned short As[64*LD];
  __shared__ unsigned short Bs[128*LD];
  __shared__ float rs[64][2], rq[64][2];
  const int tid = threadIdx.x;
  const int wave = tid >> 6, lane = tid & 63;
  const int m0 = blockIdx.x * 64;
  const int wm0 = (wave >> 1) * 32;
  const int wn0 = (wave & 1) * 64;
  const int lm = lane & 15, kq = lane >> 4;
  f32x4 acc[2][4] = {};
  const int r0 = tid >> 2, cA0 = (tid & 3) << 5;
  const int ma = m0 + r0;
  const int ba = ma >> 14, oya = (ma >> 7) & 127, oxa = ma & 127;

  for (int k0 = 0; k0 < KUP_; k0 += 128){
    int tap = k0 >> 8, cc0 = k0 & 255;
    int dy = tap/3 - 1, dx = tap%3 - 1;
    {
      int iy = oya + dy, ix = oxa + dx;
      bool ok = (iy >= 0 && iy < UH_ && ix >= 0 && ix < UW_);
      const unsigned short* src = U + (((size_t)ba*UH_ + iy)*UW_ + ix)*C_ + cc0 + cA0;
      #pragma unroll
      for (int i=0;i<4;i++){
        short8 v = {};
        if (ok) v = *(const short8*)(src + i*8);
        *(short8*)(As + r0*LD + cA0 + i*8) = v;
      }
    }
    #pragma unroll
    for (int i=0;i<8;i++){
      int ch = tid + 256*i;
      int r = ch >> 4, cc = (ch & 15) << 3;
      short8 v = *(const short8*)(Wt + (size_t)r*KUP_ + k0 + cc);
      *(short8*)(Bs + r*LD + cc) = v;
    }
    __syncthreads();
    short8 af[2][4], bf4[4][4];
    #pragma unroll
    for (int mi=0;mi<2;mi++)
      #pragma unroll
      for (int kk=0;kk<4;kk++)
        af[mi][kk] = *(const short8*)(As + (wm0 + mi*16 + lm)*LD + kk*32 + kq*8);
    #pragma unroll
    for (int ni=0;ni<4;ni++)
      #pragma unroll
      for (int kk=0;kk<4;kk++)
        bf4[ni][kk] = *(const short8*)(Bs + (wn0 + ni*16 + lm)*LD + kk*32 + kq*8);
    #pragma unroll
    for (int kk=0;kk<4;kk++)
      #pragma unroll
      for (int mi=0;mi<2;mi++)
        #pragma unroll
        for (int ni=0;ni<4;ni++)
          acc[mi][ni] = __builtin_amdgcn_mfma_f32_16x16x32_bf16(af[mi][kk], bf4[ni][kk], acc[mi][ni], 0,0,0);
    __syncthreads();
  }
  int nn[4]; float bv[4];
  #pragma unroll
  for (int ni=0;ni<4;ni++){ nn[ni] = wn0 + ni*16 + lm; bv[ni] = bias[nn[ni]]; }
  float ps[2][4] = {}, pq[2][4] = {};
  #pragma unroll
  for (int mi=0;mi<2;mi++)
    #pragma unroll
    for (int r=0;r<4;r++)
      #pragma unroll
      for (int ni=0;ni<4;ni++){
        float v = acc[mi][ni][r] + bv[ni];
        acc[mi][ni][r] = v;
        ps[mi][r] += v; pq[mi][r] += v*v;
      }
  #pragma unroll
  for (int off=1; off<16; off<<=1){
    #pragma unroll
    for (int mi=0;mi<2;mi++)
      #pragma unroll
      for (int r=0;r<4;r++){ ps[mi][r] += __shfl_xor(ps[mi][r], off); pq[mi][r] += __shfl_xor(pq[mi][r], off); }
  }
  if (lm == 0){
    #pragma unroll
    for (int mi=0;mi<2;mi++)
      #pragma unroll
      for (int r=0;r<4;r++){
        rs[wm0 + mi*16 + kq*4 + r][wave & 1] = ps[mi][r];
        rq[wm0 + mi*16 + kq*4 + r][wave & 1] = pq[mi][r];
      }
  }
  __syncthreads();
  float gv[4], pv[4];
  #pragma unroll
  for (int ni=0;ni<4;ni++){ gv[ni] = g[nn[ni]]; pv[ni] = bb[nn[ni]]; }
  #pragma unroll
  for (int mi=0;mi<2;mi++)
    #pragma unroll
    for (int r=0;r<4;r++){
      int row = wm0 + mi*16 + kq*4 + r;
      int m = m0 + row;
      float s = rs[row][0] + rs[row][1];
      float q = rq[row][0] + rq[row][1];
      float mean = s * (1.f/NOUT_), var = q*(1.f/NOUT_) - mean*mean;
      float rstd = rsqrtf(var + 1e-6f);
      #pragma unroll
      for (int ni=0;ni<4;ni++)
        Out[(size_t)m*NOUT_ + nn[ni]] = gelu_f((acc[mi][ni][r]-mean)*rstd*gv[ni] + pv[ni]);
    }
}

extern "C" void kernel_launch(void* const* d_in, const int* in_sizes, int n_in,
                              void* d_out, int out_size, void* d_ws, size_t ws_size,
                              hipStream_t stream)
{
  (void)in_sizes; (void)n_in; (void)out_size; (void)ws_size;
  const float* x_in = (const float*)d_in[0];
  char* w = (char*)d_ws;
  const size_t MB = 1u<<20;
  float* X    = (float*)(w + 0*MB);        // 8 MB residual stream (fp32)
  float* OM   = (float*)(w + 8*MB);        // 13.5 MB (off|msk concat, row=432)
  unsigned short* MIDb = (unsigned short*)(w + 22*MB);  // 16 MB (c1 out; also Ub)
  unsigned short* Ub   = MIDb;
  unsigned short* Tb   = (unsigned short*)(w + 38*MB);  // 4 MB (current LN output)
  unsigned short* Fb   = (unsigned short*)(w + 42*MB);  // 4 MB
  unsigned short* XPb  = (unsigned short*)(w + 46*MB);  // 4 MB
  unsigned short* DW7b = (unsigned short*)(w + 50*MB);  // 4 MB
  unsigned short* Sb   = (unsigned short*)(w + 54*MB);  // 4 MB
  unsigned short* WT   = (unsigned short*)(w + 58*MB);  // 3.7 MB
  float* psum = (float*)(w + 62*MB);
  float* pmax = psum + 65536;
  float* ca   = pmax + 65536;
  float* smean= ca + 512;
  float* smax = smean + 8192;
  float* sa   = smax + 8192;

  unsigned short* WtInp[2], *WtOut[2], *WtOM[2], *WtC1[2], *WtC2[2];
  {
    size_t o = 0;
    for (int i=0;i<2;i++){
      WtInp[i] = WT + o; o += 65536;
      WtOut[i] = WT + o; o += 65536;
      WtOM[i]  = WT + o; o += 110592;
      WtC1[i]  = WT + o; o += 262144;
      WtC2[i]  = WT + o; o += 262144;
    }
  }
  unsigned short* WtUp = WT + 1531904;

  // ---- batched weight prep ----
  WtJobs J;
  {
    int ji = 0, toff = 0;
    auto add = [&](const float* s, unsigned short* d, int Kd, int Nd){
      J.src[ji]=s; J.dst[ji]=d; J.Kd[ji]=Kd; J.Nd[ji]=Nd;
      J.tOff[ji]=toff; toff += (Kd>>5) * ((Nd+31)>>5); ji++;
    };
    for (int i=0;i<2;i++){
      add((const float*)d_in[11] + (size_t)i*C_*C_,   WtInp[i], C_, C_);
      add((const float*)d_in[13] + (size_t)i*C_*C_,   WtOut[i], C_, C_);
      add((const float*)d_in[7]  + (size_t)i*C_*OFFN_, WtOM[i], C_, OFFN_);
      add((const float*)d_in[9]  + (size_t)i*C_*MSKN_, WtOM[i] + (size_t)OFFN_*C_, C_, MSKN_);
      add((const float*)d_in[21] + (size_t)i*C_*C4_,  WtC1[i], C_, C4_);
      add((const float*)d_in[23] + (size_t)i*C4_*C_,  WtC2[i], C4_, C_);
    }
    add((const float*)d_in[33], WtUp, KUP_, NOUT_);
    J.tOff[ji] = toff;
    k_wt_all<<<toff,256,0,stream>>>(J);
  }

  // ---- CBAM + fused LN1 ----
  k_chpool<<<dim3(128,2),256,0,stream>>>(x_in, psum, pmax);
  k_ca<<<1,512,0,stream>>>(psum, pmax, (const float*)d_in[26], (const float*)d_in[27], ca);
  k_apply_ca<<<M_,256,0,stream>>>(x_in, X, ca, smean, smax);
  k_sa<<<M_/256,256,0,stream>>>(smean, smax, (const float*)d_in[28], sa);
  k_mul_ln_ln1<<<M_,256,0,stream>>>(X, sa, (const float*)d_in[29], (const float*)d_in[30],
      (const float*)d_in[1], (const float*)d_in[2], Tb);

  // ---- layers ----
  for (int i=0;i<2;i++){
    const float* dww  = (const float*)d_in[3] + i*9*C_;
    const float* dwb  = (const float*)d_in[4] + i*C_;
    const float* dwng = (const float*)d_in[5] + i*C_;
    const float* dwnb = (const float*)d_in[6] + i*C_;
    const float* offb = (const float*)d_in[8] + i*OFFN_;
    const float* mskb = (const float*)d_in[10] + i*MSKN_;
    const float* inpb = (const float*)d_in[12] + i*C_;
    const float* outb = (const float*)d_in[14] + i*C_;
    const float* ln2g = (const float*)d_in[15] + i*C_;
    const float* ln2b = (const float*)d_in[16] + i*C_;
    const float* dcw  = (const float*)d_in[17] + i*49*C_;
    const float* dcb  = (const float*)d_in[18] + i*C_;
    const float* fng  = (const float*)d_in[19] + i*C_;
    const float* fnb  = (const float*)d_in[20] + i*C_;
    const float* c1b  = (const float*)d_in[22] + i*C4_;
    const float* c2b  = (const float*)d_in[24] + i*C_;
    const float* gam  = (const float*)d_in[25] + i*C_;
    const float* nxg = (i==0) ? (const float*)d_in[1] + C_ : (const float*)d_in[31];
    const float* nxb = (i==0) ? (const float*)d_in[2] + C_ : (const float*)d_in[32];

    // DCNv3 branch (Tb holds ln1 output)
    k_gemm_mfma<64,0,1><<<dim3(M_/64,2),256,0,stream>>>(Tb, WtInp[i], XPb, inpb, nullptr, C_, C_);
    k_dwconv<3,1><<<M_*32/256,256,0,stream>>>(Tb, Fb, dww, dwb, dwng, dwnb);
    k_gemm_mfma<64,4,0><<<dim3(M_/64,4),256,0,stream>>>(Fb, WtOM[i], OM, offb, mskb, OMN_, C_);
    k_dcn<<<M_/16,256,0,stream>>>(XPb, OM, Sb);
    // out-proj + residual + LN2 fused -> X, Tb(ln2)
    k_gemm_ln<2><<<M_/32,512,0,stream>>>(Sb, WtOut[i], X, outb, nullptr, nullptr, Tb, ln2g, ln2b, C_);

    // LEFFN branch (Tb holds ln2 output)
    k_dwconv<7,0><<<M_*32/256,256,0,stream>>>(Tb, DW7b, dcw, dcb, fng, fnb);
    k_gemm_mfma<128,1,1><<<dim3(M_/128,8),256,0,stream>>>(DW7b, WtC1[i], MIDb, c1b, nullptr, C4_, C_);
    // c2 + residuals + gamma + next-LN fused -> X, Tb(next ln)
    k_gemm_ln<3><<<M_/32,512,0,stream>>>(MIDb, WtC2[i], X, c2b, Tb, gam, Tb, nxg, nxb, C4_);
  }

  // ---- upsample + conv(+LN+GELU) -> d_out ----
  k_upsample<<<MUP_*32/256,256,0,stream>>>(Tb, Ub);
  k_upconv_ln<<<MUP_/64,256,0,stream>>>(Ub, WtUp, (float*)d_out, (const float*)d_in[34],
      (const float*)d_in[35], (const float*)d_in[36]);
}

// Round 9
// 519.202 us; speedup vs baseline: 1.0947x; 1.0947x over previous
//
#include <hip/hip_runtime.h>
#include <math.h>

#define B_ 2
#define H_ 64
#define W_ 64
#define C_ 256
#define G_ 16
#define HW_ (H_*W_)          // 4096
#define M_ (B_*HW_)          // 8192
#define C4_ (4*C_)           // 1024
#define OFFN_ 288
#define MSKN_ 144
#define OMN_ 432
#define UH_ 128
#define UW_ 128
#define MUP_ (B_*UH_*UW_)    // 32768
#define KUP_ (9*C_)          // 2304
#define NOUT_ 128

typedef short short8 __attribute__((ext_vector_type(8)));
typedef float f32x4 __attribute__((ext_vector_type(4)));
typedef unsigned short us4 __attribute__((ext_vector_type(4)));

__device__ __forceinline__ float gelu_f(float x){
  return 0.5f * x * (1.f + erff(x * 0.70710678118654752440f));
}
__device__ __forceinline__ float sigmoid_f(float x){ return 1.f/(1.f+expf(-x)); }
__device__ __forceinline__ unsigned short f2bf(float x){
  unsigned int u = __float_as_uint(x);
  unsigned int r = (u + 0x7fffu + ((u>>16)&1u)) >> 16;
  return (unsigned short)r;
}
__device__ __forceinline__ float bf2f(unsigned short u){
  return __uint_as_float(((unsigned int)u) << 16);
}
__device__ __forceinline__ float bfl(unsigned int u){ return __uint_as_float(u<<16); }
__device__ __forceinline__ float bfh(unsigned int u){ return __uint_as_float(u & 0xffff0000u); }
__device__ __forceinline__ unsigned int pk(float a, float b){
  return (unsigned int)f2bf(a) | ((unsigned int)f2bf(b) << 16);
}

__device__ __forceinline__ void block_sum2(float& s, float& ss, float* sm){
  #pragma unroll
  for (int off=32; off>0; off>>=1){ s += __shfl_down(s, off); ss += __shfl_down(ss, off); }
  int lane = threadIdx.x & 63, wid = threadIdx.x >> 6;
  if (lane == 0){ sm[wid] = s; sm[4+wid] = ss; }
  __syncthreads();
  float a = 0.f, b = 0.f;
  int nw = blockDim.x >> 6;
  for (int i=0;i<nw;i++){ a += sm[i]; b += sm[4+i]; }
  s = a; ss = b;
}

__device__ __forceinline__ void block_summax(float& s, float& m, float* sm){
  #pragma unroll
  for (int off=32; off>0; off>>=1){ s += __shfl_down(s, off); m = fmaxf(m, __shfl_down(m, off)); }
  int lane = threadIdx.x & 63, wid = threadIdx.x >> 6;
  if (lane == 0){ sm[wid] = s; sm[4+wid] = m; }
  __syncthreads();
  float a = 0.f, b = -3.4e38f;
  int nw = blockDim.x >> 6;
  for (int i=0;i<nw;i++){ a += sm[i]; b = fmaxf(b, sm[4+i]); }
  s = a; m = b;
}

// ---------------- batched weight prep: W[K][N] fp32 -> Wt[N][K] bf16 ----------------
#define NJOBS 13
struct WtJobs {
  const float* src[NJOBS];
  unsigned short* dst[NJOBS];
  int Kd[NJOBS], Nd[NJOBS];
  int tOff[NJOBS+1];
};

__global__ __launch_bounds__(256) void k_wt_all(WtJobs J){
  __shared__ float tile[32][33];
  int bid = blockIdx.x;
  int j = 0;
  while (bid >= J.tOff[j+1]) j++;
  int lt = bid - J.tOff[j];
  const float* W = J.src[j];
  unsigned short* Wt = J.dst[j];
  int Kd = J.Kd[j], Nd = J.Nd[j];
  int ktiles = Kd >> 5;
  int k0 = (lt % ktiles) * 32, n0 = (lt / ktiles) * 32;
  int t = threadIdx.x;
  int r = t>>3, c4 = (t&7)*4;
  float4 v = make_float4(0.f,0.f,0.f,0.f);
  if (n0 + c4 < Nd) v = *(const float4*)(W + (size_t)(k0+r)*Nd + n0 + c4);
  tile[c4+0][r]=v.x; tile[c4+1][r]=v.y; tile[c4+2][r]=v.z; tile[c4+3][r]=v.w;
  __syncthreads();
  if (n0 + r < Nd){
    us4 o;
    o.x = f2bf(tile[r][c4+0]); o.y = f2bf(tile[r][c4+1]);
    o.z = f2bf(tile[r][c4+2]); o.w = f2bf(tile[r][c4+3]);
    *(us4*)(Wt + (size_t)(n0+r)*Kd + k0 + c4) = o;
  }
}

// ---------------- CBAM ----------------
__global__ __launch_bounds__(256) void k_chpool(const float* __restrict__ Xin,
      float* __restrict__ psum, float* __restrict__ pmax){
  int chunk = blockIdx.x, b = blockIdx.y; int c = threadIdx.x;
  const float* p = Xin + (((size_t)b*HW_) + chunk*32)*C_ + c;
  float s = 0.f, m = -3.4e38f;
  for (int i=0;i<32;i++){ float v = p[(size_t)i*C_]; s += v; m = fmaxf(m, v); }
  psum[(b*128+chunk)*C_+c] = s; pmax[(b*128+chunk)*C_+c] = m;
}

__global__ __launch_bounds__(512) void k_ca(const float* __restrict__ psum, const float* __restrict__ pmax,
    const float* __restrict__ w1, const float* __restrict__ w2, float* __restrict__ ca){
  __shared__ float pm[2][256], px[2][256], hh[2][2][16];
  int t = threadIdx.x;
  {
    int b = t >> 8, c = t & 255;
    float s = 0.f, m = -3.4e38f;
    for (int ch=0; ch<128; ch++){ s += psum[(b*128+ch)*256+c]; m = fmaxf(m, pmax[(b*128+ch)*256+c]); }
    pm[b][c] = s * (1.f/4096.f); px[b][c] = m;
  }
  __syncthreads();
  if (t < 64){
    int b = t >> 5, typ = (t >> 4) & 1, j = t & 15;
    const float* src = typ ? px[b] : pm[b];
    float a = 0.f;
    for (int c2=0;c2<256;c2++) a += src[c2]*w1[c2*16+j];
    hh[b][typ][j] = fmaxf(a, 0.f);
  }
  __syncthreads();
  {
    int b = t >> 8, c = t & 255;
    float a = 0.f;
    for (int j=0;j<16;j++) a += (hh[b][0][j]+hh[b][1][j]) * w2[j*256+c];
    ca[b*256+c] = sigmoid_f(a);
  }
}

__global__ __launch_bounds__(256) void k_apply_ca(const float* __restrict__ Xin, float* __restrict__ X,
    const float* __restrict__ ca, float* __restrict__ smean, float* __restrict__ smax){
  __shared__ float sm[12];
  int pix = blockIdx.x, c = threadIdx.x;
  int b = pix >> 12;
  float v = Xin[(size_t)pix*C_+c] * ca[b*C_+c];
  X[(size_t)pix*C_+c] = v;
  float s = v, m = v;
  block_summax(s, m, sm);
  if (c == 0){ smean[pix] = s * (1.f/C_); smax[pix] = m; }
}

__global__ __launch_bounds__(256) void k_sa(const float* __restrict__ smean, const float* __restrict__ smax,
    const float* __restrict__ w, float* __restrict__ sa){
  int pix = blockIdx.x*256 + threadIdx.x;
  if (pix >= M_) return;
  int b = pix >> 12, hw = pix & 4095, h = hw >> 6, ww = hw & 63;
  float s = 0.f;
  for (int ky=0;ky<7;ky++){
    int hh = h + ky - 3; if (hh < 0 || hh >= H_) continue;
    for (int kx=0;kx<7;kx++){
      int xx = ww + kx - 3; if (xx < 0 || xx >= W_) continue;
      int q = (b<<12) + (hh<<6) + xx;
      s += smean[q]*w[(ky*7+kx)*2+0] + smax[q]*w[(ky*7+kx)*2+1];
    }
  }
  sa[pix] = sigmoid_f(s);
}

// X = LN(X*sa)  (CBAM LN), then Tb = LN1(X) bf16  — two LNs fused
__global__ __launch_bounds__(256) void k_mul_ln_ln1(float* __restrict__ X, const float* __restrict__ sa,
    const float* __restrict__ g, const float* __restrict__ b,
    const float* __restrict__ g1, const float* __restrict__ b1, unsigned short* __restrict__ Tb){
  __shared__ float sm[12];
  int pix = blockIdx.x, c = threadIdx.x;
  float v = X[(size_t)pix*C_+c] * sa[pix];
  float s = v, ss = v*v;
  block_sum2(s, ss, sm);
  float mean = s * (1.f/C_), var = ss*(1.f/C_) - mean*mean;
  float r = rsqrtf(var + 1e-6f);
  float x0 = (v-mean)*r*g[c] + b[c];
  X[(size_t)pix*C_+c] = x0;
  __syncthreads();
  s = x0; ss = x0*x0;
  block_sum2(s, ss, sm);
  mean = s * (1.f/C_); var = ss*(1.f/C_) - mean*mean;
  r = rsqrtf(var + 1e-6f);
  Tb[(size_t)pix*C_+c] = f2bf((x0-mean)*r*g1[c] + b1[c]);
}

// depthwise conv (bf16 in) + bias + LN (+GELU) -> bf16, 8 ch/thread  (R5 proven)
template<int KS, int DOGELU>
__global__ __launch_bounds__(256) void k_dwconv(const unsigned short* __restrict__ T,
    unsigned short* __restrict__ Out,
    const float* __restrict__ w, const float* __restrict__ bias,
    const float* __restrict__ g, const float* __restrict__ bb){
  constexpr int R = KS/2;
  int t = blockIdx.x*256 + threadIdx.x;
  int pix = t >> 5, grp = t & 31;
  int c0 = grp*8;
  int b = pix >> 12, hw = pix & 4095, h = hw >> 6, ww = hw & 63;
  float acc[8];
  {
    float4 b0 = *(const float4*)(bias + c0), b1 = *(const float4*)(bias + c0 + 4);
    acc[0]=b0.x; acc[1]=b0.y; acc[2]=b0.z; acc[3]=b0.w;
    acc[4]=b1.x; acc[5]=b1.y; acc[6]=b1.z; acc[7]=b1.w;
  }
  const unsigned short* tb = T + ((size_t)b*HW_)*C_ + c0;
  for (int ky=0;ky<KS;ky++){
    int hh = h + ky - R; if (hh < 0 || hh >= H_) continue;
    for (int kx=0;kx<KS;kx++){
      int xx = ww + kx - R; if (xx < 0 || xx >= W_) continue;
      uint4 a = *(const uint4*)(tb + ((size_t)hh*W_+xx)*C_);
      const float* wp = w + (ky*KS+kx)*C_ + c0;
      float4 w0 = *(const float4*)wp, w1 = *(const float4*)(wp+4);
      acc[0] += bfl(a.x)*w0.x; acc[1] += bfh(a.x)*w0.y;
      acc[2] += bfl(a.y)*w0.z; acc[3] += bfh(a.y)*w0.w;
      acc[4] += bfl(a.z)*w1.x; acc[5] += bfh(a.z)*w1.y;
      acc[6] += bfl(a.w)*w1.z; acc[7] += bfh(a.w)*w1.w;
    }
  }
  float s = 0.f, ss = 0.f;
  #pragma unroll
  for (int i=0;i<8;i++){ s += acc[i]; ss += acc[i]*acc[i]; }
  #pragma unroll
  for (int off=1; off<32; off<<=1){ s += __shfl_xor(s, off); ss += __shfl_xor(ss, off); }
  float mean = s * (1.f/C_), var = ss*(1.f/C_) - mean*mean;
  float r = rsqrtf(var + 1e-6f);
  float4 g0 = *(const float4*)(g + c0), g1 = *(const float4*)(g + c0 + 4);
  float4 p0 = *(const float4*)(bb + c0), p1 = *(const float4*)(bb + c0 + 4);
  float o[8];
  o[0]=(acc[0]-mean)*r*g0.x+p0.x; o[1]=(acc[1]-mean)*r*g0.y+p0.y;
  o[2]=(acc[2]-mean)*r*g0.z+p0.z; o[3]=(acc[3]-mean)*r*g0.w+p0.w;
  o[4]=(acc[4]-mean)*r*g1.x+p1.x; o[5]=(acc[5]-mean)*r*g1.y+p1.y;
  o[6]=(acc[6]-mean)*r*g1.z+p1.z; o[7]=(acc[7]-mean)*r*g1.w+p1.w;
  if (DOGELU){
    #pragma unroll
    for (int i=0;i<8;i++) o[i] = gelu_f(o[i]);
  }
  uint4 ov;
  ov.x = pk(o[0],o[1]); ov.y = pk(o[2],o[3]); ov.z = pk(o[4],o[5]); ov.w = pk(o[6],o[7]);
  *(uint4*)(Out + (size_t)pix*C_ + c0) = ov;
}

// ---------------- bf16 MFMA GEMM (generic, N-tiled, BK=32)  (R5 proven) ----------------
// EP: 0=bias, 1=bias+gelu, 4=concat-bias (n<288: bias[n], else bias2[n-288])
template<int TM, int EP, int OUTBF>
__global__ __launch_bounds__(256) void k_gemm_mfma(
    const unsigned short* __restrict__ A, const unsigned short* __restrict__ Bt,
    void* __restrict__ OutV, const float* __restrict__ bias,
    const float* __restrict__ bias2, int Ni, int Ki)
{
  constexpr int LD = 40;
  __shared__ unsigned short As[TM*LD];
  __shared__ unsigned short Bs[128*LD];
  const int tid = threadIdx.x;
  const int wave = tid >> 6, lane = tid & 63;
  const int m0 = blockIdx.x * TM, n0 = blockIdx.y * 128;
  const int wm0 = (wave >> 1) * (TM/2);
  const int wn0 = (wave & 1) * 64;
  constexpr int MI = (TM+31)/32;
  f32x4 acc[MI][4] = {};
  const int lm = lane & 15, kq = lane >> 4;

  for (int k0 = 0; k0 < Ki; k0 += 32){
    for (int ch = tid; ch < TM*4; ch += 256){
      int r = ch >> 2, cc = (ch & 3) << 3;
      short8 v = *(const short8*)(A + (size_t)(m0 + r)*Ki + k0 + cc);
      *(short8*)(As + r*LD + cc) = v;
    }
    #pragma unroll
    for (int i=0;i<2;i++){
      int ch = tid + 256*i;
      int r = ch >> 2, cc = (ch & 3) << 3;
      short8 v = {};
      if (n0 + r < Ni) v = *(const short8*)(Bt + (size_t)(n0 + r)*Ki + k0 + cc);
      *(short8*)(Bs + r*LD + cc) = v;
    }
    __syncthreads();
    short8 af[MI], bf[4];
    #pragma unroll
    for (int mi=0;mi<MI;mi++) af[mi] = *(const short8*)(As + (wm0 + mi*16 + lm)*LD + kq*8);
    #pragma unroll
    for (int ni=0;ni<4;ni++)  bf[ni] = *(const short8*)(Bs + (wn0 + ni*16 + lm)*LD + kq*8);
    #pragma unroll
    for (int mi=0;mi<MI;mi++)
      #pragma unroll
      for (int ni=0;ni<4;ni++)
        acc[mi][ni] = __builtin_amdgcn_mfma_f32_16x16x32_bf16(af[mi], bf[ni], acc[mi][ni], 0,0,0);
    __syncthreads();
  }
  #pragma unroll
  for (int mi=0;mi<MI;mi++){
    #pragma unroll
    for (int ni=0;ni<4;ni++){
      int n = n0 + wn0 + ni*16 + lm;
      if (n < Ni){
        float bv;
        if constexpr (EP==4) bv = (n < OFFN_) ? bias[n] : bias2[n-OFFN_];
        else bv = bias[n];
        #pragma unroll
        for (int r=0;r<4;r++){
          int m = m0 + wm0 + mi*16 + kq*4 + r;
          size_t o = (size_t)m*Ni + n;
          float v = acc[mi][ni][r] + bv;
          if constexpr (EP==1) v = gelu_f(v);
          if constexpr (OUTBF) ((unsigned short*)OutV)[o] = f2bf(v);
          else                 ((float*)OutV)[o] = v;
        }
      }
    }
  }
}

// ---------------- GEMM with fused residual + row-LN epilogue (R5 proven) ----------------
// TM=32, N=256 full in-block. block=256 (4 waves: 2 m-halves x 2 n-halves), BK=32.
// EP=2: v = acc+bias+X[o];            X[o]=v; LN(v) -> OutTb bf16
// EP=3: v = X[o]+bf(res2b[o])+gamma[n]*(acc+bias); X[o]=v; LN(v) -> OutTb bf16
template<int EP>
__global__ __launch_bounds__(256) void k_gemm_ln(
    const unsigned short* __restrict__ A, const unsigned short* __restrict__ Bt,
    float* __restrict__ X, const float* __restrict__ bias,
    const unsigned short* __restrict__ res2b, const float* __restrict__ gamma,
    unsigned short* __restrict__ OutTb,
    const float* __restrict__ lng, const float* __restrict__ lnb, int Ki)
{
  constexpr int LD = 40;
  __shared__ unsigned short As[32*LD];
  __shared__ unsigned short Bs[256*LD];
  __shared__ float rs[32][2], rq[32][2];
  const int tid = threadIdx.x;
  const int wave = tid >> 6, lane = tid & 63;
  const int m0 = blockIdx.x * 32;
  const int wm0 = (wave >> 1) * 16;
  const int wn0 = (wave & 1) * 128;
  const int lm = lane & 15, kq = lane >> 4;
  f32x4 acc[8] = {};

  for (int k0 = 0; k0 < Ki; k0 += 32){
    if (tid < 128){
      int r = tid >> 2, cc = (tid & 3) << 3;
      short8 v = *(const short8*)(A + (size_t)(m0 + r)*Ki + k0 + cc);
      *(short8*)(As + r*LD + cc) = v;
    }
    #pragma unroll
    for (int i=0;i<4;i++){
      int ch = tid + 256*i;
      int r = ch >> 2, cc = (ch & 3) << 3;
      short8 v = *(const short8*)(Bt + (size_t)r*Ki + k0 + cc);
      *(short8*)(Bs + r*LD + cc) = v;
    }
    __syncthreads();
    short8 af = *(const short8*)(As + (wm0 + lm)*LD + kq*8);
    short8 bf[8];
    #pragma unroll
    for (int ni=0;ni<8;ni++) bf[ni] = *(const short8*)(Bs + (wn0 + ni*16 + lm)*LD + kq*8);
    #pragma unroll
    for (int ni=0;ni<8;ni++)
      acc[ni] = __builtin_amdgcn_mfma_f32_16x16x32_bf16(af, bf[ni], acc[ni], 0,0,0);
    __syncthreads();
  }
  // epilogue: residual add, write X, row-LN, write OutTb
  int nn[8]; float bv[8], gv[8];
  #pragma unroll
  for (int ni=0;ni<8;ni++){
    nn[ni] = wn0 + ni*16 + lm;
    bv[ni] = bias[nn[ni]];
    if constexpr (EP==3) gv[ni] = gamma[nn[ni]];
  }
  float ps[4] = {}, pq[4] = {};
  #pragma unroll
  for (int r=0;r<4;r++){
    int m = m0 + wm0 + kq*4 + r;
    #pragma unroll
    for (int ni=0;ni<8;ni++){
      size_t o = (size_t)m*C_ + nn[ni];
      float v = acc[ni][r] + bv[ni];
      if constexpr (EP==2) v = X[o] + v;
      if constexpr (EP==3) v = X[o] + bf2f(res2b[o]) + gv[ni]*v;
      X[o] = v;
      acc[ni][r] = v;
      ps[r] += v; pq[r] += v*v;
    }
  }
  #pragma unroll
  for (int off=1; off<16; off<<=1){
    #pragma unroll
    for (int r=0;r<4;r++){ ps[r] += __shfl_xor(ps[r], off); pq[r] += __shfl_xor(pq[r], off); }
  }
  if (lm == 0){
    #pragma unroll
    for (int r=0;r<4;r++){
      rs[wm0 + kq*4 + r][wave & 1] = ps[r];
      rq[wm0 + kq*4 + r][wave & 1] = pq[r];
    }
  }
  __syncthreads();
  float lg[8], lb[8];
  #pragma unroll
  for (int ni=0;ni<8;ni++){ lg[ni] = lng[nn[ni]]; lb[ni] = lnb[nn[ni]]; }
  #pragma unroll
  for (int r=0;r<4;r++){
    int row = wm0 + kq*4 + r;
    int m = m0 + row;
    float s = rs[row][0] + rs[row][1];
    float q = rq[row][0] + rq[row][1];
    float mean = s * (1.f/C_), var = q*(1.f/C_) - mean*mean;
    float rstd = rsqrtf(var + 1e-6f);
    #pragma unroll
    for (int ni=0;ni<8;ni++){
      size_t o = (size_t)m*C_ + nn[ni];
      OutTb[o] = f2bf((acc[ni][r]-mean)*rstd*lg[ni] + lb[ni]);
    }
  }
}

// DCNv3 sampling, thread = (pix, g), 16 ch; OM staged in LDS
__global__ __launch_bounds__(256) void k_dcn(const unsigned short* __restrict__ xp,
    const float* __restrict__ OM, unsigned short* __restrict__ S){
  __shared__ float lom[16*OMN_];
  int pix0 = blockIdx.x * 16;
  {
    const float* gsrc = OM + (size_t)pix0*OMN_;
    for (int idx = threadIdx.x; idx < 16*OMN_; idx += 256) lom[idx] = gsrc[idx];
  }
  __syncthreads();
  int pl = threadIdx.x >> 4, g = threadIdx.x & 15;
  int pix = pix0 + pl;
  int b = pix >> 12, hw = pix & 4095, h = hw >> 6, ww = hw & 63;
  const float* offp = lom + pl*OMN_ + g*18;
  const float* mp   = lom + pl*OMN_ + OFFN_ + g*9;
  const unsigned short* xpb = xp + ((size_t)b*HW_)*C_ + g*16;
  float e[9]; float mx = -3.4e38f;
  #pragma unroll
  for (int k=0;k<9;k++){ e[k] = mp[k]; mx = fmaxf(mx, e[k]); }
  float ssum = 0.f;
  #pragma unroll
  for (int k=0;k<9;k++){ e[k] = expf(e[k]-mx); ssum += e[k]; }
  float rinv = 1.f/ssum;
  float acc[16] = {};
  #pragma unroll
  for (int k=0;k<9;k++){
    float ox = offp[k*2+0], oy = offp[k*2+1];
    float px = (float)(ww + (k%3)) + ox;
    float py = (float)(h  + (k/3)) + oy;
    int x0 = (int)floorf(px), y0 = (int)floorf(py);
    float fx = px - (float)x0, fy = py - (float)y0;
    float mk = e[k]*rinv;
    float w00 = mk*(1.f-fx)*(1.f-fy), w01 = mk*fx*(1.f-fy);
    float w10 = mk*(1.f-fx)*fy,       w11 = mk*fx*fy;
    #define CORNER(yy,xx,WGT) do{ \
      if ((yy)>=1 && (yy)<=H_ && (xx)>=1 && (xx)<=W_){ \
        const unsigned short* p = xpb + ((size_t)((yy)-1)*W_ + ((xx)-1))*C_; \
        uint4 a0 = *(const uint4*)p; uint4 a1 = *(const uint4*)(p+8); \
        acc[0]+=WGT*bfl(a0.x); acc[1]+=WGT*bfh(a0.x); acc[2]+=WGT*bfl(a0.y); acc[3]+=WGT*bfh(a0.y); \
        acc[4]+=WGT*bfl(a0.z); acc[5]+=WGT*bfh(a0.z); acc[6]+=WGT*bfl(a0.w); acc[7]+=WGT*bfh(a0.w); \
        acc[8]+=WGT*bfl(a1.x); acc[9]+=WGT*bfh(a1.x); acc[10]+=WGT*bfl(a1.y); acc[11]+=WGT*bfh(a1.y); \
        acc[12]+=WGT*bfl(a1.z); acc[13]+=WGT*bfh(a1.z); acc[14]+=WGT*bfl(a1.w); acc[15]+=WGT*bfh(a1.w); \
      } \
    }while(0)
    CORNER(y0,   x0,   w00);
    CORNER(y0,   x0+1, w01);
    CORNER(y0+1, x0,   w10);
    CORNER(y0+1, x0+1, w11);
    #undef CORNER
  }
  unsigned short* sp = S + (size_t)pix*C_ + g*16;
  uint4 o0, o1;
  o0.x = pk(acc[0],acc[1]);   o0.y = pk(acc[2],acc[3]);
  o0.z = pk(acc[4],acc[5]);   o0.w = pk(acc[6],acc[7]);
  o1.x = pk(acc[8],acc[9]);   o1.y = pk(acc[10],acc[11]);
  o1.z = pk(acc[12],acc[13]); o1.w = pk(acc[14],acc[15]);
  *(uint4*)sp = o0;
  *(uint4*)(sp+8) = o1;
}

// bilinear 2x upsample (bf16 in) -> bf16, 8 ch/thread
__global__ __launch_bounds__(256) void k_upsample(const unsigned short* __restrict__ T, unsigned short* __restrict__ U){
  int t = blockIdx.x*256 + threadIdx.x;
  int opix = t >> 5, grp = t & 31;
  int c0 = grp*8;
  int ox = opix & 127, oy = (opix >> 7) & 127, b = opix >> 14;
  float sy = oy*0.5f - 0.25f, sx = ox*0.5f - 0.25f;
  int y0 = (int)floorf(sy), x0 = (int)floorf(sx);
  float fy = sy - (float)y0, fx = sx - (float)x0;
  int y0c = min(max(y0,0),H_-1), y1c = min(max(y0+1,0),H_-1);
  int x0c = min(max(x0,0),W_-1), x1c = min(max(x0+1,0),W_-1);
  const unsigned short* tb = T + ((size_t)b*HW_)*C_ + c0;
  uint4 q00 = *(const uint4*)(tb + ((size_t)y0c*W_+x0c)*C_);
  uint4 q01 = *(const uint4*)(tb + ((size_t)y0c*W_+x1c)*C_);
  uint4 q10 = *(const uint4*)(tb + ((size_t)y1c*W_+x0c)*C_);
  uint4 q11 = *(const uint4*)(tb + ((size_t)y1c*W_+x1c)*C_);
  float w00=(1.f-fy)*(1.f-fx), w01=(1.f-fy)*fx, w10=fy*(1.f-fx), w11=fy*fx;
  float o[8];
  o[0]=w00*bfl(q00.x)+w01*bfl(q01.x)+w10*bfl(q10.x)+w11*bfl(q11.x);
  o[1]=w00*bfh(q00.x)+w01*bfh(q01.x)+w10*bfh(q10.x)+w11*bfh(q11.x);
  o[2]=w00*bfl(q00.y)+w01*bfl(q01.y)+w10*bfl(q10.y)+w11*bfl(q11.y);
  o[3]=w00*bfh(q00.y)+w01*bfh(q01.y)+w10*bfh(q10.y)+w11*bfh(q11.y);
  o[4]=w00*bfl(q00.z)+w01*bfl(q01.z)+w10*bfl(q10.z)+w11*bfl(q11.z);
  o[5]=w00*bfh(q00.z)+w01*bfh(q01.z)+w10*bfh(q10.z)+w11*bfh(q11.z);
  o[6]=w00*bfl(q00.w)+w01*bfl(q01.w)+w10*bfl(q10.w)+w11*bfl(q11.w);
  o[7]=w00*bfh(q00.w)+w01*bfh(q01.w)+w10*bfh(q10.w)+w11*bfh(q11.w);
  uint4 ov;
  ov.x = pk(o[0],o[1]); ov.y = pk(o[2],o[3]); ov.z = pk(o[4],o[5]); ov.w = pk(o[6],o[7]);
  *(uint4*)(U + (size_t)opix*C_ + c0) = ov;
}

// implicit-GEMM 3x3 conv (TM=64, BK=128) + fused bias + row-LN + GELU -> d_out fp32
// 32 MFMA per K-iter, 18 iters. grid 512.  (R7 measured best: 50.4 µs)
__global__ __launch_bounds__(256) void k_upconv_ln(
    const unsigned short* __restrict__ U, const unsigned short* __restrict__ Wt,  // Wt[128][2304]
    float* __restrict__ Out, const float* __restrict__ bias,
    const float* __restrict__ g, const float* __restrict__ bb)
{
  constexpr int LD = 136;   // 128 + 8 pad
  __shared__ unsigned short As[64*LD];
  __shared__ unsigned short Bs[128*LD];
  __shared__ float rs[64][2], rq[64][2];
  const int tid = threadIdx.x;
  const int wave = tid >> 6, lane = tid & 63;
  const int m0 = blockIdx.x * 64;
  const int wm0 = (wave >> 1) * 32;
  const int wn0 = (wave & 1) * 64;
  const int lm = lane & 15, kq = lane >> 4;
  f32x4 acc[2][4] = {};
  const int r0 = tid >> 2, cA0 = (tid & 3) << 5;
  const int ma = m0 + r0;
  const int ba = ma >> 14, oya = (ma >> 7) & 127, oxa = ma & 127;

  for (int k0 = 0; k0 < KUP_; k0 += 128){
    int tap = k0 >> 8, cc0 = k0 & 255;
    int dy = tap/3 - 1, dx = tap%3 - 1;
    {
      int iy = oya + dy, ix = oxa + dx;
      bool ok = (iy >= 0 && iy < UH_ && ix >= 0 && ix < UW_);
      const unsigned short* src = U + (((size_t)ba*UH_ + iy)*UW_ + ix)*C_ + cc0 + cA0;
      #pragma unroll
      for (int i=0;i<4;i++){
        short8 v = {};
        if (ok) v = *(const short8*)(src + i*8);
        *(short8*)(As + r0*LD + cA0 + i*8) = v;
      }
    }
    #pragma unroll
    for (int i=0;i<8;i++){
      int ch = tid + 256*i;
      int r = ch >> 4, cc = (ch & 15) << 3;
      short8 v = *(const short8*)(Wt + (size_t)r*KUP_ + k0 + cc);
      *(short8*)(Bs + r*LD + cc) = v;
    }
    __syncthreads();
    short8 af[2][4], bf4[4][4];
    #pragma unroll
    for (int mi=0;mi<2;mi++)
      #pragma unroll
      for (int kk=0;kk<4;kk++)
        af[mi][kk] = *(const short8*)(As + (wm0 + mi*16 + lm)*LD + kk*32 + kq*8);
    #pragma unroll
    for (int ni=0;ni<4;ni++)
      #pragma unroll
      for (int kk=0;kk<4;kk++)
        bf4[ni][kk] = *(const short8*)(Bs + (wn0 + ni*16 + lm)*LD + kk*32 + kq*8);
    #pragma unroll
    for (int kk=0;kk<4;kk++)
      #pragma unroll
      for (int mi=0;mi<2;mi++)
        #pragma unroll
        for (int ni=0;ni<4;ni++)
          acc[mi][ni] = __builtin_amdgcn_mfma_f32_16x16x32_bf16(af[mi][kk], bf4[ni][kk], acc[mi][ni], 0,0,0);
    __syncthreads();
  }
  int nn[4]; float bv[4];
  #pragma unroll
  for (int ni=0;ni<4;ni++){ nn[ni] = wn0 + ni*16 + lm; bv[ni] = bias[nn[ni]]; }
  float ps[2][4] = {}, pq[2][4] = {};
  #pragma unroll
  for (int mi=0;mi<2;mi++)
    #pragma unroll
    for (int r=0;r<4;r++)
      #pragma unroll
      for (int ni=0;ni<4;ni++){
        float v = acc[mi][ni][r] + bv[ni];
        acc[mi][ni][r] = v;
        ps[mi][r] += v; pq[mi][r] += v*v;
      }
  #pragma unroll
  for (int off=1; off<16; off<<=1){
    #pragma unroll
    for (int mi=0;mi<2;mi++)
      #pragma unroll
      for (int r=0;r<4;r++){ ps[mi][r] += __shfl_xor(ps[mi][r], off); pq[mi][r] += __shfl_xor(pq[mi][r], off); }
  }
  if (lm == 0){
    #pragma unroll
    for (int mi=0;mi<2;mi++)
      #pragma unroll
      for (int r=0;r<4;r++){
        rs[wm0 + mi*16 + kq*4 + r][wave & 1] = ps[mi][r];
        rq[wm0 + mi*16 + kq*4 + r][wave & 1] = pq[mi][r];
      }
  }
  __syncthreads();
  float gv[4], pv[4];
  #pragma unroll
  for (int ni=0;ni<4;ni++){ gv[ni] = g[nn[ni]]; pv[ni] = bb[nn[ni]]; }
  #pragma unroll
  for (int mi=0;mi<2;mi++)
    #pragma unroll
    for (int r=0;r<4;r++){
      int row = wm0 + mi*16 + kq*4 + r;
      int m = m0 + row;
      float s = rs[row][0] + rs[row][1];
      float q = rq[row][0] + rq[row][1];
      float mean = s * (1.f/NOUT_), var = q*(1.f/NOUT_) - mean*mean;
      float rstd = rsqrtf(var + 1e-6f);
      #pragma unroll
      for (int ni=0;ni<4;ni++)
        Out[(size_t)m*NOUT_ + nn[ni]] = gelu_f((acc[mi][ni][r]-mean)*rstd*gv[ni] + pv[ni]);
    }
}

extern "C" void kernel_launch(void* const* d_in, const int* in_sizes, int n_in,
                              void* d_out, int out_size, void* d_ws, size_t ws_size,
                              hipStream_t stream)
{
  (void)in_sizes; (void)n_in; (void)out_size; (void)ws_size;
  const float* x_in = (const float*)d_in[0];
  char* w = (char*)d_ws;
  const size_t MB = 1u<<20;
  float* X    = (float*)(w + 0*MB);        // 8 MB residual stream (fp32)
  float* OM   = (float*)(w + 8*MB);        // 13.5 MB (off|msk concat, row=432)
  unsigned short* MIDb = (unsigned short*)(w + 22*MB);  // 16 MB (c1 out; also Ub)
  unsigned short* Ub   = MIDb;
  unsigned short* Tb   = (unsigned short*)(w + 38*MB);  // 4 MB (current LN output)
  unsigned short* Fb   = (unsigned short*)(w + 42*MB);  // 4 MB
  unsigned short* XPb  = (unsigned short*)(w + 46*MB);  // 4 MB
  unsigned short* DW7b = (unsigned short*)(w + 50*MB);  // 4 MB
  unsigned short* Sb   = (unsigned short*)(w + 54*MB);  // 4 MB
  unsigned short* WT   = (unsigned short*)(w + 58*MB);  // 3.7 MB
  float* psum = (float*)(w + 62*MB);
  float* pmax = psum + 65536;
  float* ca   = pmax + 65536;
  float* smean= ca + 512;
  float* smax = smean + 8192;
  float* sa   = smax + 8192;

  unsigned short* WtInp[2], *WtOut[2], *WtOM[2], *WtC1[2], *WtC2[2];
  {
    size_t o = 0;
    for (int i=0;i<2;i++){
      WtInp[i] = WT + o; o += 65536;
      WtOut[i] = WT + o; o += 65536;
      WtOM[i]  = WT + o; o += 110592;
      WtC1[i]  = WT + o; o += 262144;
      WtC2[i]  = WT + o; o += 262144;
    }
  }
  unsigned short* WtUp = WT + 1531904;

  // ---- batched weight prep ----
  WtJobs J;
  {
    int ji = 0, toff = 0;
    auto add = [&](const float* s, unsigned short* d, int Kd, int Nd){
      J.src[ji]=s; J.dst[ji]=d; J.Kd[ji]=Kd; J.Nd[ji]=Nd;
      J.tOff[ji]=toff; toff += (Kd>>5) * ((Nd+31)>>5); ji++;
    };
    for (int i=0;i<2;i++){
      add((const float*)d_in[11] + (size_t)i*C_*C_,   WtInp[i], C_, C_);
      add((const float*)d_in[13] + (size_t)i*C_*C_,   WtOut[i], C_, C_);
      add((const float*)d_in[7]  + (size_t)i*C_*OFFN_, WtOM[i], C_, OFFN_);
      add((const float*)d_in[9]  + (size_t)i*C_*MSKN_, WtOM[i] + (size_t)OFFN_*C_, C_, MSKN_);
      add((const float*)d_in[21] + (size_t)i*C_*C4_,  WtC1[i], C_, C4_);
      add((const float*)d_in[23] + (size_t)i*C4_*C_,  WtC2[i], C4_, C_);
    }
    add((const float*)d_in[33], WtUp, KUP_, NOUT_);
    J.tOff[ji] = toff;
    k_wt_all<<<toff,256,0,stream>>>(J);
  }

  // ---- CBAM + fused LN1 ----
  k_chpool<<<dim3(128,2),256,0,stream>>>(x_in, psum, pmax);
  k_ca<<<1,512,0,stream>>>(psum, pmax, (const float*)d_in[26], (const float*)d_in[27], ca);
  k_apply_ca<<<M_,256,0,stream>>>(x_in, X, ca, smean, smax);
  k_sa<<<M_/256,256,0,stream>>>(smean, smax, (const float*)d_in[28], sa);
  k_mul_ln_ln1<<<M_,256,0,stream>>>(X, sa, (const float*)d_in[29], (const float*)d_in[30],
      (const float*)d_in[1], (const float*)d_in[2], Tb);

  // ---- layers ----
  for (int i=0;i<2;i++){
    const float* dww  = (const float*)d_in[3] + i*9*C_;
    const float* dwb  = (const float*)d_in[4] + i*C_;
    const float* dwng = (const float*)d_in[5] + i*C_;
    const float* dwnb = (const float*)d_in[6] + i*C_;
    const float* offb = (const float*)d_in[8] + i*OFFN_;
    const float* mskb = (const float*)d_in[10] + i*MSKN_;
    const float* inpb = (const float*)d_in[12] + i*C_;
    const float* outb = (const float*)d_in[14] + i*C_;
    const float* ln2g = (const float*)d_in[15] + i*C_;
    const float* ln2b = (const float*)d_in[16] + i*C_;
    const float* dcw  = (const float*)d_in[17] + i*49*C_;
    const float* dcb  = (const float*)d_in[18] + i*C_;
    const float* fng  = (const float*)d_in[19] + i*C_;
    const float* fnb  = (const float*)d_in[20] + i*C_;
    const float* c1b  = (const float*)d_in[22] + i*C4_;
    const float* c2b  = (const float*)d_in[24] + i*C_;
    const float* gam  = (const float*)d_in[25] + i*C_;
    const float* nxg = (i==0) ? (const float*)d_in[1] + C_ : (const float*)d_in[31];
    const float* nxb = (i==0) ? (const float*)d_in[2] + C_ : (const float*)d_in[32];

    // DCNv3 branch (Tb holds ln1 output)
    k_gemm_mfma<64,0,1><<<dim3(M_/64,2),256,0,stream>>>(Tb, WtInp[i], XPb, inpb, nullptr, C_, C_);
    k_dwconv<3,1><<<M_*32/256,256,0,stream>>>(Tb, Fb, dww, dwb, dwng, dwnb);
    k_gemm_mfma<64,4,0><<<dim3(M_/64,4),256,0,stream>>>(Fb, WtOM[i], OM, offb, mskb, OMN_, C_);
    k_dcn<<<M_/16,256,0,stream>>>(XPb, OM, Sb);
    // out-proj + residual + LN2 fused -> X, Tb(ln2)
    k_gemm_ln<2><<<M_/32,256,0,stream>>>(Sb, WtOut[i], X, outb, nullptr, nullptr, Tb, ln2g, ln2b, C_);

    // LEFFN branch (Tb holds ln2 output)
    k_dwconv<7,0><<<M_*32/256,256,0,stream>>>(Tb, DW7b, dcw, dcb, fng, fnb);
    k_gemm_mfma<128,1,1><<<dim3(M_/128,8),256,0,stream>>>(DW7b, WtC1[i], MIDb, c1b, nullptr, C4_, C_);
    // c2 + residuals + gamma + next-LN fused -> X, Tb(next ln)
    k_gemm_ln<3><<<M_/32,256,0,stream>>>(MIDb, WtC2[i], X, c2b, Tb, gam, Tb, nxg, nxb, C4_);
  }

  // ---- upsample + conv(+LN+GELU) -> d_out ----
  k_upsample<<<MUP_*32/256,256,0,stream>>>(Tb, Ub);
  k_upconv_ln<<<MUP_/64,256,0,stream>>>(Ub, WtUp, (float*)d_out, (const float*)d_in[34],
      (const float*)d_in[35], (const float*)d_in[36]);
}

// Round 10
// 512.445 us; speedup vs baseline: 1.1091x; 1.0132x over previous
//
#include <hip/hip_runtime.h>
#include <math.h>

#define B_ 2
#define H_ 64
#define W_ 64
#define C_ 256
#define G_ 16
#define HW_ (H_*W_)          // 4096
#define M_ (B_*HW_)          // 8192
#define C4_ (4*C_)           // 1024
#define OFFN_ 288
#define MSKN_ 144
#define OMN_ 432
#define UH_ 128
#define UW_ 128
#define MUP_ (B_*UH_*UW_)    // 32768
#define KUP_ (9*C_)          // 2304
#define NOUT_ 128

typedef short short8 __attribute__((ext_vector_type(8)));
typedef float f32x4 __attribute__((ext_vector_type(4)));
typedef unsigned short us4 __attribute__((ext_vector_type(4)));

__device__ __forceinline__ float gelu_f(float x){
  return 0.5f * x * (1.f + erff(x * 0.70710678118654752440f));
}
__device__ __forceinline__ float sigmoid_f(float x){ return 1.f/(1.f+expf(-x)); }
__device__ __forceinline__ unsigned short f2bf(float x){
  unsigned int u = __float_as_uint(x);
  unsigned int r = (u + 0x7fffu + ((u>>16)&1u)) >> 16;
  return (unsigned short)r;
}
__device__ __forceinline__ float bf2f(unsigned short u){
  return __uint_as_float(((unsigned int)u) << 16);
}
__device__ __forceinline__ float bfl(unsigned int u){ return __uint_as_float(u<<16); }
__device__ __forceinline__ float bfh(unsigned int u){ return __uint_as_float(u & 0xffff0000u); }
__device__ __forceinline__ unsigned int pk(float a, float b){
  return (unsigned int)f2bf(a) | ((unsigned int)f2bf(b) << 16);
}

__device__ __forceinline__ void block_sum2(float& s, float& ss, float* sm){
  #pragma unroll
  for (int off=32; off>0; off>>=1){ s += __shfl_down(s, off); ss += __shfl_down(ss, off); }
  int lane = threadIdx.x & 63, wid = threadIdx.x >> 6;
  if (lane == 0){ sm[wid] = s; sm[4+wid] = ss; }
  __syncthreads();
  float a = 0.f, b = 0.f;
  int nw = blockDim.x >> 6;
  for (int i=0;i<nw;i++){ a += sm[i]; b += sm[4+i]; }
  s = a; ss = b;
}

__device__ __forceinline__ void block_summax(float& s, float& m, float* sm){
  #pragma unroll
  for (int off=32; off>0; off>>=1){ s += __shfl_down(s, off); m = fmaxf(m, __shfl_down(m, off)); }
  int lane = threadIdx.x & 63, wid = threadIdx.x >> 6;
  if (lane == 0){ sm[wid] = s; sm[4+wid] = m; }
  __syncthreads();
  float a = 0.f, b = -3.4e38f;
  int nw = blockDim.x >> 6;
  for (int i=0;i<nw;i++){ a += sm[i]; b = fmaxf(b, sm[4+i]); }
  s = a; m = b;
}

// ---------------- fused: batched weight prep + CBAM channel pool ----------------
#define NJOBS 13
struct WtJobs {
  const float* src[NJOBS];
  unsigned short* dst[NJOBS];
  int Kd[NJOBS], Nd[NJOBS];
  int tOff[NJOBS+1];
};

__global__ __launch_bounds__(256) void k_wt_pool(WtJobs J, const float* __restrict__ Xin,
    float* __restrict__ psum, float* __restrict__ pmax){
  __shared__ float tile[32][33];
  int bid = blockIdx.x;
  int nwt = J.tOff[NJOBS];
  if (bid >= nwt){
    // chpool: 256 blocks, 32 pixels per block
    int lb = bid - nwt;
    int chunk = lb & 127, b = lb >> 7; int c = threadIdx.x;
    const float* p = Xin + (((size_t)b*HW_) + chunk*32)*C_ + c;
    float s = 0.f, m = -3.4e38f;
    for (int i=0;i<32;i++){ float v = p[(size_t)i*C_]; s += v; m = fmaxf(m, v); }
    psum[(b*128+chunk)*C_+c] = s; pmax[(b*128+chunk)*C_+c] = m;
    return;
  }
  int j = 0;
  while (bid >= J.tOff[j+1]) j++;
  int lt = bid - J.tOff[j];
  const float* W = J.src[j];
  unsigned short* Wt = J.dst[j];
  int Kd = J.Kd[j], Nd = J.Nd[j];
  int ktiles = Kd >> 5;
  int k0 = (lt % ktiles) * 32, n0 = (lt / ktiles) * 32;
  int t = threadIdx.x;
  int r = t>>3, c4 = (t&7)*4;
  float4 v = make_float4(0.f,0.f,0.f,0.f);
  if (n0 + c4 < Nd) v = *(const float4*)(W + (size_t)(k0+r)*Nd + n0 + c4);
  tile[c4+0][r]=v.x; tile[c4+1][r]=v.y; tile[c4+2][r]=v.z; tile[c4+3][r]=v.w;
  __syncthreads();
  if (n0 + r < Nd){
    us4 o;
    o.x = f2bf(tile[r][c4+0]); o.y = f2bf(tile[r][c4+1]);
    o.z = f2bf(tile[r][c4+2]); o.w = f2bf(tile[r][c4+3]);
    *(us4*)(Wt + (size_t)(n0+r)*Kd + k0 + c4) = o;
  }
}

// ---------------- CBAM ----------------
__global__ __launch_bounds__(512) void k_ca(const float* __restrict__ psum, const float* __restrict__ pmax,
    const float* __restrict__ w1, const float* __restrict__ w2, float* __restrict__ ca){
  __shared__ float pm[2][256], px[2][256], hh[2][2][16];
  int t = threadIdx.x;
  {
    int b = t >> 8, c = t & 255;
    float s = 0.f, m = -3.4e38f;
    for (int ch=0; ch<128; ch++){ s += psum[(b*128+ch)*256+c]; m = fmaxf(m, pmax[(b*128+ch)*256+c]); }
    pm[b][c] = s * (1.f/4096.f); px[b][c] = m;
  }
  __syncthreads();
  if (t < 64){
    int b = t >> 5, typ = (t >> 4) & 1, j = t & 15;
    const float* src = typ ? px[b] : pm[b];
    float a = 0.f;
    for (int c2=0;c2<256;c2++) a += src[c2]*w1[c2*16+j];
    hh[b][typ][j] = fmaxf(a, 0.f);
  }
  __syncthreads();
  {
    int b = t >> 8, c = t & 255;
    float a = 0.f;
    for (int j=0;j<16;j++) a += (hh[b][0][j]+hh[b][1][j]) * w2[j*256+c];
    ca[b*256+c] = sigmoid_f(a);
  }
}

__global__ __launch_bounds__(256) void k_apply_ca(const float* __restrict__ Xin, float* __restrict__ X,
    const float* __restrict__ ca, float* __restrict__ smean, float* __restrict__ smax){
  __shared__ float sm[12];
  int pix = blockIdx.x, c = threadIdx.x;
  int b = pix >> 12;
  float v = Xin[(size_t)pix*C_+c] * ca[b*C_+c];
  X[(size_t)pix*C_+c] = v;
  float s = v, m = v;
  block_summax(s, m, sm);
  if (c == 0){ smean[pix] = s * (1.f/C_); smax[pix] = m; }
}

__global__ __launch_bounds__(256) void k_sa(const float* __restrict__ smean, const float* __restrict__ smax,
    const float* __restrict__ w, float* __restrict__ sa){
  int pix = blockIdx.x*256 + threadIdx.x;
  if (pix >= M_) return;
  int b = pix >> 12, hw = pix & 4095, h = hw >> 6, ww = hw & 63;
  float s = 0.f;
  for (int ky=0;ky<7;ky++){
    int hh = h + ky - 3; if (hh < 0 || hh >= H_) continue;
    for (int kx=0;kx<7;kx++){
      int xx = ww + kx - 3; if (xx < 0 || xx >= W_) continue;
      int q = (b<<12) + (hh<<6) + xx;
      s += smean[q]*w[(ky*7+kx)*2+0] + smax[q]*w[(ky*7+kx)*2+1];
    }
  }
  sa[pix] = sigmoid_f(s);
}

// X = LN(X*sa)  (CBAM LN), then Tb = LN1(X) bf16
__global__ __launch_bounds__(256) void k_mul_ln_ln1(float* __restrict__ X, const float* __restrict__ sa,
    const float* __restrict__ g, const float* __restrict__ b,
    const float* __restrict__ g1, const float* __restrict__ b1, unsigned short* __restrict__ Tb){
  __shared__ float sm[12];
  int pix = blockIdx.x, c = threadIdx.x;
  float v = X[(size_t)pix*C_+c] * sa[pix];
  float s = v, ss = v*v;
  block_sum2(s, ss, sm);
  float mean = s * (1.f/C_), var = ss*(1.f/C_) - mean*mean;
  float r = rsqrtf(var + 1e-6f);
  float x0 = (v-mean)*r*g[c] + b[c];
  X[(size_t)pix*C_+c] = x0;
  __syncthreads();
  s = x0; ss = x0*x0;
  block_sum2(s, ss, sm);
  mean = s * (1.f/C_); var = ss*(1.f/C_) - mean*mean;
  r = rsqrtf(var + 1e-6f);
  Tb[(size_t)pix*C_+c] = f2bf((x0-mean)*r*g1[c] + b1[c]);
}

// dwconv body (shared by fused + standalone kernels)
template<int KS, int DOGELU>
__device__ __forceinline__ void dwconv_body(int t, const unsigned short* __restrict__ T,
    unsigned short* __restrict__ Out,
    const float* __restrict__ w, const float* __restrict__ bias,
    const float* __restrict__ g, const float* __restrict__ bb){
  constexpr int R = KS/2;
  int pix = t >> 5, grp = t & 31;
  int c0 = grp*8;
  int b = pix >> 12, hw = pix & 4095, h = hw >> 6, ww = hw & 63;
  float acc[8];
  {
    float4 b0 = *(const float4*)(bias + c0), b1 = *(const float4*)(bias + c0 + 4);
    acc[0]=b0.x; acc[1]=b0.y; acc[2]=b0.z; acc[3]=b0.w;
    acc[4]=b1.x; acc[5]=b1.y; acc[6]=b1.z; acc[7]=b1.w;
  }
  const unsigned short* tb = T + ((size_t)b*HW_)*C_ + c0;
  for (int ky=0;ky<KS;ky++){
    int hh = h + ky - R; if (hh < 0 || hh >= H_) continue;
    for (int kx=0;kx<KS;kx++){
      int xx = ww + kx - R; if (xx < 0 || xx >= W_) continue;
      uint4 a = *(const uint4*)(tb + ((size_t)hh*W_+xx)*C_);
      const float* wp = w + (ky*KS+kx)*C_ + c0;
      float4 w0 = *(const float4*)wp, w1 = *(const float4*)(wp+4);
      acc[0] += bfl(a.x)*w0.x; acc[1] += bfh(a.x)*w0.y;
      acc[2] += bfl(a.y)*w0.z; acc[3] += bfh(a.y)*w0.w;
      acc[4] += bfl(a.z)*w1.x; acc[5] += bfh(a.z)*w1.y;
      acc[6] += bfl(a.w)*w1.z; acc[7] += bfh(a.w)*w1.w;
    }
  }
  float s = 0.f, ss = 0.f;
  #pragma unroll
  for (int i=0;i<8;i++){ s += acc[i]; ss += acc[i]*acc[i]; }
  #pragma unroll
  for (int off=1; off<32; off<<=1){ s += __shfl_xor(s, off); ss += __shfl_xor(ss, off); }
  float mean = s * (1.f/C_), var = ss*(1.f/C_) - mean*mean;
  float r = rsqrtf(var + 1e-6f);
  float4 g0 = *(const float4*)(g + c0), g1 = *(const float4*)(g + c0 + 4);
  float4 p0 = *(const float4*)(bb + c0), p1 = *(const float4*)(bb + c0 + 4);
  float o[8];
  o[0]=(acc[0]-mean)*r*g0.x+p0.x; o[1]=(acc[1]-mean)*r*g0.y+p0.y;
  o[2]=(acc[2]-mean)*r*g0.z+p0.z; o[3]=(acc[3]-mean)*r*g0.w+p0.w;
  o[4]=(acc[4]-mean)*r*g1.x+p1.x; o[5]=(acc[5]-mean)*r*g1.y+p1.y;
  o[6]=(acc[6]-mean)*r*g1.z+p1.z; o[7]=(acc[7]-mean)*r*g1.w+p1.w;
  if (DOGELU){
    #pragma unroll
    for (int i=0;i<8;i++) o[i] = gelu_f(o[i]);
  }
  uint4 ov;
  ov.x = pk(o[0],o[1]); ov.y = pk(o[2],o[3]); ov.z = pk(o[4],o[5]); ov.w = pk(o[6],o[7]);
  *(uint4*)(Out + (size_t)pix*C_ + c0) = ov;
}

// standalone dw7
__global__ __launch_bounds__(256) void k_dw7(const unsigned short* __restrict__ T,
    unsigned short* __restrict__ Out,
    const float* __restrict__ w, const float* __restrict__ bias,
    const float* __restrict__ g, const float* __restrict__ bb){
  dwconv_body<7,0>(blockIdx.x*256 + threadIdx.x, T, Out, w, bias, g, bb);
}

// ---------------- fused: inp-proj GEMM (blocks 0..255) + dw3 (blocks 256..1279) ----------------
// GEMM: XPb[M,256] = Tb[M,256] @ WtInp^T + inpb, bf16 out. TM=64, BK=32, grid part (128 m) x (2 n).
__global__ __launch_bounds__(256) void k_inp_dw3(
    const unsigned short* __restrict__ Tb, const unsigned short* __restrict__ Bt,
    unsigned short* __restrict__ XPb, const float* __restrict__ inpb,
    unsigned short* __restrict__ Fb,
    const float* __restrict__ dww, const float* __restrict__ dwb,
    const float* __restrict__ dwng, const float* __restrict__ dwnb)
{
  constexpr int LD = 40;
  __shared__ unsigned short As[64*LD];
  __shared__ unsigned short Bs[128*LD];
  const int bid = blockIdx.x;
  const int tid = threadIdx.x;
  if (bid >= 256){
    dwconv_body<3,1>((bid-256)*256 + tid, Tb, Fb, dww, dwb, dwng, dwnb);
    return;
  }
  const int wave = tid >> 6, lane = tid & 63;
  const int m0 = (bid & 127) * 64, n0 = (bid >> 7) * 128;
  const int wm0 = (wave >> 1) * 32;
  const int wn0 = (wave & 1) * 64;
  f32x4 acc[2][4] = {};
  const int lm = lane & 15, kq = lane >> 4;

  for (int k0 = 0; k0 < C_; k0 += 32){
    {
      int r = tid >> 2, cc = (tid & 3) << 3;
      short8 v = *(const short8*)(Tb + (size_t)(m0 + r)*C_ + k0 + cc);
      *(short8*)(As + r*LD + cc) = v;
    }
    #pragma unroll
    for (int i=0;i<2;i++){
      int ch = tid + 256*i;
      int r = ch >> 2, cc = (ch & 3) << 3;
      short8 v = *(const short8*)(Bt + (size_t)(n0 + r)*C_ + k0 + cc);
      *(short8*)(Bs + r*LD + cc) = v;
    }
    __syncthreads();
    short8 af[2], bf[4];
    #pragma unroll
    for (int mi=0;mi<2;mi++) af[mi] = *(const short8*)(As + (wm0 + mi*16 + lm)*LD + kq*8);
    #pragma unroll
    for (int ni=0;ni<4;ni++)  bf[ni] = *(const short8*)(Bs + (wn0 + ni*16 + lm)*LD + kq*8);
    #pragma unroll
    for (int mi=0;mi<2;mi++)
      #pragma unroll
      for (int ni=0;ni<4;ni++)
        acc[mi][ni] = __builtin_amdgcn_mfma_f32_16x16x32_bf16(af[mi], bf[ni], acc[mi][ni], 0,0,0);
    __syncthreads();
  }
  #pragma unroll
  for (int mi=0;mi<2;mi++){
    #pragma unroll
    for (int ni=0;ni<4;ni++){
      int n = n0 + wn0 + ni*16 + lm;
      float bv = inpb[n];
      #pragma unroll
      for (int r=0;r<4;r++){
        int m = m0 + wm0 + mi*16 + kq*4 + r;
        XPb[(size_t)m*C_ + n] = f2bf(acc[mi][ni][r] + bv);
      }
    }
  }
}

// ---------------- bf16 MFMA GEMM (generic, N-tiled, BK=32) ----------------
// EP: 0=bias, 1=bias+gelu, 4=concat-bias (n<288: bias[n], else bias2[n-288])
template<int TM, int EP, int OUTBF>
__global__ __launch_bounds__(256) void k_gemm_mfma(
    const unsigned short* __restrict__ A, const unsigned short* __restrict__ Bt,
    void* __restrict__ OutV, const float* __restrict__ bias,
    const float* __restrict__ bias2, int Ni, int Ki)
{
  constexpr int LD = 40;
  __shared__ unsigned short As[TM*LD];
  __shared__ unsigned short Bs[128*LD];
  const int tid = threadIdx.x;
  const int wave = tid >> 6, lane = tid & 63;
  const int m0 = blockIdx.x * TM, n0 = blockIdx.y * 128;
  const int wm0 = (wave >> 1) * (TM/2);
  const int wn0 = (wave & 1) * 64;
  constexpr int MI = (TM+31)/32;
  f32x4 acc[MI][4] = {};
  const int lm = lane & 15, kq = lane >> 4;

  for (int k0 = 0; k0 < Ki; k0 += 32){
    for (int ch = tid; ch < TM*4; ch += 256){
      int r = ch >> 2, cc = (ch & 3) << 3;
      short8 v = *(const short8*)(A + (size_t)(m0 + r)*Ki + k0 + cc);
      *(short8*)(As + r*LD + cc) = v;
    }
    #pragma unroll
    for (int i=0;i<2;i++){
      int ch = tid + 256*i;
      int r = ch >> 2, cc = (ch & 3) << 3;
      short8 v = {};
      if (n0 + r < Ni) v = *(const short8*)(Bt + (size_t)(n0 + r)*Ki + k0 + cc);
      *(short8*)(Bs + r*LD + cc) = v;
    }
    __syncthreads();
    short8 af[MI], bf[4];
    #pragma unroll
    for (int mi=0;mi<MI;mi++) af[mi] = *(const short8*)(As + (wm0 + mi*16 + lm)*LD + kq*8);
    #pragma unroll
    for (int ni=0;ni<4;ni++)  bf[ni] = *(const short8*)(Bs + (wn0 + ni*16 + lm)*LD + kq*8);
    #pragma unroll
    for (int mi=0;mi<MI;mi++)
      #pragma unroll
      for (int ni=0;ni<4;ni++)
        acc[mi][ni] = __builtin_amdgcn_mfma_f32_16x16x32_bf16(af[mi], bf[ni], acc[mi][ni], 0,0,0);
    __syncthreads();
  }
  #pragma unroll
  for (int mi=0;mi<MI;mi++){
    #pragma unroll
    for (int ni=0;ni<4;ni++){
      int n = n0 + wn0 + ni*16 + lm;
      if (n < Ni){
        float bv;
        if constexpr (EP==4) bv = (n < OFFN_) ? bias[n] : bias2[n-OFFN_];
        else bv = bias[n];
        #pragma unroll
        for (int r=0;r<4;r++){
          int m = m0 + wm0 + mi*16 + kq*4 + r;
          size_t o = (size_t)m*Ni + n;
          float v = acc[mi][ni][r] + bv;
          if constexpr (EP==1) v = gelu_f(v);
          if constexpr (OUTBF) ((unsigned short*)OutV)[o] = f2bf(v);
          else                 ((float*)OutV)[o] = v;
        }
      }
    }
  }
}

// ---------------- GEMM with fused residual + row-LN epilogue (R5 proven) ----------------
template<int EP>
__global__ __launch_bounds__(256) void k_gemm_ln(
    const unsigned short* __restrict__ A, const unsigned short* __restrict__ Bt,
    float* __restrict__ X, const float* __restrict__ bias,
    const unsigned short* __restrict__ res2b, const float* __restrict__ gamma,
    unsigned short* __restrict__ OutTb,
    const float* __restrict__ lng, const float* __restrict__ lnb, int Ki)
{
  constexpr int LD = 40;
  __shared__ unsigned short As[32*LD];
  __shared__ unsigned short Bs[256*LD];
  __shared__ float rs[32][2], rq[32][2];
  const int tid = threadIdx.x;
  const int wave = tid >> 6, lane = tid & 63;
  const int m0 = blockIdx.x * 32;
  const int wm0 = (wave >> 1) * 16;
  const int wn0 = (wave & 1) * 128;
  const int lm = lane & 15, kq = lane >> 4;
  f32x4 acc[8] = {};

  for (int k0 = 0; k0 < Ki; k0 += 32){
    if (tid < 128){
      int r = tid >> 2, cc = (tid & 3) << 3;
      short8 v = *(const short8*)(A + (size_t)(m0 + r)*Ki + k0 + cc);
      *(short8*)(As + r*LD + cc) = v;
    }
    #pragma unroll
    for (int i=0;i<4;i++){
      int ch = tid + 256*i;
      int r = ch >> 2, cc = (ch & 3) << 3;
      short8 v = *(const short8*)(Bt + (size_t)r*Ki + k0 + cc);
      *(short8*)(Bs + r*LD + cc) = v;
    }
    __syncthreads();
    short8 af = *(const short8*)(As + (wm0 + lm)*LD + kq*8);
    short8 bf[8];
    #pragma unroll
    for (int ni=0;ni<8;ni++) bf[ni] = *(const short8*)(Bs + (wn0 + ni*16 + lm)*LD + kq*8);
    #pragma unroll
    for (int ni=0;ni<8;ni++)
      acc[ni] = __builtin_amdgcn_mfma_f32_16x16x32_bf16(af, bf[ni], acc[ni], 0,0,0);
    __syncthreads();
  }
  int nn[8]; float bv[8], gv[8];
  #pragma unroll
  for (int ni=0;ni<8;ni++){
    nn[ni] = wn0 + ni*16 + lm;
    bv[ni] = bias[nn[ni]];
    if constexpr (EP==3) gv[ni] = gamma[nn[ni]];
  }
  float ps[4] = {}, pq[4] = {};
  #pragma unroll
  for (int r=0;r<4;r++){
    int m = m0 + wm0 + kq*4 + r;
    #pragma unroll
    for (int ni=0;ni<8;ni++){
      size_t o = (size_t)m*C_ + nn[ni];
      float v = acc[ni][r] + bv[ni];
      if constexpr (EP==2) v = X[o] + v;
      if constexpr (EP==3) v = X[o] + bf2f(res2b[o]) + gv[ni]*v;
      X[o] = v;
      acc[ni][r] = v;
      ps[r] += v; pq[r] += v*v;
    }
  }
  #pragma unroll
  for (int off=1; off<16; off<<=1){
    #pragma unroll
    for (int r=0;r<4;r++){ ps[r] += __shfl_xor(ps[r], off); pq[r] += __shfl_xor(pq[r], off); }
  }
  if (lm == 0){
    #pragma unroll
    for (int r=0;r<4;r++){
      rs[wm0 + kq*4 + r][wave & 1] = ps[r];
      rq[wm0 + kq*4 + r][wave & 1] = pq[r];
    }
  }
  __syncthreads();
  float lg[8], lb[8];
  #pragma unroll
  for (int ni=0;ni<8;ni++){ lg[ni] = lng[nn[ni]]; lb[ni] = lnb[nn[ni]]; }
  #pragma unroll
  for (int r=0;r<4;r++){
    int row = wm0 + kq*4 + r;
    int m = m0 + row;
    float s = rs[row][0] + rs[row][1];
    float q = rq[row][0] + rq[row][1];
    float mean = s * (1.f/C_), var = q*(1.f/C_) - mean*mean;
    float rstd = rsqrtf(var + 1e-6f);
    #pragma unroll
    for (int ni=0;ni<8;ni++){
      size_t o = (size_t)m*C_ + nn[ni];
      OutTb[o] = f2bf((acc[ni][r]-mean)*rstd*lg[ni] + lb[ni]);
    }
  }
}

// DCNv3 sampling, thread = (pix, g), 16 ch; OM staged in LDS
__global__ __launch_bounds__(256) void k_dcn(const unsigned short* __restrict__ xp,
    const float* __restrict__ OM, unsigned short* __restrict__ S){
  __shared__ float lom[16*OMN_];
  int pix0 = blockIdx.x * 16;
  {
    const float* gsrc = OM + (size_t)pix0*OMN_;
    for (int idx = threadIdx.x; idx < 16*OMN_; idx += 256) lom[idx] = gsrc[idx];
  }
  __syncthreads();
  int pl = threadIdx.x >> 4, g = threadIdx.x & 15;
  int pix = pix0 + pl;
  int b = pix >> 12, hw = pix & 4095, h = hw >> 6, ww = hw & 63;
  const float* offp = lom + pl*OMN_ + g*18;
  const float* mp   = lom + pl*OMN_ + OFFN_ + g*9;
  const unsigned short* xpb = xp + ((size_t)b*HW_)*C_ + g*16;
  float e[9]; float mx = -3.4e38f;
  #pragma unroll
  for (int k=0;k<9;k++){ e[k] = mp[k]; mx = fmaxf(mx, e[k]); }
  float ssum = 0.f;
  #pragma unroll
  for (int k=0;k<9;k++){ e[k] = expf(e[k]-mx); ssum += e[k]; }
  float rinv = 1.f/ssum;
  float acc[16] = {};
  #pragma unroll
  for (int k=0;k<9;k++){
    float ox = offp[k*2+0], oy = offp[k*2+1];
    float px = (float)(ww + (k%3)) + ox;
    float py = (float)(h  + (k/3)) + oy;
    int x0 = (int)floorf(px), y0 = (int)floorf(py);
    float fx = px - (float)x0, fy = py - (float)y0;
    float mk = e[k]*rinv;
    float w00 = mk*(1.f-fx)*(1.f-fy), w01 = mk*fx*(1.f-fy);
    float w10 = mk*(1.f-fx)*fy,       w11 = mk*fx*fy;
    #define CORNER(yy,xx,WGT) do{ \
      if ((yy)>=1 && (yy)<=H_ && (xx)>=1 && (xx)<=W_){ \
        const unsigned short* p = xpb + ((size_t)((yy)-1)*W_ + ((xx)-1))*C_; \
        uint4 a0 = *(const uint4*)p; uint4 a1 = *(const uint4*)(p+8); \
        acc[0]+=WGT*bfl(a0.x); acc[1]+=WGT*bfh(a0.x); acc[2]+=WGT*bfl(a0.y); acc[3]+=WGT*bfh(a0.y); \
        acc[4]+=WGT*bfl(a0.z); acc[5]+=WGT*bfh(a0.z); acc[6]+=WGT*bfl(a0.w); acc[7]+=WGT*bfh(a0.w); \
        acc[8]+=WGT*bfl(a1.x); acc[9]+=WGT*bfh(a1.x); acc[10]+=WGT*bfl(a1.y); acc[11]+=WGT*bfh(a1.y); \
        acc[12]+=WGT*bfl(a1.z); acc[13]+=WGT*bfh(a1.z); acc[14]+=WGT*bfl(a1.w); acc[15]+=WGT*bfh(a1.w); \
      } \
    }while(0)
    CORNER(y0,   x0,   w00);
    CORNER(y0,   x0+1, w01);
    CORNER(y0+1, x0,   w10);
    CORNER(y0+1, x0+1, w11);
    #undef CORNER
  }
  unsigned short* sp = S + (size_t)pix*C_ + g*16;
  uint4 o0, o1;
  o0.x = pk(acc[0],acc[1]);   o0.y = pk(acc[2],acc[3]);
  o0.z = pk(acc[4],acc[5]);   o0.w = pk(acc[6],acc[7]);
  o1.x = pk(acc[8],acc[9]);   o1.y = pk(acc[10],acc[11]);
  o1.z = pk(acc[12],acc[13]); o1.w = pk(acc[14],acc[15]);
  *(uint4*)sp = o0;
  *(uint4*)(sp+8) = o1;
}

// bilinear 2x upsample (bf16 in) -> bf16, 8 ch/thread
__global__ __launch_bounds__(256) void k_upsample(const unsigned short* __restrict__ T, unsigned short* __restrict__ U){
  int t = blockIdx.x*256 + threadIdx.x;
  int opix = t >> 5, grp = t & 31;
  int c0 = grp*8;
  int ox = opix & 127, oy = (opix >> 7) & 127, b = opix >> 14;
  float sy = oy*0.5f - 0.25f, sx = ox*0.5f - 0.25f;
  int y0 = (int)floorf(sy), x0 = (int)floorf(sx);
  float fy = sy - (float)y0, fx = sx - (float)x0;
  int y0c = min(max(y0,0),H_-1), y1c = min(max(y0+1,0),H_-1);
  int x0c = min(max(x0,0),W_-1), x1c = min(max(x0+1,0),W_-1);
  const unsigned short* tb = T + ((size_t)b*HW_)*C_ + c0;
  uint4 q00 = *(const uint4*)(tb + ((size_t)y0c*W_+x0c)*C_);
  uint4 q01 = *(const uint4*)(tb + ((size_t)y0c*W_+x1c)*C_);
  uint4 q10 = *(const uint4*)(tb + ((size_t)y1c*W_+x0c)*C_);
  uint4 q11 = *(const uint4*)(tb + ((size_t)y1c*W_+x1c)*C_);
  float w00=(1.f-fy)*(1.f-fx), w01=(1.f-fy)*fx, w10=fy*(1.f-fx), w11=fy*fx;
  float o[8];
  o[0]=w00*bfl(q00.x)+w01*bfl(q01.x)+w10*bfl(q10.x)+w11*bfl(q11.x);
  o[1]=w00*bfh(q00.x)+w01*bfh(q01.x)+w10*bfh(q10.x)+w11*bfh(q11.x);
  o[2]=w00*bfl(q00.y)+w01*bfl(q01.y)+w10*bfl(q10.y)+w11*bfl(q11.y);
  o[3]=w00*bfh(q00.y)+w01*bfh(q01.y)+w10*bfh(q10.y)+w11*bfh(q11.y);
  o[4]=w00*bfl(q00.z)+w01*bfl(q01.z)+w10*bfl(q10.z)+w11*bfl(q11.z);
  o[5]=w00*bfh(q00.z)+w01*bfh(q01.z)+w10*bfh(q10.z)+w11*bfh(q11.z);
  o[6]=w00*bfl(q00.w)+w01*bfl(q01.w)+w10*bfl(q10.w)+w11*bfl(q11.w);
  o[7]=w00*bfh(q00.w)+w01*bfh(q01.w)+w10*bfh(q10.w)+w11*bfh(q11.w);
  uint4 ov;
  ov.x = pk(o[0],o[1]); ov.y = pk(o[2],o[3]); ov.z = pk(o[4],o[5]); ov.w = pk(o[6],o[7]);
  *(uint4*)(U + (size_t)opix*C_ + c0) = ov;
}

// implicit-GEMM 3x3 conv (TM=64, BK=128) + fused bias + row-LN + GELU -> d_out fp32
__global__ __launch_bounds__(256) void k_upconv_ln(
    const unsigned short* __restrict__ U, const unsigned short* __restrict__ Wt,
    float* __restrict__ Out, const float* __restrict__ bias,
    const float* __restrict__ g, const float* __restrict__ bb)
{
  constexpr int LD = 136;
  __shared__ unsigned short As[64*LD];
  __shared__ unsigned short Bs[128*LD];
  __shared__ float rs[64][2], rq[64][2];
  const int tid = threadIdx.x;
  const int wave = tid >> 6, lane = tid & 63;
  const int m0 = blockIdx.x * 64;
  const int wm0 = (wave >> 1) * 32;
  const int wn0 = (wave & 1) * 64;
  const int lm = lane & 15, kq = lane >> 4;
  f32x4 acc[2][4] = {};
  const int r0 = tid >> 2, cA0 = (tid & 3) << 5;
  const int ma = m0 + r0;
  const int ba = ma >> 14, oya = (ma >> 7) & 127, oxa = ma & 127;

  for (int k0 = 0; k0 < KUP_; k0 += 128){
    int tap = k0 >> 8, cc0 = k0 & 255;
    int dy = tap/3 - 1, dx = tap%3 - 1;
    {
      int iy = oya + dy, ix = oxa + dx;
      bool ok = (iy >= 0 && iy < UH_ && ix >= 0 && ix < UW_);
      const unsigned short* src = U + (((size_t)ba*UH_ + iy)*UW_ + ix)*C_ + cc0 + cA0;
      #pragma unroll
      for (int i=0;i<4;i++){
        short8 v = {};
        if (ok) v = *(const short8*)(src + i*8);
        *(short8*)(As + r0*LD + cA0 + i*8) = v;
      }
    }
    #pragma unroll
    for (int i=0;i<8;i++){
      int ch = tid + 256*i;
      int r = ch >> 4, cc = (ch & 15) << 3;
      short8 v = *(const short8*)(Wt + (size_t)r*KUP_ + k0 + cc);
      *(short8*)(Bs + r*LD + cc) = v;
    }
    __syncthreads();
    short8 af[2][4], bf4[4][4];
    #pragma unroll
    for (int mi=0;mi<2;mi++)
      #pragma unroll
      for (int kk=0;kk<4;kk++)
        af[mi][kk] = *(const short8*)(As + (wm0 + mi*16 + lm)*LD + kk*32 + kq*8);
    #pragma unroll
    for (int ni=0;ni<4;ni++)
      #pragma unroll
      for (int kk=0;kk<4;kk++)
        bf4[ni][kk] = *(const short8*)(Bs + (wn0 + ni*16 + lm)*LD + kk*32 + kq*8);
    #pragma unroll
    for (int kk=0;kk<4;kk++)
      #pragma unroll
      for (int mi=0;mi<2;mi++)
        #pragma unroll
        for (int ni=0;ni<4;ni++)
          acc[mi][ni] = __builtin_amdgcn_mfma_f32_16x16x32_bf16(af[mi][kk], bf4[ni][kk], acc[mi][ni], 0,0,0);
    __syncthreads();
  }
  int nn[4]; float bv[4];
  #pragma unroll
  for (int ni=0;ni<4;ni++){ nn[ni] = wn0 + ni*16 + lm; bv[ni] = bias[nn[ni]]; }
  float ps[2][4] = {}, pq[2][4] = {};
  #pragma unroll
  for (int mi=0;mi<2;mi++)
    #pragma unroll
    for (int r=0;r<4;r++)
      #pragma unroll
      for (int ni=0;ni<4;ni++){
        float v = acc[mi][ni][r] + bv[ni];
        acc[mi][ni][r] = v;
        ps[mi][r] += v; pq[mi][r] += v*v;
      }
  #pragma unroll
  for (int off=1; off<16; off<<=1){
    #pragma unroll
    for (int mi=0;mi<2;mi++)
      #pragma unroll
      for (int r=0;r<4;r++){ ps[mi][r] += __shfl_xor(ps[mi][r], off); pq[mi][r] += __shfl_xor(pq[mi][r], off); }
  }
  if (lm == 0){
    #pragma unroll
    for (int mi=0;mi<2;mi++)
      #pragma unroll
      for (int r=0;r<4;r++){
        rs[wm0 + mi*16 + kq*4 + r][wave & 1] = ps[mi][r];
        rq[wm0 + mi*16 + kq*4 + r][wave & 1] = pq[mi][r];
      }
  }
  __syncthreads();
  float gv[4], pv[4];
  #pragma unroll
  for (int ni=0;ni<4;ni++){ gv[ni] = g[nn[ni]]; pv[ni] = bb[nn[ni]]; }
  #pragma unroll
  for (int mi=0;mi<2;mi++)
    #pragma unroll
    for (int r=0;r<4;r++){
      int row = wm0 + mi*16 + kq*4 + r;
      int m = m0 + row;
      float s = rs[row][0] + rs[row][1];
      float q = rq[row][0] + rq[row][1];
      float mean = s * (1.f/NOUT_), var = q*(1.f/NOUT_) - mean*mean;
      float rstd = rsqrtf(var + 1e-6f);
      #pragma unroll
      for (int ni=0;ni<4;ni++)
        Out[(size_t)m*NOUT_ + nn[ni]] = gelu_f((acc[mi][ni][r]-mean)*rstd*gv[ni] + pv[ni]);
    }
}

extern "C" void kernel_launch(void* const* d_in, const int* in_sizes, int n_in,
                              void* d_out, int out_size, void* d_ws, size_t ws_size,
                              hipStream_t stream)
{
  (void)in_sizes; (void)n_in; (void)out_size; (void)ws_size;
  const float* x_in = (const float*)d_in[0];
  char* w = (char*)d_ws;
  const size_t MB = 1u<<20;
  float* X    = (float*)(w + 0*MB);
  float* OM   = (float*)(w + 8*MB);
  unsigned short* MIDb = (unsigned short*)(w + 22*MB);
  unsigned short* Ub   = MIDb;
  unsigned short* Tb   = (unsigned short*)(w + 38*MB);
  unsigned short* Fb   = (unsigned short*)(w + 42*MB);
  unsigned short* XPb  = (unsigned short*)(w + 46*MB);
  unsigned short* DW7b = (unsigned short*)(w + 50*MB);
  unsigned short* Sb   = (unsigned short*)(w + 54*MB);
  unsigned short* WT   = (unsigned short*)(w + 58*MB);
  float* psum = (float*)(w + 62*MB);
  float* pmax = psum + 65536;
  float* ca   = pmax + 65536;
  float* smean= ca + 512;
  float* smax = smean + 8192;
  float* sa   = smax + 8192;

  unsigned short* WtInp[2], *WtOut[2], *WtOM[2], *WtC1[2], *WtC2[2];
  {
    size_t o = 0;
    for (int i=0;i<2;i++){
      WtInp[i] = WT + o; o += 65536;
      WtOut[i] = WT + o; o += 65536;
      WtOM[i]  = WT + o; o += 110592;
      WtC1[i]  = WT + o; o += 262144;
      WtC2[i]  = WT + o; o += 262144;
    }
  }
  unsigned short* WtUp = WT + 1531904;

  // ---- fused weight prep + chpool (1 dispatch) ----
  WtJobs J;
  int toff = 0;
  {
    int ji = 0;
    auto add = [&](const float* s, unsigned short* d, int Kd, int Nd){
      J.src[ji]=s; J.dst[ji]=d; J.Kd[ji]=Kd; J.Nd[ji]=Nd;
      J.tOff[ji]=toff; toff += (Kd>>5) * ((Nd+31)>>5); ji++;
    };
    for (int i=0;i<2;i++){
      add((const float*)d_in[11] + (size_t)i*C_*C_,   WtInp[i], C_, C_);
      add((const float*)d_in[13] + (size_t)i*C_*C_,   WtOut[i], C_, C_);
      add((const float*)d_in[7]  + (size_t)i*C_*OFFN_, WtOM[i], C_, OFFN_);
      add((const float*)d_in[9]  + (size_t)i*C_*MSKN_, WtOM[i] + (size_t)OFFN_*C_, C_, MSKN_);
      add((const float*)d_in[21] + (size_t)i*C_*C4_,  WtC1[i], C_, C4_);
      add((const float*)d_in[23] + (size_t)i*C4_*C_,  WtC2[i], C4_, C_);
    }
    add((const float*)d_in[33], WtUp, KUP_, NOUT_);
    J.tOff[ji] = toff;
  }
  k_wt_pool<<<toff + 256,256,0,stream>>>(J, x_in, psum, pmax);

  // ---- CBAM + fused LN1 ----
  k_ca<<<1,512,0,stream>>>(psum, pmax, (const float*)d_in[26], (const float*)d_in[27], ca);
  k_apply_ca<<<M_,256,0,stream>>>(x_in, X, ca, smean, smax);
  k_sa<<<M_/256,256,0,stream>>>(smean, smax, (const float*)d_in[28], sa);
  k_mul_ln_ln1<<<M_,256,0,stream>>>(X, sa, (const float*)d_in[29], (const float*)d_in[30],
      (const float*)d_in[1], (const float*)d_in[2], Tb);

  // ---- layers ----
  for (int i=0;i<2;i++){
    const float* dww  = (const float*)d_in[3] + i*9*C_;
    const float* dwb  = (const float*)d_in[4] + i*C_;
    const float* dwng = (const float*)d_in[5] + i*C_;
    const float* dwnb = (const float*)d_in[6] + i*C_;
    const float* offb = (const float*)d_in[8] + i*OFFN_;
    const float* mskb = (const float*)d_in[10] + i*MSKN_;
    const float* inpb = (const float*)d_in[12] + i*C_;
    const float* outb = (const float*)d_in[14] + i*C_;
    const float* ln2g = (const float*)d_in[15] + i*C_;
    const float* ln2b = (const float*)d_in[16] + i*C_;
    const float* dcw  = (const float*)d_in[17] + i*49*C_;
    const float* dcb  = (const float*)d_in[18] + i*C_;
    const float* fng  = (const float*)d_in[19] + i*C_;
    const float* fnb  = (const float*)d_in[20] + i*C_;
    const float* c1b  = (const float*)d_in[22] + i*C4_;
    const float* c2b  = (const float*)d_in[24] + i*C_;
    const float* gam  = (const float*)d_in[25] + i*C_;
    const float* nxg = (i==0) ? (const float*)d_in[1] + C_ : (const float*)d_in[31];
    const float* nxb = (i==0) ? (const float*)d_in[2] + C_ : (const float*)d_in[32];

    // fused inp-proj GEMM + dw3 (both read Tb) — 1 dispatch, concurrent fill
    k_inp_dw3<<<256 + M_*32/256/1,256,0,stream>>>(Tb, WtInp[i], XPb, inpb, Fb, dww, dwb, dwng, dwnb);
    k_gemm_mfma<64,4,0><<<dim3(M_/64,4),256,0,stream>>>(Fb, WtOM[i], OM, offb, mskb, OMN_, C_);
    k_dcn<<<M_/16,256,0,stream>>>(XPb, OM, Sb);
    k_gemm_ln<2><<<M_/32,256,0,stream>>>(Sb, WtOut[i], X, outb, nullptr, nullptr, Tb, ln2g, ln2b, C_);

    // LEFFN branch (Tb holds ln2 output)
    k_dw7<<<M_*32/256,256,0,stream>>>(Tb, DW7b, dcw, dcb, fng, fnb);
    k_gemm_mfma<128,1,1><<<dim3(M_/128,8),256,0,stream>>>(DW7b, WtC1[i], MIDb, c1b, nullptr, C4_, C_);
    k_gemm_ln<3><<<M_/32,256,0,stream>>>(MIDb, WtC2[i], X, c2b, Tb, gam, Tb, nxg, nxb, C4_);
  }

  // ---- upsample + conv(+LN+GELU) -> d_out ----
  k_upsample<<<MUP_*32/256,256,0,stream>>>(Tb, Ub);
  k_upconv_ln<<<MUP_/64,256,0,stream>>>(Ub, WtUp, (float*)d_out, (const float*)d_in[34],
      (const float*)d_in[35], (const float*)d_in[36]);
}

// Round 11
// 502.565 us; speedup vs baseline: 1.1309x; 1.0197x over previous
//
#include <hip/hip_runtime.h>
#include <math.h>

#define B_ 2
#define H_ 64
#define W_ 64
#define C_ 256
#define G_ 16
#define HW_ (H_*W_)          // 4096
#define M_ (B_*HW_)          // 8192
#define C4_ (4*C_)           // 1024
#define OFFN_ 288
#define MSKN_ 144
#define OMN_ 432
#define UH_ 128
#define UW_ 128
#define MUP_ (B_*UH_*UW_)    // 32768
#define KUP_ (9*C_)          // 2304
#define NOUT_ 128

typedef short short8 __attribute__((ext_vector_type(8)));
typedef float f32x4 __attribute__((ext_vector_type(4)));
typedef unsigned short us4 __attribute__((ext_vector_type(4)));

__device__ __forceinline__ float gelu_f(float x){
  return 0.5f * x * (1.f + erff(x * 0.70710678118654752440f));
}
__device__ __forceinline__ float sigmoid_f(float x){ return 1.f/(1.f+expf(-x)); }
__device__ __forceinline__ unsigned short f2bf(float x){
  unsigned int u = __float_as_uint(x);
  unsigned int r = (u + 0x7fffu + ((u>>16)&1u)) >> 16;
  return (unsigned short)r;
}
__device__ __forceinline__ float bf2f(unsigned short u){
  return __uint_as_float(((unsigned int)u) << 16);
}
__device__ __forceinline__ float bfl(unsigned int u){ return __uint_as_float(u<<16); }
__device__ __forceinline__ float bfh(unsigned int u){ return __uint_as_float(u & 0xffff0000u); }
__device__ __forceinline__ unsigned int pk(float a, float b){
  return (unsigned int)f2bf(a) | ((unsigned int)f2bf(b) << 16);
}

__device__ __forceinline__ void block_sum2(float& s, float& ss, float* sm){
  #pragma unroll
  for (int off=32; off>0; off>>=1){ s += __shfl_down(s, off); ss += __shfl_down(ss, off); }
  int lane = threadIdx.x & 63, wid = threadIdx.x >> 6;
  if (lane == 0){ sm[wid] = s; sm[4+wid] = ss; }
  __syncthreads();
  float a = 0.f, b = 0.f;
  int nw = blockDim.x >> 6;
  for (int i=0;i<nw;i++){ a += sm[i]; b += sm[4+i]; }
  s = a; ss = b;
}

__device__ __forceinline__ void block_summax(float& s, float& m, float* sm){
  #pragma unroll
  for (int off=32; off>0; off>>=1){ s += __shfl_down(s, off); m = fmaxf(m, __shfl_down(m, off)); }
  int lane = threadIdx.x & 63, wid = threadIdx.x >> 6;
  if (lane == 0){ sm[wid] = s; sm[4+wid] = m; }
  __syncthreads();
  float a = 0.f, b = -3.4e38f;
  int nw = blockDim.x >> 6;
  for (int i=0;i<nw;i++){ a += sm[i]; b = fmaxf(b, sm[4+i]); }
  s = a; m = b;
}

// ---------------- fused: batched weight prep + CBAM channel pool ----------------
#define NJOBS 13
struct WtJobs {
  const float* src[NJOBS];
  unsigned short* dst[NJOBS];
  int Kd[NJOBS], Nd[NJOBS];
  int tOff[NJOBS+1];
};

__global__ __launch_bounds__(256) void k_wt_pool(WtJobs J, const float* __restrict__ Xin,
    float* __restrict__ psum, float* __restrict__ pmax){
  __shared__ float tile[32][33];
  int bid = blockIdx.x;
  int nwt = J.tOff[NJOBS];
  if (bid >= nwt){
    int lb = bid - nwt;
    int chunk = lb & 127, b = lb >> 7; int c = threadIdx.x;
    const float* p = Xin + (((size_t)b*HW_) + chunk*32)*C_ + c;
    float s = 0.f, m = -3.4e38f;
    for (int i=0;i<32;i++){ float v = p[(size_t)i*C_]; s += v; m = fmaxf(m, v); }
    psum[(b*128+chunk)*C_+c] = s; pmax[(b*128+chunk)*C_+c] = m;
    return;
  }
  int j = 0;
  while (bid >= J.tOff[j+1]) j++;
  int lt = bid - J.tOff[j];
  const float* W = J.src[j];
  unsigned short* Wt = J.dst[j];
  int Kd = J.Kd[j], Nd = J.Nd[j];
  int ktiles = Kd >> 5;
  int k0 = (lt % ktiles) * 32, n0 = (lt / ktiles) * 32;
  int t = threadIdx.x;
  int r = t>>3, c4 = (t&7)*4;
  float4 v = make_float4(0.f,0.f,0.f,0.f);
  if (n0 + c4 < Nd) v = *(const float4*)(W + (size_t)(k0+r)*Nd + n0 + c4);
  tile[c4+0][r]=v.x; tile[c4+1][r]=v.y; tile[c4+2][r]=v.z; tile[c4+3][r]=v.w;
  __syncthreads();
  if (n0 + r < Nd){
    us4 o;
    o.x = f2bf(tile[r][c4+0]); o.y = f2bf(tile[r][c4+1]);
    o.z = f2bf(tile[r][c4+2]); o.w = f2bf(tile[r][c4+3]);
    *(us4*)(Wt + (size_t)(n0+r)*Kd + k0 + c4) = o;
  }
}

// ---------------- CBAM ----------------
__global__ __launch_bounds__(512) void k_ca(const float* __restrict__ psum, const float* __restrict__ pmax,
    const float* __restrict__ w1, const float* __restrict__ w2, float* __restrict__ ca){
  __shared__ float pm[2][256], px[2][256], hh[2][2][16];
  int t = threadIdx.x;
  {
    int b = t >> 8, c = t & 255;
    float s = 0.f, m = -3.4e38f;
    for (int ch=0; ch<128; ch++){ s += psum[(b*128+ch)*256+c]; m = fmaxf(m, pmax[(b*128+ch)*256+c]); }
    pm[b][c] = s * (1.f/4096.f); px[b][c] = m;
  }
  __syncthreads();
  if (t < 64){
    int b = t >> 5, typ = (t >> 4) & 1, j = t & 15;
    const float* src = typ ? px[b] : pm[b];
    float a = 0.f;
    for (int c2=0;c2<256;c2++) a += src[c2]*w1[c2*16+j];
    hh[b][typ][j] = fmaxf(a, 0.f);
  }
  __syncthreads();
  {
    int b = t >> 8, c = t & 255;
    float a = 0.f;
    for (int j=0;j<16;j++) a += (hh[b][0][j]+hh[b][1][j]) * w2[j*256+c];
    ca[b*256+c] = sigmoid_f(a);
  }
}

__global__ __launch_bounds__(256) void k_apply_ca(const float* __restrict__ Xin, float* __restrict__ X,
    const float* __restrict__ ca, float* __restrict__ smean, float* __restrict__ smax){
  __shared__ float sm[12];
  int pix = blockIdx.x, c = threadIdx.x;
  int b = pix >> 12;
  float v = Xin[(size_t)pix*C_+c] * ca[b*C_+c];
  X[(size_t)pix*C_+c] = v;
  float s = v, m = v;
  block_summax(s, m, sm);
  if (c == 0){ smean[pix] = s * (1.f/C_); smax[pix] = m; }
}

// fused: spatial-attention (7x7 over smean/smax, this pixel only) + X=LN(X*sa) + Tb=LN1(X)
__global__ __launch_bounds__(256) void k_sa_mul_ln_ln1(float* __restrict__ X,
    const float* __restrict__ smean, const float* __restrict__ smax, const float* __restrict__ wsa,
    const float* __restrict__ g, const float* __restrict__ b,
    const float* __restrict__ g1, const float* __restrict__ b1, unsigned short* __restrict__ Tb){
  __shared__ float sm[12];
  __shared__ float sav;
  int pix = blockIdx.x, c = threadIdx.x;
  int bb2 = pix >> 12, hw = pix & 4095, h = hw >> 6, ww = hw & 63;
  // phase 1: sa for this pixel — threads 0..48 handle one tap each, wave-0 reduce
  {
    float s = 0.f;
    if (c < 49){
      int ky = c / 7, kx = c % 7;
      int hh = h + ky - 3, xx = ww + kx - 3;
      if (hh >= 0 && hh < H_ && xx >= 0 && xx < W_){
        int q = (bb2<<12) + (hh<<6) + xx;
        s = smean[q]*wsa[c*2+0] + smax[q]*wsa[c*2+1];
      }
    }
    if (c < 64){
      #pragma unroll
      for (int off=32; off>0; off>>=1) s += __shfl_down(s, off);
      if (c == 0) sav = sigmoid_f(s);
    }
  }
  __syncthreads();
  float v = X[(size_t)pix*C_+c] * sav;
  float s = v, ss = v*v;
  block_sum2(s, ss, sm);
  float mean = s * (1.f/C_), var = ss*(1.f/C_) - mean*mean;
  float r = rsqrtf(var + 1e-6f);
  float x0 = (v-mean)*r*g[c] + b[c];
  X[(size_t)pix*C_+c] = x0;
  __syncthreads();
  s = x0; ss = x0*x0;
  block_sum2(s, ss, sm);
  mean = s * (1.f/C_); var = ss*(1.f/C_) - mean*mean;
  r = rsqrtf(var + 1e-6f);
  Tb[(size_t)pix*C_+c] = f2bf((x0-mean)*r*g1[c] + b1[c]);
}

// dwconv body (shared by fused + standalone kernels)
template<int KS, int DOGELU>
__device__ __forceinline__ void dwconv_body(int t, const unsigned short* __restrict__ T,
    unsigned short* __restrict__ Out,
    const float* __restrict__ w, const float* __restrict__ bias,
    const float* __restrict__ g, const float* __restrict__ bb){
  constexpr int R = KS/2;
  int pix = t >> 5, grp = t & 31;
  int c0 = grp*8;
  int b = pix >> 12, hw = pix & 4095, h = hw >> 6, ww = hw & 63;
  float acc[8];
  {
    float4 b0 = *(const float4*)(bias + c0), b1 = *(const float4*)(bias + c0 + 4);
    acc[0]=b0.x; acc[1]=b0.y; acc[2]=b0.z; acc[3]=b0.w;
    acc[4]=b1.x; acc[5]=b1.y; acc[6]=b1.z; acc[7]=b1.w;
  }
  const unsigned short* tb = T + ((size_t)b*HW_)*C_ + c0;
  for (int ky=0;ky<KS;ky++){
    int hh = h + ky - R; if (hh < 0 || hh >= H_) continue;
    for (int kx=0;kx<KS;kx++){
      int xx = ww + kx - R; if (xx < 0 || xx >= W_) continue;
      uint4 a = *(const uint4*)(tb + ((size_t)hh*W_+xx)*C_);
      const float* wp = w + (ky*KS+kx)*C_ + c0;
      float4 w0 = *(const float4*)wp, w1 = *(const float4*)(wp+4);
      acc[0] += bfl(a.x)*w0.x; acc[1] += bfh(a.x)*w0.y;
      acc[2] += bfl(a.y)*w0.z; acc[3] += bfh(a.y)*w0.w;
      acc[4] += bfl(a.z)*w1.x; acc[5] += bfh(a.z)*w1.y;
      acc[6] += bfl(a.w)*w1.z; acc[7] += bfh(a.w)*w1.w;
    }
  }
  float s = 0.f, ss = 0.f;
  #pragma unroll
  for (int i=0;i<8;i++){ s += acc[i]; ss += acc[i]*acc[i]; }
  #pragma unroll
  for (int off=1; off<32; off<<=1){ s += __shfl_xor(s, off); ss += __shfl_xor(ss, off); }
  float mean = s * (1.f/C_), var = ss*(1.f/C_) - mean*mean;
  float r = rsqrtf(var + 1e-6f);
  float4 g0 = *(const float4*)(g + c0), g1 = *(const float4*)(g + c0 + 4);
  float4 p0 = *(const float4*)(bb + c0), p1 = *(const float4*)(bb + c0 + 4);
  float o[8];
  o[0]=(acc[0]-mean)*r*g0.x+p0.x; o[1]=(acc[1]-mean)*r*g0.y+p0.y;
  o[2]=(acc[2]-mean)*r*g0.z+p0.z; o[3]=(acc[3]-mean)*r*g0.w+p0.w;
  o[4]=(acc[4]-mean)*r*g1.x+p1.x; o[5]=(acc[5]-mean)*r*g1.y+p1.y;
  o[6]=(acc[6]-mean)*r*g1.z+p1.z; o[7]=(acc[7]-mean)*r*g1.w+p1.w;
  if (DOGELU){
    #pragma unroll
    for (int i=0;i<8;i++) o[i] = gelu_f(o[i]);
  }
  uint4 ov;
  ov.x = pk(o[0],o[1]); ov.y = pk(o[2],o[3]); ov.z = pk(o[4],o[5]); ov.w = pk(o[6],o[7]);
  *(uint4*)(Out + (size_t)pix*C_ + c0) = ov;
}

// standalone dw7
__global__ __launch_bounds__(256) void k_dw7(const unsigned short* __restrict__ T,
    unsigned short* __restrict__ Out,
    const float* __restrict__ w, const float* __restrict__ bias,
    const float* __restrict__ g, const float* __restrict__ bb){
  dwconv_body<7,0>(blockIdx.x*256 + threadIdx.x, T, Out, w, bias, g, bb);
}

// ---------------- fused: inp-proj GEMM (blocks 0..255) + dw3 (blocks 256..1279) ----------------
__global__ __launch_bounds__(256) void k_inp_dw3(
    const unsigned short* __restrict__ Tb, const unsigned short* __restrict__ Bt,
    unsigned short* __restrict__ XPb, const float* __restrict__ inpb,
    unsigned short* __restrict__ Fb,
    const float* __restrict__ dww, const float* __restrict__ dwb,
    const float* __restrict__ dwng, const float* __restrict__ dwnb)
{
  constexpr int LD = 40;
  __shared__ unsigned short As[64*LD];
  __shared__ unsigned short Bs[128*LD];
  const int bid = blockIdx.x;
  const int tid = threadIdx.x;
  if (bid >= 256){
    dwconv_body<3,1>((bid-256)*256 + tid, Tb, Fb, dww, dwb, dwng, dwnb);
    return;
  }
  const int wave = tid >> 6, lane = tid & 63;
  const int m0 = (bid & 127) * 64, n0 = (bid >> 7) * 128;
  const int wm0 = (wave >> 1) * 32;
  const int wn0 = (wave & 1) * 64;
  f32x4 acc[2][4] = {};
  const int lm = lane & 15, kq = lane >> 4;

  for (int k0 = 0; k0 < C_; k0 += 32){
    {
      int r = tid >> 2, cc = (tid & 3) << 3;
      short8 v = *(const short8*)(Tb + (size_t)(m0 + r)*C_ + k0 + cc);
      *(short8*)(As + r*LD + cc) = v;
    }
    #pragma unroll
    for (int i=0;i<2;i++){
      int ch = tid + 256*i;
      int r = ch >> 2, cc = (ch & 3) << 3;
      short8 v = *(const short8*)(Bt + (size_t)(n0 + r)*C_ + k0 + cc);
      *(short8*)(Bs + r*LD + cc) = v;
    }
    __syncthreads();
    short8 af[2], bf[4];
    #pragma unroll
    for (int mi=0;mi<2;mi++) af[mi] = *(const short8*)(As + (wm0 + mi*16 + lm)*LD + kq*8);
    #pragma unroll
    for (int ni=0;ni<4;ni++)  bf[ni] = *(const short8*)(Bs + (wn0 + ni*16 + lm)*LD + kq*8);
    #pragma unroll
    for (int mi=0;mi<2;mi++)
      #pragma unroll
      for (int ni=0;ni<4;ni++)
        acc[mi][ni] = __builtin_amdgcn_mfma_f32_16x16x32_bf16(af[mi], bf[ni], acc[mi][ni], 0,0,0);
    __syncthreads();
  }
  #pragma unroll
  for (int mi=0;mi<2;mi++){
    #pragma unroll
    for (int ni=0;ni<4;ni++){
      int n = n0 + wn0 + ni*16 + lm;
      float bv = inpb[n];
      #pragma unroll
      for (int r=0;r<4;r++){
        int m = m0 + wm0 + mi*16 + kq*4 + r;
        XPb[(size_t)m*C_ + n] = f2bf(acc[mi][ni][r] + bv);
      }
    }
  }
}

// ---------------- bf16 MFMA GEMM (generic, N-tiled, BK=32) ----------------
template<int TM, int EP, int OUTBF>
__global__ __launch_bounds__(256) void k_gemm_mfma(
    const unsigned short* __restrict__ A, const unsigned short* __restrict__ Bt,
    void* __restrict__ OutV, const float* __restrict__ bias,
    const float* __restrict__ bias2, int Ni, int Ki)
{
  constexpr int LD = 40;
  __shared__ unsigned short As[TM*LD];
  __shared__ unsigned short Bs[128*LD];
  const int tid = threadIdx.x;
  const int wave = tid >> 6, lane = tid & 63;
  const int m0 = blockIdx.x * TM, n0 = blockIdx.y * 128;
  const int wm0 = (wave >> 1) * (TM/2);
  const int wn0 = (wave & 1) * 64;
  constexpr int MI = (TM+31)/32;
  f32x4 acc[MI][4] = {};
  const int lm = lane & 15, kq = lane >> 4;

  for (int k0 = 0; k0 < Ki; k0 += 32){
    for (int ch = tid; ch < TM*4; ch += 256){
      int r = ch >> 2, cc = (ch & 3) << 3;
      short8 v = *(const short8*)(A + (size_t)(m0 + r)*Ki + k0 + cc);
      *(short8*)(As + r*LD + cc) = v;
    }
    #pragma unroll
    for (int i=0;i<2;i++){
      int ch = tid + 256*i;
      int r = ch >> 2, cc = (ch & 3) << 3;
      short8 v = {};
      if (n0 + r < Ni) v = *(const short8*)(Bt + (size_t)(n0 + r)*Ki + k0 + cc);
      *(short8*)(Bs + r*LD + cc) = v;
    }
    __syncthreads();
    short8 af[MI], bf[4];
    #pragma unroll
    for (int mi=0;mi<MI;mi++) af[mi] = *(const short8*)(As + (wm0 + mi*16 + lm)*LD + kq*8);
    #pragma unroll
    for (int ni=0;ni<4;ni++)  bf[ni] = *(const short8*)(Bs + (wn0 + ni*16 + lm)*LD + kq*8);
    #pragma unroll
    for (int mi=0;mi<MI;mi++)
      #pragma unroll
      for (int ni=0;ni<4;ni++)
        acc[mi][ni] = __builtin_amdgcn_mfma_f32_16x16x32_bf16(af[mi], bf[ni], acc[mi][ni], 0,0,0);
    __syncthreads();
  }
  #pragma unroll
  for (int mi=0;mi<MI;mi++){
    #pragma unroll
    for (int ni=0;ni<4;ni++){
      int n = n0 + wn0 + ni*16 + lm;
      if (n < Ni){
        float bv;
        if constexpr (EP==4) bv = (n < OFFN_) ? bias[n] : bias2[n-OFFN_];
        else bv = bias[n];
        #pragma unroll
        for (int r=0;r<4;r++){
          int m = m0 + wm0 + mi*16 + kq*4 + r;
          size_t o = (size_t)m*Ni + n;
          float v = acc[mi][ni][r] + bv;
          if constexpr (EP==1) v = gelu_f(v);
          if constexpr (OUTBF) ((unsigned short*)OutV)[o] = f2bf(v);
          else                 ((float*)OutV)[o] = v;
        }
      }
    }
  }
}

// ---------------- GEMM with fused residual + row-LN epilogue ----------------
template<int EP>
__global__ __launch_bounds__(256) void k_gemm_ln(
    const unsigned short* __restrict__ A, const unsigned short* __restrict__ Bt,
    float* __restrict__ X, const float* __restrict__ bias,
    const unsigned short* __restrict__ res2b, const float* __restrict__ gamma,
    unsigned short* __restrict__ OutTb,
    const float* __restrict__ lng, const float* __restrict__ lnb, int Ki)
{
  constexpr int LD = 40;
  __shared__ unsigned short As[32*LD];
  __shared__ unsigned short Bs[256*LD];
  __shared__ float rs[32][2], rq[32][2];
  const int tid = threadIdx.x;
  const int wave = tid >> 6, lane = tid & 63;
  const int m0 = blockIdx.x * 32;
  const int wm0 = (wave >> 1) * 16;
  const int wn0 = (wave & 1) * 128;
  const int lm = lane & 15, kq = lane >> 4;
  f32x4 acc[8] = {};

  for (int k0 = 0; k0 < Ki; k0 += 32){
    if (tid < 128){
      int r = tid >> 2, cc = (tid & 3) << 3;
      short8 v = *(const short8*)(A + (size_t)(m0 + r)*Ki + k0 + cc);
      *(short8*)(As + r*LD + cc) = v;
    }
    #pragma unroll
    for (int i=0;i<4;i++){
      int ch = tid + 256*i;
      int r = ch >> 2, cc = (ch & 3) << 3;
      short8 v = *(const short8*)(Bt + (size_t)r*Ki + k0 + cc);
      *(short8*)(Bs + r*LD + cc) = v;
    }
    __syncthreads();
    short8 af = *(const short8*)(As + (wm0 + lm)*LD + kq*8);
    short8 bf[8];
    #pragma unroll
    for (int ni=0;ni<8;ni++) bf[ni] = *(const short8*)(Bs + (wn0 + ni*16 + lm)*LD + kq*8);
    #pragma unroll
    for (int ni=0;ni<8;ni++)
      acc[ni] = __builtin_amdgcn_mfma_f32_16x16x32_bf16(af, bf[ni], acc[ni], 0,0,0);
    __syncthreads();
  }
  int nn[8]; float bv[8], gv[8];
  #pragma unroll
  for (int ni=0;ni<8;ni++){
    nn[ni] = wn0 + ni*16 + lm;
    bv[ni] = bias[nn[ni]];
    if constexpr (EP==3) gv[ni] = gamma[nn[ni]];
  }
  float ps[4] = {}, pq[4] = {};
  #pragma unroll
  for (int r=0;r<4;r++){
    int m = m0 + wm0 + kq*4 + r;
    #pragma unroll
    for (int ni=0;ni<8;ni++){
      size_t o = (size_t)m*C_ + nn[ni];
      float v = acc[ni][r] + bv[ni];
      if constexpr (EP==2) v = X[o] + v;
      if constexpr (EP==3) v = X[o] + bf2f(res2b[o]) + gv[ni]*v;
      X[o] = v;
      acc[ni][r] = v;
      ps[r] += v; pq[r] += v*v;
    }
  }
  #pragma unroll
  for (int off=1; off<16; off<<=1){
    #pragma unroll
    for (int r=0;r<4;r++){ ps[r] += __shfl_xor(ps[r], off); pq[r] += __shfl_xor(pq[r], off); }
  }
  if (lm == 0){
    #pragma unroll
    for (int r=0;r<4;r++){
      rs[wm0 + kq*4 + r][wave & 1] = ps[r];
      rq[wm0 + kq*4 + r][wave & 1] = pq[r];
    }
  }
  __syncthreads();
  float lg[8], lb[8];
  #pragma unroll
  for (int ni=0;ni<8;ni++){ lg[ni] = lng[nn[ni]]; lb[ni] = lnb[nn[ni]]; }
  #pragma unroll
  for (int r=0;r<4;r++){
    int row = wm0 + kq*4 + r;
    int m = m0 + row;
    float s = rs[row][0] + rs[row][1];
    float q = rq[row][0] + rq[row][1];
    float mean = s * (1.f/C_), var = q*(1.f/C_) - mean*mean;
    float rstd = rsqrtf(var + 1e-6f);
    #pragma unroll
    for (int ni=0;ni<8;ni++){
      size_t o = (size_t)m*C_ + nn[ni];
      OutTb[o] = f2bf((acc[ni][r]-mean)*rstd*lg[ni] + lb[ni]);
    }
  }
}

// DCNv3 sampling, thread = (pix, g), 16 ch; OM staged in LDS
__global__ __launch_bounds__(256) void k_dcn(const unsigned short* __restrict__ xp,
    const float* __restrict__ OM, unsigned short* __restrict__ S){
  __shared__ float lom[16*OMN_];
  int pix0 = blockIdx.x * 16;
  {
    const float* gsrc = OM + (size_t)pix0*OMN_;
    for (int idx = threadIdx.x; idx < 16*OMN_; idx += 256) lom[idx] = gsrc[idx];
  }
  __syncthreads();
  int pl = threadIdx.x >> 4, g = threadIdx.x & 15;
  int pix = pix0 + pl;
  int b = pix >> 12, hw = pix & 4095, h = hw >> 6, ww = hw & 63;
  const float* offp = lom + pl*OMN_ + g*18;
  const float* mp   = lom + pl*OMN_ + OFFN_ + g*9;
  const unsigned short* xpb = xp + ((size_t)b*HW_)*C_ + g*16;
  float e[9]; float mx = -3.4e38f;
  #pragma unroll
  for (int k=0;k<9;k++){ e[k] = mp[k]; mx = fmaxf(mx, e[k]); }
  float ssum = 0.f;
  #pragma unroll
  for (int k=0;k<9;k++){ e[k] = expf(e[k]-mx); ssum += e[k]; }
  float rinv = 1.f/ssum;
  float acc[16] = {};
  #pragma unroll
  for (int k=0;k<9;k++){
    float ox = offp[k*2+0], oy = offp[k*2+1];
    float px = (float)(ww + (k%3)) + ox;
    float py = (float)(h  + (k/3)) + oy;
    int x0 = (int)floorf(px), y0 = (int)floorf(py);
    float fx = px - (float)x0, fy = py - (float)y0;
    float mk = e[k]*rinv;
    float w00 = mk*(1.f-fx)*(1.f-fy), w01 = mk*fx*(1.f-fy);
    float w10 = mk*(1.f-fx)*fy,       w11 = mk*fx*fy;
    #define CORNER(yy,xx,WGT) do{ \
      if ((yy)>=1 && (yy)<=H_ && (xx)>=1 && (xx)<=W_){ \
        const unsigned short* p = xpb + ((size_t)((yy)-1)*W_ + ((xx)-1))*C_; \
        uint4 a0 = *(const uint4*)p; uint4 a1 = *(const uint4*)(p+8); \
        acc[0]+=WGT*bfl(a0.x); acc[1]+=WGT*bfh(a0.x); acc[2]+=WGT*bfl(a0.y); acc[3]+=WGT*bfh(a0.y); \
        acc[4]+=WGT*bfl(a0.z); acc[5]+=WGT*bfh(a0.z); acc[6]+=WGT*bfl(a0.w); acc[7]+=WGT*bfh(a0.w); \
        acc[8]+=WGT*bfl(a1.x); acc[9]+=WGT*bfh(a1.x); acc[10]+=WGT*bfl(a1.y); acc[11]+=WGT*bfh(a1.y); \
        acc[12]+=WGT*bfl(a1.z); acc[13]+=WGT*bfh(a1.z); acc[14]+=WGT*bfl(a1.w); acc[15]+=WGT*bfh(a1.w); \
      } \
    }while(0)
    CORNER(y0,   x0,   w00);
    CORNER(y0,   x0+1, w01);
    CORNER(y0+1, x0,   w10);
    CORNER(y0+1, x0+1, w11);
    #undef CORNER
  }
  unsigned short* sp = S + (size_t)pix*C_ + g*16;
  uint4 o0, o1;
  o0.x = pk(acc[0],acc[1]);   o0.y = pk(acc[2],acc[3]);
  o0.z = pk(acc[4],acc[5]);   o0.w = pk(acc[6],acc[7]);
  o1.x = pk(acc[8],acc[9]);   o1.y = pk(acc[10],acc[11]);
  o1.z = pk(acc[12],acc[13]); o1.w = pk(acc[14],acc[15]);
  *(uint4*)sp = o0;
  *(uint4*)(sp+8) = o1;
}

// bilinear 2x upsample (bf16 in) -> bf16, 8 ch/thread
__global__ __launch_bounds__(256) void k_upsample(const unsigned short* __restrict__ T, unsigned short* __restrict__ U){
  int t = blockIdx.x*256 + threadIdx.x;
  int opix = t >> 5, grp = t & 31;
  int c0 = grp*8;
  int ox = opix & 127, oy = (opix >> 7) & 127, b = opix >> 14;
  float sy = oy*0.5f - 0.25f, sx = ox*0.5f - 0.25f;
  int y0 = (int)floorf(sy), x0 = (int)floorf(sx);
  float fy = sy - (float)y0, fx = sx - (float)x0;
  int y0c = min(max(y0,0),H_-1), y1c = min(max(y0+1,0),H_-1);
  int x0c = min(max(x0,0),W_-1), x1c = min(max(x0+1,0),W_-1);
  const unsigned short* tb = T + ((size_t)b*HW_)*C_ + c0;
  uint4 q00 = *(const uint4*)(tb + ((size_t)y0c*W_+x0c)*C_);
  uint4 q01 = *(const uint4*)(tb + ((size_t)y0c*W_+x1c)*C_);
  uint4 q10 = *(const uint4*)(tb + ((size_t)y1c*W_+x0c)*C_);
  uint4 q11 = *(const uint4*)(tb + ((size_t)y1c*W_+x1c)*C_);
  float w00=(1.f-fy)*(1.f-fx), w01=(1.f-fy)*fx, w10=fy*(1.f-fx), w11=fy*fx;
  float o[8];
  o[0]=w00*bfl(q00.x)+w01*bfl(q01.x)+w10*bfl(q10.x)+w11*bfl(q11.x);
  o[1]=w00*bfh(q00.x)+w01*bfh(q01.x)+w10*bfh(q10.x)+w11*bfh(q11.x);
  o[2]=w00*bfl(q00.y)+w01*bfl(q01.y)+w10*bfl(q10.y)+w11*bfl(q11.y);
  o[3]=w00*bfh(q00.y)+w01*bfh(q01.y)+w10*bfh(q10.y)+w11*bfh(q11.y);
  o[4]=w00*bfl(q00.z)+w01*bfl(q01.z)+w10*bfl(q10.z)+w11*bfl(q11.z);
  o[5]=w00*bfh(q00.z)+w01*bfh(q01.z)+w10*bfh(q10.z)+w11*bfh(q11.z);
  o[6]=w00*bfl(q00.w)+w01*bfl(q01.w)+w10*bfl(q10.w)+w11*bfl(q11.w);
  o[7]=w00*bfh(q00.w)+w01*bfh(q01.w)+w10*bfh(q10.w)+w11*bfh(q11.w);
  uint4 ov;
  ov.x = pk(o[0],o[1]); ov.y = pk(o[2],o[3]); ov.z = pk(o[4],o[5]); ov.w = pk(o[6],o[7]);
  *(uint4*)(U + (size_t)opix*C_ + c0) = ov;
}

// implicit-GEMM 3x3 conv (TM=64, BK=128) + fused bias + row-LN + GELU -> d_out fp32
__global__ __launch_bounds__(256) void k_upconv_ln(
    const unsigned short* __restrict__ U, const unsigned short* __restrict__ Wt,
    float* __restrict__ Out, const float* __restrict__ bias,
    const float* __restrict__ g, const float* __restrict__ bb)
{
  constexpr int LD = 136;
  __shared__ unsigned short As[64*LD];
  __shared__ unsigned short Bs[128*LD];
  __shared__ float rs[64][2], rq[64][2];
  const int tid = threadIdx.x;
  const int wave = tid >> 6, lane = tid & 63;
  const int m0 = blockIdx.x * 64;
  const int wm0 = (wave >> 1) * 32;
  const int wn0 = (wave & 1) * 64;
  const int lm = lane & 15, kq = lane >> 4;
  f32x4 acc[2][4] = {};
  const int r0 = tid >> 2, cA0 = (tid & 3) << 5;
  const int ma = m0 + r0;
  const int ba = ma >> 14, oya = (ma >> 7) & 127, oxa = ma & 127;

  for (int k0 = 0; k0 < KUP_; k0 += 128){
    int tap = k0 >> 8, cc0 = k0 & 255;
    int dy = tap/3 - 1, dx = tap%3 - 1;
    {
      int iy = oya + dy, ix = oxa + dx;
      bool ok = (iy >= 0 && iy < UH_ && ix >= 0 && ix < UW_);
      const unsigned short* src = U + (((size_t)ba*UH_ + iy)*UW_ + ix)*C_ + cc0 + cA0;
      #pragma unroll
      for (int i=0;i<4;i++){
        short8 v = {};
        if (ok) v = *(const short8*)(src + i*8);
        *(short8*)(As + r0*LD + cA0 + i*8) = v;
      }
    }
    #pragma unroll
    for (int i=0;i<8;i++){
      int ch = tid + 256*i;
      int r = ch >> 4, cc = (ch & 15) << 3;
      short8 v = *(const short8*)(Wt + (size_t)r*KUP_ + k0 + cc);
      *(short8*)(Bs + r*LD + cc) = v;
    }
    __syncthreads();
    short8 af[2][4], bf4[4][4];
    #pragma unroll
    for (int mi=0;mi<2;mi++)
      #pragma unroll
      for (int kk=0;kk<4;kk++)
        af[mi][kk] = *(const short8*)(As + (wm0 + mi*16 + lm)*LD + kk*32 + kq*8);
    #pragma unroll
    for (int ni=0;ni<4;ni++)
      #pragma unroll
      for (int kk=0;kk<4;kk++)
        bf4[ni][kk] = *(const short8*)(Bs + (wn0 + ni*16 + lm)*LD + kk*32 + kq*8);
    #pragma unroll
    for (int kk=0;kk<4;kk++)
      #pragma unroll
      for (int mi=0;mi<2;mi++)
        #pragma unroll
        for (int ni=0;ni<4;ni++)
          acc[mi][ni] = __builtin_amdgcn_mfma_f32_16x16x32_bf16(af[mi][kk], bf4[ni][kk], acc[mi][ni], 0,0,0);
    __syncthreads();
  }
  int nn[4]; float bv[4];
  #pragma unroll
  for (int ni=0;ni<4;ni++){ nn[ni] = wn0 + ni*16 + lm; bv[ni] = bias[nn[ni]]; }
  float ps[2][4] = {}, pq[2][4] = {};
  #pragma unroll
  for (int mi=0;mi<2;mi++)
    #pragma unroll
    for (int r=0;r<4;r++)
      #pragma unroll
      for (int ni=0;ni<4;ni++){
        float v = acc[mi][ni][r] + bv[ni];
        acc[mi][ni][r] = v;
        ps[mi][r] += v; pq[mi][r] += v*v;
      }
  #pragma unroll
  for (int off=1; off<16; off<<=1){
    #pragma unroll
    for (int mi=0;mi<2;mi++)
      #pragma unroll
      for (int r=0;r<4;r++){ ps[mi][r] += __shfl_xor(ps[mi][r], off); pq[mi][r] += __shfl_xor(pq[mi][r], off); }
  }
  if (lm == 0){
    #pragma unroll
    for (int mi=0;mi<2;mi++)
      #pragma unroll
      for (int r=0;r<4;r++){
        rs[wm0 + mi*16 + kq*4 + r][wave & 1] = ps[mi][r];
        rq[wm0 + mi*16 + kq*4 + r][wave & 1] = pq[mi][r];
      }
  }
  __syncthreads();
  float gv[4], pv[4];
  #pragma unroll
  for (int ni=0;ni<4;ni++){ gv[ni] = g[nn[ni]]; pv[ni] = bb[nn[ni]]; }
  #pragma unroll
  for (int mi=0;mi<2;mi++)
    #pragma unroll
    for (int r=0;r<4;r++){
      int row = wm0 + mi*16 + kq*4 + r;
      int m = m0 + row;
      float s = rs[row][0] + rs[row][1];
      float q = rq[row][0] + rq[row][1];
      float mean = s * (1.f/NOUT_), var = q*(1.f/NOUT_) - mean*mean;
      float rstd = rsqrtf(var + 1e-6f);
      #pragma unroll
      for (int ni=0;ni<4;ni++)
        Out[(size_t)m*NOUT_ + nn[ni]] = gelu_f((acc[mi][ni][r]-mean)*rstd*gv[ni] + pv[ni]);
    }
}

extern "C" void kernel_launch(void* const* d_in, const int* in_sizes, int n_in,
                              void* d_out, int out_size, void* d_ws, size_t ws_size,
                              hipStream_t stream)
{
  (void)in_sizes; (void)n_in; (void)out_size; (void)ws_size;
  const float* x_in = (const float*)d_in[0];
  char* w = (char*)d_ws;
  const size_t MB = 1u<<20;
  float* X    = (float*)(w + 0*MB);
  float* OM   = (float*)(w + 8*MB);
  unsigned short* MIDb = (unsigned short*)(w + 22*MB);
  unsigned short* Ub   = MIDb;
  unsigned short* Tb   = (unsigned short*)(w + 38*MB);
  unsigned short* Fb   = (unsigned short*)(w + 42*MB);
  unsigned short* XPb  = (unsigned short*)(w + 46*MB);
  unsigned short* DW7b = (unsigned short*)(w + 50*MB);
  unsigned short* Sb   = (unsigned short*)(w + 54*MB);
  unsigned short* WT   = (unsigned short*)(w + 58*MB);
  float* psum = (float*)(w + 62*MB);
  float* pmax = psum + 65536;
  float* ca   = pmax + 65536;
  float* smean= ca + 512;
  float* smax = smean + 8192;

  unsigned short* WtInp[2], *WtOut[2], *WtOM[2], *WtC1[2], *WtC2[2];
  {
    size_t o = 0;
    for (int i=0;i<2;i++){
      WtInp[i] = WT + o; o += 65536;
      WtOut[i] = WT + o; o += 65536;
      WtOM[i]  = WT + o; o += 110592;
      WtC1[i]  = WT + o; o += 262144;
      WtC2[i]  = WT + o; o += 262144;
    }
  }
  unsigned short* WtUp = WT + 1531904;

  // ---- fused weight prep + chpool (1 dispatch) ----
  WtJobs J;
  int toff = 0;
  {
    int ji = 0;
    auto add = [&](const float* s, unsigned short* d, int Kd, int Nd){
      J.src[ji]=s; J.dst[ji]=d; J.Kd[ji]=Kd; J.Nd[ji]=Nd;
      J.tOff[ji]=toff; toff += (Kd>>5) * ((Nd+31)>>5); ji++;
    };
    for (int i=0;i<2;i++){
      add((const float*)d_in[11] + (size_t)i*C_*C_,   WtInp[i], C_, C_);
      add((const float*)d_in[13] + (size_t)i*C_*C_,   WtOut[i], C_, C_);
      add((const float*)d_in[7]  + (size_t)i*C_*OFFN_, WtOM[i], C_, OFFN_);
      add((const float*)d_in[9]  + (size_t)i*C_*MSKN_, WtOM[i] + (size_t)OFFN_*C_, C_, MSKN_);
      add((const float*)d_in[21] + (size_t)i*C_*C4_,  WtC1[i], C_, C4_);
      add((const float*)d_in[23] + (size_t)i*C4_*C_,  WtC2[i], C4_, C_);
    }
    add((const float*)d_in[33], WtUp, KUP_, NOUT_);
    J.tOff[ji] = toff;
  }
  k_wt_pool<<<toff + 256,256,0,stream>>>(J, x_in, psum, pmax);

  // ---- CBAM + fused SA+LN+LN1 ----
  k_ca<<<1,512,0,stream>>>(psum, pmax, (const float*)d_in[26], (const float*)d_in[27], ca);
  k_apply_ca<<<M_,256,0,stream>>>(x_in, X, ca, smean, smax);
  k_sa_mul_ln_ln1<<<M_,256,0,stream>>>(X, smean, smax, (const float*)d_in[28],
      (const float*)d_in[29], (const float*)d_in[30],
      (const float*)d_in[1], (const float*)d_in[2], Tb);

  // ---- layers ----
  for (int i=0;i<2;i++){
    const float* dww  = (const float*)d_in[3] + i*9*C_;
    const float* dwb  = (const float*)d_in[4] + i*C_;
    const float* dwng = (const float*)d_in[5] + i*C_;
    const float* dwnb = (const float*)d_in[6] + i*C_;
    const float* offb = (const float*)d_in[8] + i*OFFN_;
    const float* mskb = (const float*)d_in[10] + i*MSKN_;
    const float* inpb = (const float*)d_in[12] + i*C_;
    const float* outb = (const float*)d_in[14] + i*C_;
    const float* ln2g = (const float*)d_in[15] + i*C_;
    const float* ln2b = (const float*)d_in[16] + i*C_;
    const float* dcw  = (const float*)d_in[17] + i*49*C_;
    const float* dcb  = (const float*)d_in[18] + i*C_;
    const float* fng  = (const float*)d_in[19] + i*C_;
    const float* fnb  = (const float*)d_in[20] + i*C_;
    const float* c1b  = (const float*)d_in[22] + i*C4_;
    const float* c2b  = (const float*)d_in[24] + i*C_;
    const float* gam  = (const float*)d_in[25] + i*C_;
    const float* nxg = (i==0) ? (const float*)d_in[1] + C_ : (const float*)d_in[31];
    const float* nxb = (i==0) ? (const float*)d_in[2] + C_ : (const float*)d_in[32];

    // fused inp-proj GEMM + dw3 (both read Tb) — 1 dispatch
    k_inp_dw3<<<256 + M_*32/256,256,0,stream>>>(Tb, WtInp[i], XPb, inpb, Fb, dww, dwb, dwng, dwnb);
    k_gemm_mfma<64,4,0><<<dim3(M_/64,4),256,0,stream>>>(Fb, WtOM[i], OM, offb, mskb, OMN_, C_);
    k_dcn<<<M_/16,256,0,stream>>>(XPb, OM, Sb);
    k_gemm_ln<2><<<M_/32,256,0,stream>>>(Sb, WtOut[i], X, outb, nullptr, nullptr, Tb, ln2g, ln2b, C_);

    // LEFFN branch (Tb holds ln2 output)
    k_dw7<<<M_*32/256,256,0,stream>>>(Tb, DW7b, dcw, dcb, fng, fnb);
    k_gemm_mfma<128,1,1><<<dim3(M_/128,8),256,0,stream>>>(DW7b, WtC1[i], MIDb, c1b, nullptr, C4_, C_);
    k_gemm_ln<3><<<M_/32,256,0,stream>>>(MIDb, WtC2[i], X, c2b, Tb, gam, Tb, nxg, nxb, C4_);
  }

  // ---- upsample + conv(+LN+GELU) -> d_out ----
  k_upsample<<<MUP_*32/256,256,0,stream>>>(Tb, Ub);
  k_upconv_ln<<<MUP_/64,256,0,stream>>>(Ub, WtUp, (float*)d_out, (const float*)d_in[34],
      (const float*)d_in[35], (const float*)d_in[36]);
}

// Round 12
// 501.840 us; speedup vs baseline: 1.1326x; 1.0014x over previous
//
#include <hip/hip_runtime.h>
#include <math.h>

#define B_ 2
#define H_ 64
#define W_ 64
#define C_ 256
#define G_ 16
#define HW_ (H_*W_)          // 4096
#define M_ (B_*HW_)          // 8192
#define C4_ (4*C_)           // 1024
#define OFFN_ 288
#define MSKN_ 144
#define OMN_ 432
#define UH_ 128
#define UW_ 128
#define MUP_ (B_*UH_*UW_)    // 32768
#define KUP_ (9*C_)          // 2304
#define NOUT_ 128

typedef short short8 __attribute__((ext_vector_type(8)));
typedef float f32x4 __attribute__((ext_vector_type(4)));
typedef unsigned short us4 __attribute__((ext_vector_type(4)));

__device__ __forceinline__ float gelu_f(float x){
  return 0.5f * x * (1.f + erff(x * 0.70710678118654752440f));
}
__device__ __forceinline__ float sigmoid_f(float x){ return 1.f/(1.f+expf(-x)); }
__device__ __forceinline__ unsigned short f2bf(float x){
  unsigned int u = __float_as_uint(x);
  unsigned int r = (u + 0x7fffu + ((u>>16)&1u)) >> 16;
  return (unsigned short)r;
}
__device__ __forceinline__ float bf2f(unsigned short u){
  return __uint_as_float(((unsigned int)u) << 16);
}
__device__ __forceinline__ float bfl(unsigned int u){ return __uint_as_float(u<<16); }
__device__ __forceinline__ float bfh(unsigned int u){ return __uint_as_float(u & 0xffff0000u); }
__device__ __forceinline__ unsigned int pk(float a, float b){
  return (unsigned int)f2bf(a) | ((unsigned int)f2bf(b) << 16);
}

__device__ __forceinline__ void block_sum2(float& s, float& ss, float* sm){
  #pragma unroll
  for (int off=32; off>0; off>>=1){ s += __shfl_down(s, off); ss += __shfl_down(ss, off); }
  int lane = threadIdx.x & 63, wid = threadIdx.x >> 6;
  if (lane == 0){ sm[wid] = s; sm[4+wid] = ss; }
  __syncthreads();
  float a = 0.f, b = 0.f;
  int nw = blockDim.x >> 6;
  for (int i=0;i<nw;i++){ a += sm[i]; b += sm[4+i]; }
  s = a; ss = b;
}

__device__ __forceinline__ void block_summax(float& s, float& m, float* sm){
  #pragma unroll
  for (int off=32; off>0; off>>=1){ s += __shfl_down(s, off); m = fmaxf(m, __shfl_down(m, off)); }
  int lane = threadIdx.x & 63, wid = threadIdx.x >> 6;
  if (lane == 0){ sm[wid] = s; sm[4+wid] = m; }
  __syncthreads();
  float a = 0.f, b = -3.4e38f;
  int nw = blockDim.x >> 6;
  for (int i=0;i<nw;i++){ a += sm[i]; b = fmaxf(b, sm[4+i]); }
  s = a; m = b;
}

// ---------------- fused: batched weight prep + CBAM channel pool ----------------
#define NJOBS 13
struct WtJobs {
  const float* src[NJOBS];
  unsigned short* dst[NJOBS];
  int Kd[NJOBS], Nd[NJOBS];
  int tOff[NJOBS+1];
};

__global__ __launch_bounds__(256) void k_wt_pool(WtJobs J, const float* __restrict__ Xin,
    float* __restrict__ psum, float* __restrict__ pmax){
  __shared__ float tile[32][33];
  int bid = blockIdx.x;
  int nwt = J.tOff[NJOBS];
  if (bid >= nwt){
    int lb = bid - nwt;
    int chunk = lb & 127, b = lb >> 7; int c = threadIdx.x;
    const float* p = Xin + (((size_t)b*HW_) + chunk*32)*C_ + c;
    float s = 0.f, m = -3.4e38f;
    for (int i=0;i<32;i++){ float v = p[(size_t)i*C_]; s += v; m = fmaxf(m, v); }
    psum[(b*128+chunk)*C_+c] = s; pmax[(b*128+chunk)*C_+c] = m;
    return;
  }
  int j = 0;
  while (bid >= J.tOff[j+1]) j++;
  int lt = bid - J.tOff[j];
  const float* W = J.src[j];
  unsigned short* Wt = J.dst[j];
  int Kd = J.Kd[j], Nd = J.Nd[j];
  int ktiles = Kd >> 5;
  int k0 = (lt % ktiles) * 32, n0 = (lt / ktiles) * 32;
  int t = threadIdx.x;
  int r = t>>3, c4 = (t&7)*4;
  float4 v = make_float4(0.f,0.f,0.f,0.f);
  if (n0 + c4 < Nd) v = *(const float4*)(W + (size_t)(k0+r)*Nd + n0 + c4);
  tile[c4+0][r]=v.x; tile[c4+1][r]=v.y; tile[c4+2][r]=v.z; tile[c4+3][r]=v.w;
  __syncthreads();
  if (n0 + r < Nd){
    us4 o;
    o.x = f2bf(tile[r][c4+0]); o.y = f2bf(tile[r][c4+1]);
    o.z = f2bf(tile[r][c4+2]); o.w = f2bf(tile[r][c4+3]);
    *(us4*)(Wt + (size_t)(n0+r)*Kd + k0 + c4) = o;
  }
}

// ---------------- CBAM ----------------
__global__ __launch_bounds__(512) void k_ca(const float* __restrict__ psum, const float* __restrict__ pmax,
    const float* __restrict__ w1, const float* __restrict__ w2, float* __restrict__ ca){
  __shared__ float pm[2][256], px[2][256], hh[2][2][16];
  int t = threadIdx.x;
  {
    int b = t >> 8, c = t & 255;
    float s = 0.f, m = -3.4e38f;
    for (int ch=0; ch<128; ch++){ s += psum[(b*128+ch)*256+c]; m = fmaxf(m, pmax[(b*128+ch)*256+c]); }
    pm[b][c] = s * (1.f/4096.f); px[b][c] = m;
  }
  __syncthreads();
  if (t < 64){
    int b = t >> 5, typ = (t >> 4) & 1, j = t & 15;
    const float* src = typ ? px[b] : pm[b];
    float a = 0.f;
    for (int c2=0;c2<256;c2++) a += src[c2]*w1[c2*16+j];
    hh[b][typ][j] = fmaxf(a, 0.f);
  }
  __syncthreads();
  {
    int b = t >> 8, c = t & 255;
    float a = 0.f;
    for (int j=0;j<16;j++) a += (hh[b][0][j]+hh[b][1][j]) * w2[j*256+c];
    ca[b*256+c] = sigmoid_f(a);
  }
}

__global__ __launch_bounds__(256) void k_apply_ca(const float* __restrict__ Xin, float* __restrict__ X,
    const float* __restrict__ ca, float* __restrict__ smean, float* __restrict__ smax){
  __shared__ float sm[12];
  int pix = blockIdx.x, c = threadIdx.x;
  int b = pix >> 12;
  float v = Xin[(size_t)pix*C_+c] * ca[b*C_+c];
  X[(size_t)pix*C_+c] = v;
  float s = v, m = v;
  block_summax(s, m, sm);
  if (c == 0){ smean[pix] = s * (1.f/C_); smax[pix] = m; }
}

// fused: spatial-attention (7x7) + X=LN(X*sa) + Tb=LN1(X)
__global__ __launch_bounds__(256) void k_sa_mul_ln_ln1(float* __restrict__ X,
    const float* __restrict__ smean, const float* __restrict__ smax, const float* __restrict__ wsa,
    const float* __restrict__ g, const float* __restrict__ b,
    const float* __restrict__ g1, const float* __restrict__ b1, unsigned short* __restrict__ Tb){
  __shared__ float sm[12];
  __shared__ float sav;
  int pix = blockIdx.x, c = threadIdx.x;
  int bb2 = pix >> 12, hw = pix & 4095, h = hw >> 6, ww = hw & 63;
  {
    float s = 0.f;
    if (c < 49){
      int ky = c / 7, kx = c % 7;
      int hh = h + ky - 3, xx = ww + kx - 3;
      if (hh >= 0 && hh < H_ && xx >= 0 && xx < W_){
        int q = (bb2<<12) + (hh<<6) + xx;
        s = smean[q]*wsa[c*2+0] + smax[q]*wsa[c*2+1];
      }
    }
    if (c < 64){
      #pragma unroll
      for (int off=32; off>0; off>>=1) s += __shfl_down(s, off);
      if (c == 0) sav = sigmoid_f(s);
    }
  }
  __syncthreads();
  float v = X[(size_t)pix*C_+c] * sav;
  float s = v, ss = v*v;
  block_sum2(s, ss, sm);
  float mean = s * (1.f/C_), var = ss*(1.f/C_) - mean*mean;
  float r = rsqrtf(var + 1e-6f);
  float x0 = (v-mean)*r*g[c] + b[c];
  X[(size_t)pix*C_+c] = x0;
  __syncthreads();
  s = x0; ss = x0*x0;
  block_sum2(s, ss, sm);
  mean = s * (1.f/C_); var = ss*(1.f/C_) - mean*mean;
  r = rsqrtf(var + 1e-6f);
  Tb[(size_t)pix*C_+c] = f2bf((x0-mean)*r*g1[c] + b1[c]);
}

// dwconv body (shared by fused + standalone kernels)
template<int KS, int DOGELU>
__device__ __forceinline__ void dwconv_body(int t, const unsigned short* __restrict__ T,
    unsigned short* __restrict__ Out,
    const float* __restrict__ w, const float* __restrict__ bias,
    const float* __restrict__ g, const float* __restrict__ bb){
  constexpr int R = KS/2;
  int pix = t >> 5, grp = t & 31;
  int c0 = grp*8;
  int b = pix >> 12, hw = pix & 4095, h = hw >> 6, ww = hw & 63;
  float acc[8];
  {
    float4 b0 = *(const float4*)(bias + c0), b1 = *(const float4*)(bias + c0 + 4);
    acc[0]=b0.x; acc[1]=b0.y; acc[2]=b0.z; acc[3]=b0.w;
    acc[4]=b1.x; acc[5]=b1.y; acc[6]=b1.z; acc[7]=b1.w;
  }
  const unsigned short* tb = T + ((size_t)b*HW_)*C_ + c0;
  for (int ky=0;ky<KS;ky++){
    int hh = h + ky - R; if (hh < 0 || hh >= H_) continue;
    for (int kx=0;kx<KS;kx++){
      int xx = ww + kx - R; if (xx < 0 || xx >= W_) continue;
      uint4 a = *(const uint4*)(tb + ((size_t)hh*W_+xx)*C_);
      const float* wp = w + (ky*KS+kx)*C_ + c0;
      float4 w0 = *(const float4*)wp, w1 = *(const float4*)(wp+4);
      acc[0] += bfl(a.x)*w0.x; acc[1] += bfh(a.x)*w0.y;
      acc[2] += bfl(a.y)*w0.z; acc[3] += bfh(a.y)*w0.w;
      acc[4] += bfl(a.z)*w1.x; acc[5] += bfh(a.z)*w1.y;
      acc[6] += bfl(a.w)*w1.z; acc[7] += bfh(a.w)*w1.w;
    }
  }
  float s = 0.f, ss = 0.f;
  #pragma unroll
  for (int i=0;i<8;i++){ s += acc[i]; ss += acc[i]*acc[i]; }
  #pragma unroll
  for (int off=1; off<32; off<<=1){ s += __shfl_xor(s, off); ss += __shfl_xor(ss, off); }
  float mean = s * (1.f/C_), var = ss*(1.f/C_) - mean*mean;
  float r = rsqrtf(var + 1e-6f);
  float4 g0 = *(const float4*)(g + c0), g1 = *(const float4*)(g + c0 + 4);
  float4 p0 = *(const float4*)(bb + c0), p1 = *(const float4*)(bb + c0 + 4);
  float o[8];
  o[0]=(acc[0]-mean)*r*g0.x+p0.x; o[1]=(acc[1]-mean)*r*g0.y+p0.y;
  o[2]=(acc[2]-mean)*r*g0.z+p0.z; o[3]=(acc[3]-mean)*r*g0.w+p0.w;
  o[4]=(acc[4]-mean)*r*g1.x+p1.x; o[5]=(acc[5]-mean)*r*g1.y+p1.y;
  o[6]=(acc[6]-mean)*r*g1.z+p1.z; o[7]=(acc[7]-mean)*r*g1.w+p1.w;
  if (DOGELU){
    #pragma unroll
    for (int i=0;i<8;i++) o[i] = gelu_f(o[i]);
  }
  uint4 ov;
  ov.x = pk(o[0],o[1]); ov.y = pk(o[2],o[3]); ov.z = pk(o[4],o[5]); ov.w = pk(o[6],o[7]);
  *(uint4*)(Out + (size_t)pix*C_ + c0) = ov;
}

// standalone dw7
__global__ __launch_bounds__(256) void k_dw7(const unsigned short* __restrict__ T,
    unsigned short* __restrict__ Out,
    const float* __restrict__ w, const float* __restrict__ bias,
    const float* __restrict__ g, const float* __restrict__ bb){
  dwconv_body<7,0>(blockIdx.x*256 + threadIdx.x, T, Out, w, bias, g, bb);
}

// ---------------- fused: inp-proj GEMM (blocks 0..255) + dw3 (blocks 256..1279) ----------------
__global__ __launch_bounds__(256) void k_inp_dw3(
    const unsigned short* __restrict__ Tb, const unsigned short* __restrict__ Bt,
    unsigned short* __restrict__ XPb, const float* __restrict__ inpb,
    unsigned short* __restrict__ Fb,
    const float* __restrict__ dww, const float* __restrict__ dwb,
    const float* __restrict__ dwng, const float* __restrict__ dwnb)
{
  constexpr int LD = 40;
  __shared__ unsigned short As[64*LD];
  __shared__ unsigned short Bs[128*LD];
  const int bid = blockIdx.x;
  const int tid = threadIdx.x;
  if (bid >= 256){
    dwconv_body<3,1>((bid-256)*256 + tid, Tb, Fb, dww, dwb, dwng, dwnb);
    return;
  }
  const int wave = tid >> 6, lane = tid & 63;
  const int m0 = (bid & 127) * 64, n0 = (bid >> 7) * 128;
  const int wm0 = (wave >> 1) * 32;
  const int wn0 = (wave & 1) * 64;
  f32x4 acc[2][4] = {};
  const int lm = lane & 15, kq = lane >> 4;

  for (int k0 = 0; k0 < C_; k0 += 32){
    {
      int r = tid >> 2, cc = (tid & 3) << 3;
      short8 v = *(const short8*)(Tb + (size_t)(m0 + r)*C_ + k0 + cc);
      *(short8*)(As + r*LD + cc) = v;
    }
    #pragma unroll
    for (int i=0;i<2;i++){
      int ch = tid + 256*i;
      int r = ch >> 2, cc = (ch & 3) << 3;
      short8 v = *(const short8*)(Bt + (size_t)(n0 + r)*C_ + k0 + cc);
      *(short8*)(Bs + r*LD + cc) = v;
    }
    __syncthreads();
    short8 af[2], bf[4];
    #pragma unroll
    for (int mi=0;mi<2;mi++) af[mi] = *(const short8*)(As + (wm0 + mi*16 + lm)*LD + kq*8);
    #pragma unroll
    for (int ni=0;ni<4;ni++)  bf[ni] = *(const short8*)(Bs + (wn0 + ni*16 + lm)*LD + kq*8);
    #pragma unroll
    for (int mi=0;mi<2;mi++)
      #pragma unroll
      for (int ni=0;ni<4;ni++)
        acc[mi][ni] = __builtin_amdgcn_mfma_f32_16x16x32_bf16(af[mi], bf[ni], acc[mi][ni], 0,0,0);
    __syncthreads();
  }
  #pragma unroll
  for (int mi=0;mi<2;mi++){
    #pragma unroll
    for (int ni=0;ni<4;ni++){
      int n = n0 + wn0 + ni*16 + lm;
      float bv = inpb[n];
      #pragma unroll
      for (int r=0;r<4;r++){
        int m = m0 + wm0 + mi*16 + kq*4 + r;
        XPb[(size_t)m*C_ + n] = f2bf(acc[mi][ni][r] + bv);
      }
    }
  }
}

// ---------------- bf16 MFMA GEMM (generic, N-tiled, BK=32) ----------------
template<int TM, int EP, int OUTBF>
__global__ __launch_bounds__(256) void k_gemm_mfma(
    const unsigned short* __restrict__ A, const unsigned short* __restrict__ Bt,
    void* __restrict__ OutV, const float* __restrict__ bias,
    const float* __restrict__ bias2, int Ni, int Ki)
{
  constexpr int LD = 40;
  __shared__ unsigned short As[TM*LD];
  __shared__ unsigned short Bs[128*LD];
  const int tid = threadIdx.x;
  const int wave = tid >> 6, lane = tid & 63;
  const int m0 = blockIdx.x * TM, n0 = blockIdx.y * 128;
  const int wm0 = (wave >> 1) * (TM/2);
  const int wn0 = (wave & 1) * 64;
  constexpr int MI = (TM+31)/32;
  f32x4 acc[MI][4] = {};
  const int lm = lane & 15, kq = lane >> 4;

  for (int k0 = 0; k0 < Ki; k0 += 32){
    for (int ch = tid; ch < TM*4; ch += 256){
      int r = ch >> 2, cc = (ch & 3) << 3;
      short8 v = *(const short8*)(A + (size_t)(m0 + r)*Ki + k0 + cc);
      *(short8*)(As + r*LD + cc) = v;
    }
    #pragma unroll
    for (int i=0;i<2;i++){
      int ch = tid + 256*i;
      int r = ch >> 2, cc = (ch & 3) << 3;
      short8 v = {};
      if (n0 + r < Ni) v = *(const short8*)(Bt + (size_t)(n0 + r)*Ki + k0 + cc);
      *(short8*)(Bs + r*LD + cc) = v;
    }
    __syncthreads();
    short8 af[MI], bf[4];
    #pragma unroll
    for (int mi=0;mi<MI;mi++) af[mi] = *(const short8*)(As + (wm0 + mi*16 + lm)*LD + kq*8);
    #pragma unroll
    for (int ni=0;ni<4;ni++)  bf[ni] = *(const short8*)(Bs + (wn0 + ni*16 + lm)*LD + kq*8);
    #pragma unroll
    for (int mi=0;mi<MI;mi++)
      #pragma unroll
      for (int ni=0;ni<4;ni++)
        acc[mi][ni] = __builtin_amdgcn_mfma_f32_16x16x32_bf16(af[mi], bf[ni], acc[mi][ni], 0,0,0);
    __syncthreads();
  }
  #pragma unroll
  for (int mi=0;mi<MI;mi++){
    #pragma unroll
    for (int ni=0;ni<4;ni++){
      int n = n0 + wn0 + ni*16 + lm;
      if (n < Ni){
        float bv;
        if constexpr (EP==4) bv = (n < OFFN_) ? bias[n] : bias2[n-OFFN_];
        else bv = bias[n];
        #pragma unroll
        for (int r=0;r<4;r++){
          int m = m0 + wm0 + mi*16 + kq*4 + r;
          size_t o = (size_t)m*Ni + n;
          float v = acc[mi][ni][r] + bv;
          if constexpr (EP==1) v = gelu_f(v);
          if constexpr (OUTBF) ((unsigned short*)OutV)[o] = f2bf(v);
          else                 ((float*)OutV)[o] = v;
        }
      }
    }
  }
}

// ---------------- GEMM with fused residual + row-LN epilogue (c2 path, EP=3) ----------------
template<int EP>
__global__ __launch_bounds__(256) void k_gemm_ln(
    const unsigned short* __restrict__ A, const unsigned short* __restrict__ Bt,
    float* __restrict__ X, const float* __restrict__ bias,
    const unsigned short* __restrict__ res2b, const float* __restrict__ gamma,
    unsigned short* __restrict__ OutTb,
    const float* __restrict__ lng, const float* __restrict__ lnb, int Ki)
{
  constexpr int LD = 40;
  __shared__ unsigned short As[32*LD];
  __shared__ unsigned short Bs[256*LD];
  __shared__ float rs[32][2], rq[32][2];
  const int tid = threadIdx.x;
  const int wave = tid >> 6, lane = tid & 63;
  const int m0 = blockIdx.x * 32;
  const int wm0 = (wave >> 1) * 16;
  const int wn0 = (wave & 1) * 128;
  const int lm = lane & 15, kq = lane >> 4;
  f32x4 acc[8] = {};

  for (int k0 = 0; k0 < Ki; k0 += 32){
    if (tid < 128){
      int r = tid >> 2, cc = (tid & 3) << 3;
      short8 v = *(const short8*)(A + (size_t)(m0 + r)*Ki + k0 + cc);
      *(short8*)(As + r*LD + cc) = v;
    }
    #pragma unroll
    for (int i=0;i<4;i++){
      int ch = tid + 256*i;
      int r = ch >> 2, cc = (ch & 3) << 3;
      short8 v = *(const short8*)(Bt + (size_t)r*Ki + k0 + cc);
      *(short8*)(Bs + r*LD + cc) = v;
    }
    __syncthreads();
    short8 af = *(const short8*)(As + (wm0 + lm)*LD + kq*8);
    short8 bf[8];
    #pragma unroll
    for (int ni=0;ni<8;ni++) bf[ni] = *(const short8*)(Bs + (wn0 + ni*16 + lm)*LD + kq*8);
    #pragma unroll
    for (int ni=0;ni<8;ni++)
      acc[ni] = __builtin_amdgcn_mfma_f32_16x16x32_bf16(af, bf[ni], acc[ni], 0,0,0);
    __syncthreads();
  }
  int nn[8]; float bv[8], gv[8];
  #pragma unroll
  for (int ni=0;ni<8;ni++){
    nn[ni] = wn0 + ni*16 + lm;
    bv[ni] = bias[nn[ni]];
    if constexpr (EP==3) gv[ni] = gamma[nn[ni]];
  }
  float ps[4] = {}, pq[4] = {};
  #pragma unroll
  for (int r=0;r<4;r++){
    int m = m0 + wm0 + kq*4 + r;
    #pragma unroll
    for (int ni=0;ni<8;ni++){
      size_t o = (size_t)m*C_ + nn[ni];
      float v = acc[ni][r] + bv[ni];
      if constexpr (EP==2) v = X[o] + v;
      if constexpr (EP==3) v = X[o] + bf2f(res2b[o]) + gv[ni]*v;
      X[o] = v;
      acc[ni][r] = v;
      ps[r] += v; pq[r] += v*v;
    }
  }
  #pragma unroll
  for (int off=1; off<16; off<<=1){
    #pragma unroll
    for (int r=0;r<4;r++){ ps[r] += __shfl_xor(ps[r], off); pq[r] += __shfl_xor(pq[r], off); }
  }
  if (lm == 0){
    #pragma unroll
    for (int r=0;r<4;r++){
      rs[wm0 + kq*4 + r][wave & 1] = ps[r];
      rq[wm0 + kq*4 + r][wave & 1] = pq[r];
    }
  }
  __syncthreads();
  float lg[8], lb[8];
  #pragma unroll
  for (int ni=0;ni<8;ni++){ lg[ni] = lng[nn[ni]]; lb[ni] = lnb[nn[ni]]; }
  #pragma unroll
  for (int r=0;r<4;r++){
    int row = wm0 + kq*4 + r;
    int m = m0 + row;
    float s = rs[row][0] + rs[row][1];
    float q = rq[row][0] + rq[row][1];
    float mean = s * (1.f/C_), var = q*(1.f/C_) - mean*mean;
    float rstd = rsqrtf(var + 1e-6f);
    #pragma unroll
    for (int ni=0;ni<8;ni++){
      size_t o = (size_t)m*C_ + nn[ni];
      OutTb[o] = f2bf((acc[ni][r]-mean)*rstd*lg[ni] + lb[ni]);
    }
  }
}

// ---------------- fused: DCN sampling + out-proj GEMM + residual + LN2 ----------------
// Block = 32 pixels. Phase 0: dcn sampling for 32 pixels -> full-K A tile in LDS (bf16).
// Then K-loop with zero A staging; epilogue = residual add + X write + row-LN -> Tb.
__global__ __launch_bounds__(256) void k_dcn_gemm_ln(
    const unsigned short* __restrict__ xp, const float* __restrict__ OM,
    const unsigned short* __restrict__ Bt,
    float* __restrict__ X, const float* __restrict__ bias,
    unsigned short* __restrict__ OutTb,
    const float* __restrict__ lng, const float* __restrict__ lnb)
{
  constexpr int LDA = 264;                 // 256 + 8 pad
  constexpr int LD = 40;
  __shared__ unsigned short As[32*LDA];    // 16.5 KB full-K A tile
  __shared__ unsigned short Bs[256*LD];    // 20 KB
  __shared__ float rs[32][2], rq[32][2];
  const int tid = threadIdx.x;
  const int wave = tid >> 6, lane = tid & 63;
  const int m0 = blockIdx.x * 32;
  const int wm0 = (wave >> 1) * 16;
  const int wn0 = (wave & 1) * 128;
  const int lm = lane & 15, kq = lane >> 4;

  // ---- phase 0: dcn sampling into As ----
  #pragma unroll
  for (int it=0; it<2; it++){
    int task = tid + 256*it;               // [0,512)
    int pl = task >> 4, g = task & 15;
    int pix = m0 + pl;
    int b = pix >> 12, hw = pix & 4095, h = hw >> 6, ww = hw & 63;
    const float* offp = OM + (size_t)pix*OMN_ + g*18;
    const float* mp   = OM + (size_t)pix*OMN_ + OFFN_ + g*9;
    const unsigned short* xpb = xp + ((size_t)b*HW_)*C_ + g*16;
    float e[9]; float mx = -3.4e38f;
    #pragma unroll
    for (int k=0;k<9;k++){ e[k] = mp[k]; mx = fmaxf(mx, e[k]); }
    float ssum = 0.f;
    #pragma unroll
    for (int k=0;k<9;k++){ e[k] = expf(e[k]-mx); ssum += e[k]; }
    float rinv = 1.f/ssum;
    float acc[16] = {};
    #pragma unroll
    for (int k=0;k<9;k++){
      float ox = offp[k*2+0], oy = offp[k*2+1];
      float px = (float)(ww + (k%3)) + ox;
      float py = (float)(h  + (k/3)) + oy;
      int x0 = (int)floorf(px), y0 = (int)floorf(py);
      float fx = px - (float)x0, fy = py - (float)y0;
      float mk = e[k]*rinv;
      float w00 = mk*(1.f-fx)*(1.f-fy), w01 = mk*fx*(1.f-fy);
      float w10 = mk*(1.f-fx)*fy,       w11 = mk*fx*fy;
      #define CORNER(yy,xx,WGT) do{ \
        if ((yy)>=1 && (yy)<=H_ && (xx)>=1 && (xx)<=W_){ \
          const unsigned short* p = xpb + ((size_t)((yy)-1)*W_ + ((xx)-1))*C_; \
          uint4 a0 = *(const uint4*)p; uint4 a1 = *(const uint4*)(p+8); \
          acc[0]+=WGT*bfl(a0.x); acc[1]+=WGT*bfh(a0.x); acc[2]+=WGT*bfl(a0.y); acc[3]+=WGT*bfh(a0.y); \
          acc[4]+=WGT*bfl(a0.z); acc[5]+=WGT*bfh(a0.z); acc[6]+=WGT*bfl(a0.w); acc[7]+=WGT*bfh(a0.w); \
          acc[8]+=WGT*bfl(a1.x); acc[9]+=WGT*bfh(a1.x); acc[10]+=WGT*bfl(a1.y); acc[11]+=WGT*bfh(a1.y); \
          acc[12]+=WGT*bfl(a1.z); acc[13]+=WGT*bfh(a1.z); acc[14]+=WGT*bfl(a1.w); acc[15]+=WGT*bfh(a1.w); \
        } \
      }while(0)
      CORNER(y0,   x0,   w00);
      CORNER(y0,   x0+1, w01);
      CORNER(y0+1, x0,   w10);
      CORNER(y0+1, x0+1, w11);
      #undef CORNER
    }
    uint4 o0, o1;
    o0.x = pk(acc[0],acc[1]);   o0.y = pk(acc[2],acc[3]);
    o0.z = pk(acc[4],acc[5]);   o0.w = pk(acc[6],acc[7]);
    o1.x = pk(acc[8],acc[9]);   o1.y = pk(acc[10],acc[11]);
    o1.z = pk(acc[12],acc[13]); o1.w = pk(acc[14],acc[15]);
    *(uint4*)(As + pl*LDA + g*16) = o0;
    *(uint4*)(As + pl*LDA + g*16 + 8) = o1;
  }
  __syncthreads();

  // ---- GEMM K-loop (A from LDS, stage Bs only) ----
  f32x4 acc[8] = {};
  for (int k0 = 0; k0 < C_; k0 += 32){
    #pragma unroll
    for (int i=0;i<4;i++){
      int ch = tid + 256*i;
      int r = ch >> 2, cc = (ch & 3) << 3;
      short8 v = *(const short8*)(Bt + (size_t)r*C_ + k0 + cc);
      *(short8*)(Bs + r*LD + cc) = v;
    }
    __syncthreads();
    short8 af = *(const short8*)(As + (wm0 + lm)*LDA + k0 + kq*8);
    short8 bf[8];
    #pragma unroll
    for (int ni=0;ni<8;ni++) bf[ni] = *(const short8*)(Bs + (wn0 + ni*16 + lm)*LD + kq*8);
    #pragma unroll
    for (int ni=0;ni<8;ni++)
      acc[ni] = __builtin_amdgcn_mfma_f32_16x16x32_bf16(af, bf[ni], acc[ni], 0,0,0);
    __syncthreads();
  }
  // ---- epilogue: residual + X write + row-LN -> Tb ----
  int nn[8]; float bv[8];
  #pragma unroll
  for (int ni=0;ni<8;ni++){ nn[ni] = wn0 + ni*16 + lm; bv[ni] = bias[nn[ni]]; }
  float ps[4] = {}, pq[4] = {};
  #pragma unroll
  for (int r=0;r<4;r++){
    int m = m0 + wm0 + kq*4 + r;
    #pragma unroll
    for (int ni=0;ni<8;ni++){
      size_t o = (size_t)m*C_ + nn[ni];
      float v = X[o] + acc[ni][r] + bv[ni];
      X[o] = v;
      acc[ni][r] = v;
      ps[r] += v; pq[r] += v*v;
    }
  }
  #pragma unroll
  for (int off=1; off<16; off<<=1){
    #pragma unroll
    for (int r=0;r<4;r++){ ps[r] += __shfl_xor(ps[r], off); pq[r] += __shfl_xor(pq[r], off); }
  }
  if (lm == 0){
    #pragma unroll
    for (int r=0;r<4;r++){
      rs[wm0 + kq*4 + r][wave & 1] = ps[r];
      rq[wm0 + kq*4 + r][wave & 1] = pq[r];
    }
  }
  __syncthreads();
  float lg[8], lb[8];
  #pragma unroll
  for (int ni=0;ni<8;ni++){ lg[ni] = lng[nn[ni]]; lb[ni] = lnb[nn[ni]]; }
  #pragma unroll
  for (int r=0;r<4;r++){
    int row = wm0 + kq*4 + r;
    int m = m0 + row;
    float s = rs[row][0] + rs[row][1];
    float q = rq[row][0] + rq[row][1];
    float mean = s * (1.f/C_), var = q*(1.f/C_) - mean*mean;
    float rstd = rsqrtf(var + 1e-6f);
    #pragma unroll
    for (int ni=0;ni<8;ni++){
      size_t o = (size_t)m*C_ + nn[ni];
      OutTb[o] = f2bf((acc[ni][r]-mean)*rstd*lg[ni] + lb[ni]);
    }
  }
}

// bilinear 2x upsample (bf16 in) -> bf16, 8 ch/thread
__global__ __launch_bounds__(256) void k_upsample(const unsigned short* __restrict__ T, unsigned short* __restrict__ U){
  int t = blockIdx.x*256 + threadIdx.x;
  int opix = t >> 5, grp = t & 31;
  int c0 = grp*8;
  int ox = opix & 127, oy = (opix >> 7) & 127, b = opix >> 14;
  float sy = oy*0.5f - 0.25f, sx = ox*0.5f - 0.25f;
  int y0 = (int)floorf(sy), x0 = (int)floorf(sx);
  float fy = sy - (float)y0, fx = sx - (float)x0;
  int y0c = min(max(y0,0),H_-1), y1c = min(max(y0+1,0),H_-1);
  int x0c = min(max(x0,0),W_-1), x1c = min(max(x0+1,0),W_-1);
  const unsigned short* tb = T + ((size_t)b*HW_)*C_ + c0;
  uint4 q00 = *(const uint4*)(tb + ((size_t)y0c*W_+x0c)*C_);
  uint4 q01 = *(const uint4*)(tb + ((size_t)y0c*W_+x1c)*C_);
  uint4 q10 = *(const uint4*)(tb + ((size_t)y1c*W_+x0c)*C_);
  uint4 q11 = *(const uint4*)(tb + ((size_t)y1c*W_+x1c)*C_);
  float w00=(1.f-fy)*(1.f-fx), w01=(1.f-fy)*fx, w10=fy*(1.f-fx), w11=fy*fx;
  float o[8];
  o[0]=w00*bfl(q00.x)+w01*bfl(q01.x)+w10*bfl(q10.x)+w11*bfl(q11.x);
  o[1]=w00*bfh(q00.x)+w01*bfh(q01.x)+w10*bfh(q10.x)+w11*bfh(q11.x);
  o[2]=w00*bfl(q00.y)+w01*bfl(q01.y)+w10*bfl(q10.y)+w11*bfl(q11.y);
  o[3]=w00*bfh(q00.y)+w01*bfh(q01.y)+w10*bfh(q10.y)+w11*bfh(q11.y);
  o[4]=w00*bfl(q00.z)+w01*bfl(q01.z)+w10*bfl(q10.z)+w11*bfl(q11.z);
  o[5]=w00*bfh(q00.z)+w01*bfh(q01.z)+w10*bfh(q10.z)+w11*bfh(q11.z);
  o[6]=w00*bfl(q00.w)+w01*bfl(q01.w)+w10*bfl(q10.w)+w11*bfl(q11.w);
  o[7]=w00*bfh(q00.w)+w01*bfh(q01.w)+w10*bfh(q10.w)+w11*bfh(q11.w);
  uint4 ov;
  ov.x = pk(o[0],o[1]); ov.y = pk(o[2],o[3]); ov.z = pk(o[4],o[5]); ov.w = pk(o[6],o[7]);
  *(uint4*)(U + (size_t)opix*C_ + c0) = ov;
}

// implicit-GEMM 3x3 conv (TM=64, BK=128) + fused bias + row-LN + GELU -> d_out fp32
__global__ __launch_bounds__(256) void k_upconv_ln(
    const unsigned short* __restrict__ U, const unsigned short* __restrict__ Wt,
    float* __restrict__ Out, const float* __restrict__ bias,
    const float* __restrict__ g, const float* __restrict__ bb)
{
  constexpr int LD = 136;
  __shared__ unsigned short As[64*LD];
  __shared__ unsigned short Bs[128*LD];
  __shared__ float rs[64][2], rq[64][2];
  const int tid = threadIdx.x;
  const int wave = tid >> 6, lane = tid & 63;
  const int m0 = blockIdx.x * 64;
  const int wm0 = (wave >> 1) * 32;
  const int wn0 = (wave & 1) * 64;
  const int lm = lane & 15, kq = lane >> 4;
  f32x4 acc[2][4] = {};
  const int r0 = tid >> 2, cA0 = (tid & 3) << 5;
  const int ma = m0 + r0;
  const int ba = ma >> 14, oya = (ma >> 7) & 127, oxa = ma & 127;

  for (int k0 = 0; k0 < KUP_; k0 += 128){
    int tap = k0 >> 8, cc0 = k0 & 255;
    int dy = tap/3 - 1, dx = tap%3 - 1;
    {
      int iy = oya + dy, ix = oxa + dx;
      bool ok = (iy >= 0 && iy < UH_ && ix >= 0 && ix < UW_);
      const unsigned short* src = U + (((size_t)ba*UH_ + iy)*UW_ + ix)*C_ + cc0 + cA0;
      #pragma unroll
      for (int i=0;i<4;i++){
        short8 v = {};
        if (ok) v = *(const short8*)(src + i*8);
        *(short8*)(As + r0*LD + cA0 + i*8) = v;
      }
    }
    #pragma unroll
    for (int i=0;i<8;i++){
      int ch = tid + 256*i;
      int r = ch >> 4, cc = (ch & 15) << 3;
      short8 v = *(const short8*)(Wt + (size_t)r*KUP_ + k0 + cc);
      *(short8*)(Bs + r*LD + cc) = v;
    }
    __syncthreads();
    short8 af[2][4], bf4[4][4];
    #pragma unroll
    for (int mi=0;mi<2;mi++)
      #pragma unroll
      for (int kk=0;kk<4;kk++)
        af[mi][kk] = *(const short8*)(As + (wm0 + mi*16 + lm)*LD + kk*32 + kq*8);
    #pragma unroll
    for (int ni=0;ni<4;ni++)
      #pragma unroll
      for (int kk=0;kk<4;kk++)
        bf4[ni][kk] = *(const short8*)(Bs + (wn0 + ni*16 + lm)*LD + kk*32 + kq*8);
    #pragma unroll
    for (int kk=0;kk<4;kk++)
      #pragma unroll
      for (int mi=0;mi<2;mi++)
        #pragma unroll
        for (int ni=0;ni<4;ni++)
          acc[mi][ni] = __builtin_amdgcn_mfma_f32_16x16x32_bf16(af[mi][kk], bf4[ni][kk], acc[mi][ni], 0,0,0);
    __syncthreads();
  }
  int nn[4]; float bv[4];
  #pragma unroll
  for (int ni=0;ni<4;ni++){ nn[ni] = wn0 + ni*16 + lm; bv[ni] = bias[nn[ni]]; }
  float ps[2][4] = {}, pq[2][4] = {};
  #pragma unroll
  for (int mi=0;mi<2;mi++)
    #pragma unroll
    for (int r=0;r<4;r++)
      #pragma unroll
      for (int ni=0;ni<4;ni++){
        float v = acc[mi][ni][r] + bv[ni];
        acc[mi][ni][r] = v;
        ps[mi][r] += v; pq[mi][r] += v*v;
      }
  #pragma unroll
  for (int off=1; off<16; off<<=1){
    #pragma unroll
    for (int mi=0;mi<2;mi++)
      #pragma unroll
      for (int r=0;r<4;r++){ ps[mi][r] += __shfl_xor(ps[mi][r], off); pq[mi][r] += __shfl_xor(pq[mi][r], off); }
  }
  if (lm == 0){
    #pragma unroll
    for (int mi=0;mi<2;mi++)
      #pragma unroll
      for (int r=0;r<4;r++){
        rs[wm0 + mi*16 + kq*4 + r][wave & 1] = ps[mi][r];
        rq[wm0 + mi*16 + kq*4 + r][wave & 1] = pq[mi][r];
      }
  }
  __syncthreads();
  float gv[4], pv[4];
  #pragma unroll
  for (int ni=0;ni<4;ni++){ gv[ni] = g[nn[ni]]; pv[ni] = bb[nn[ni]]; }
  #pragma unroll
  for (int mi=0;mi<2;mi++)
    #pragma unroll
    for (int r=0;r<4;r++){
      int row = wm0 + mi*16 + kq*4 + r;
      int m = m0 + row;
      float s = rs[row][0] + rs[row][1];
      float q = rq[row][0] + rq[row][1];
      float mean = s * (1.f/NOUT_), var = q*(1.f/NOUT_) - mean*mean;
      float rstd = rsqrtf(var + 1e-6f);
      #pragma unroll
      for (int ni=0;ni<4;ni++)
        Out[(size_t)m*NOUT_ + nn[ni]] = gelu_f((acc[mi][ni][r]-mean)*rstd*gv[ni] + pv[ni]);
    }
}

extern "C" void kernel_launch(void* const* d_in, const int* in_sizes, int n_in,
                              void* d_out, int out_size, void* d_ws, size_t ws_size,
                              hipStream_t stream)
{
  (void)in_sizes; (void)n_in; (void)out_size; (void)ws_size;
  const float* x_in = (const float*)d_in[0];
  char* w = (char*)d_ws;
  const size_t MB = 1u<<20;
  float* X    = (float*)(w + 0*MB);
  float* OM   = (float*)(w + 8*MB);
  unsigned short* MIDb = (unsigned short*)(w + 22*MB);
  unsigned short* Ub   = MIDb;
  unsigned short* Tb   = (unsigned short*)(w + 38*MB);
  unsigned short* Fb   = (unsigned short*)(w + 42*MB);
  unsigned short* XPb  = (unsigned short*)(w + 46*MB);
  unsigned short* DW7b = (unsigned short*)(w + 50*MB);
  unsigned short* WT   = (unsigned short*)(w + 58*MB);
  float* psum = (float*)(w + 62*MB);
  float* pmax = psum + 65536;
  float* ca   = pmax + 65536;
  float* smean= ca + 512;
  float* smax = smean + 8192;

  unsigned short* WtInp[2], *WtOut[2], *WtOM[2], *WtC1[2], *WtC2[2];
  {
    size_t o = 0;
    for (int i=0;i<2;i++){
      WtInp[i] = WT + o; o += 65536;
      WtOut[i] = WT + o; o += 65536;
      WtOM[i]  = WT + o; o += 110592;
      WtC1[i]  = WT + o; o += 262144;
      WtC2[i]  = WT + o; o += 262144;
    }
  }
  unsigned short* WtUp = WT + 1531904;

  // ---- fused weight prep + chpool (1 dispatch) ----
  WtJobs J;
  int toff = 0;
  {
    int ji = 0;
    auto add = [&](const float* s, unsigned short* d, int Kd, int Nd){
      J.src[ji]=s; J.dst[ji]=d; J.Kd[ji]=Kd; J.Nd[ji]=Nd;
      J.tOff[ji]=toff; toff += (Kd>>5) * ((Nd+31)>>5); ji++;
    };
    for (int i=0;i<2;i++){
      add((const float*)d_in[11] + (size_t)i*C_*C_,   WtInp[i], C_, C_);
      add((const float*)d_in[13] + (size_t)i*C_*C_,   WtOut[i], C_, C_);
      add((const float*)d_in[7]  + (size_t)i*C_*OFFN_, WtOM[i], C_, OFFN_);
      add((const float*)d_in[9]  + (size_t)i*C_*MSKN_, WtOM[i] + (size_t)OFFN_*C_, C_, MSKN_);
      add((const float*)d_in[21] + (size_t)i*C_*C4_,  WtC1[i], C_, C4_);
      add((const float*)d_in[23] + (size_t)i*C4_*C_,  WtC2[i], C4_, C_);
    }
    add((const float*)d_in[33], WtUp, KUP_, NOUT_);
    J.tOff[ji] = toff;
  }
  k_wt_pool<<<toff + 256,256,0,stream>>>(J, x_in, psum, pmax);

  // ---- CBAM + fused SA+LN+LN1 ----
  k_ca<<<1,512,0,stream>>>(psum, pmax, (const float*)d_in[26], (const float*)d_in[27], ca);
  k_apply_ca<<<M_,256,0,stream>>>(x_in, X, ca, smean, smax);
  k_sa_mul_ln_ln1<<<M_,256,0,stream>>>(X, smean, smax, (const float*)d_in[28],
      (const float*)d_in[29], (const float*)d_in[30],
      (const float*)d_in[1], (const float*)d_in[2], Tb);

  // ---- layers ----
  for (int i=0;i<2;i++){
    const float* dww  = (const float*)d_in[3] + i*9*C_;
    const float* dwb  = (const float*)d_in[4] + i*C_;
    const float* dwng = (const float*)d_in[5] + i*C_;
    const float* dwnb = (const float*)d_in[6] + i*C_;
    const float* offb = (const float*)d_in[8] + i*OFFN_;
    const float* mskb = (const float*)d_in[10] + i*MSKN_;
    const float* inpb = (const float*)d_in[12] + i*C_;
    const float* outb = (const float*)d_in[14] + i*C_;
    const float* ln2g = (const float*)d_in[15] + i*C_;
    const float* ln2b = (const float*)d_in[16] + i*C_;
    const float* dcw  = (const float*)d_in[17] + i*49*C_;
    const float* dcb  = (const float*)d_in[18] + i*C_;
    const float* fng  = (const float*)d_in[19] + i*C_;
    const float* fnb  = (const float*)d_in[20] + i*C_;
    const float* c1b  = (const float*)d_in[22] + i*C4_;
    const float* c2b  = (const float*)d_in[24] + i*C_;
    const float* gam  = (const float*)d_in[25] + i*C_;
    const float* nxg = (i==0) ? (const float*)d_in[1] + C_ : (const float*)d_in[31];
    const float* nxb = (i==0) ? (const float*)d_in[2] + C_ : (const float*)d_in[32];

    // fused inp-proj GEMM + dw3 (both read Tb) — 1 dispatch
    k_inp_dw3<<<256 + M_*32/256,256,0,stream>>>(Tb, WtInp[i], XPb, inpb, Fb, dww, dwb, dwng, dwnb);
    k_gemm_mfma<64,4,0><<<dim3(M_/64,4),256,0,stream>>>(Fb, WtOM[i], OM, offb, mskb, OMN_, C_);
    // fused dcn sampling + out-proj + residual + LN2 -> X, Tb(ln2)
    k_dcn_gemm_ln<<<M_/32,256,0,stream>>>(XPb, OM, WtOut[i], X, outb, Tb, ln2g, ln2b);

    // LEFFN branch (Tb holds ln2 output)
    k_dw7<<<M_*32/256,256,0,stream>>>(Tb, DW7b, dcw, dcb, fng, fnb);
    k_gemm_mfma<128,1,1><<<dim3(M_/128,8),256,0,stream>>>(DW7b, WtC1[i], MIDb, c1b, nullptr, C4_, C_);
    k_gemm_ln<3><<<M_/32,256,0,stream>>>(MIDb, WtC2[i], X, c2b, Tb, gam, Tb, nxg, nxb, C4_);
  }

  // ---- upsample + conv(+LN+GELU) -> d_out ----
  k_upsample<<<MUP_*32/256,256,0,stream>>>(Tb, Ub);
  k_upconv_ln<<<MUP_/64,256,0,stream>>>(Ub, WtUp, (float*)d_out, (const float*)d_in[34],
      (const float*)d_in[35], (const float*)d_in[36]);
}